// Round 9
// baseline (2017.232 us; speedup 1.0000x reference)
//
#include <hip/hip_runtime.h>
#include <cstdint>
#include <cstddef>

#define LK(x) ((x) > 0.f ? (x) : 0.01f * (x))

typedef _Float16 f16x8 __attribute__((ext_vector_type(8)));
typedef _Float16 f16x4 __attribute__((ext_vector_type(4)));
typedef float f32x4 __attribute__((ext_vector_type(4)));

constexpr int B_ = 256;
constexpr int N_ = 256;
constexpr int BN = B_ * N_;
constexpr int CHUNK_B = 64;                 // batches per UV chunk
constexpr int CHUNK_ROWS = CHUNK_B * N_;    // 16384 rows

// fp16 2-way split (for fp16x3 path)
__device__ inline void dec2(float v, _Float16& h, _Float16& l) {
  _Float16 hh = (_Float16)v;
  h = hh;
  l = (_Float16)(v - (float)hh);
}

// ---------------- KNN: one block per batch, one thread per point ----------------
__global__ void knn_kernel(const float* __restrict__ feat, int F, int* __restrict__ idxout) {
  __shared__ float px[N_], py[N_], pz[N_];
  int b = blockIdx.x, t = threadIdx.x;
  const float* row = feat + ((size_t)b * N_ + t) * F;
  px[t] = row[0]; py[t] = row[1]; pz[t] = row[2];
  __syncthreads();
  float x = px[t], y = py[t], z = pz[t];
  float bd0 = INFINITY, bd1 = INFINITY, bd2 = INFINITY, bd3 = INFINITY;
  int bi0 = 0, bi1 = 0, bi2 = 0, bi3 = 0;
  for (int j = 0; j < N_; ++j) {
    #pragma clang fp contract(off)
    float dx = x - px[j], dy = y - py[j], dz = z - pz[j];
    float d = (dx * dx + dy * dy) + dz * dz;
    if (j == t) continue;
    if (d < bd3) {
      if (d < bd2) {
        bd3 = bd2; bi3 = bi2;
        if (d < bd1) {
          bd2 = bd1; bi2 = bi1;
          if (d < bd0) { bd1 = bd0; bi1 = bi0; bd0 = d; bi0 = j; }
          else         { bd1 = d; bi1 = j; }
        } else         { bd2 = d; bi2 = j; }
      } else           { bd3 = d; bi3 = j; }
    }
  }
  int* o = idxout + ((size_t)b * N_ + t) * 4;
  o[0] = bi0; o[1] = bi1; o[2] = bi2; o[3] = bi3;
}

// ============================ fp32 path (bit-exact chain) ============================

// wcat = [w1_top - w1_bot | w1_bot] (F x 2H1), bcat = [b1 | 0]
__global__ void prep_uvw(const float* __restrict__ w1, const float* __restrict__ b1,
                         int F, int H1, float* __restrict__ wcat, float* __restrict__ bcat) {
  int t = blockIdx.x * 256 + threadIdx.x;
  int FH = F * H1;
  if (t < FH) {
    int k = t / H1, c = t - k * H1;
    float top = w1[(size_t)k * H1 + c];
    float bot = w1[(size_t)(F + k) * H1 + c];
    wcat[(size_t)k * 2 * H1 + c]      = top - bot;
    wcat[(size_t)k * 2 * H1 + H1 + c] = bot;
  }
  if (t < H1) { bcat[t] = b1[t]; bcat[H1 + t] = 0.f; }
}

// fp32 GEMM: 128x64 tile, BK=16, 256 thr, 8x4 micro (proven R3 config)
template<bool ACT_A, bool ACCUM, bool HAS_BIAS>
__global__ __launch_bounds__(256) void gemm_f32(
    const float* __restrict__ A, const float* __restrict__ W,
    const float* __restrict__ bias, float* __restrict__ C,
    int M, int N, int K) {
  __shared__ float sA[16][132];
  __shared__ float sW[16][68];
  int tid = threadIdx.x;
  int m0 = blockIdx.y * 128;
  int n0 = blockIdx.x * 64;
  int kkA = tid & 15, mA = tid >> 4;
  int nW = tid & 63, kW = tid >> 6;
  int ty = tid >> 4, tx = tid & 15;
  float acc[8][4] = {};
  for (int k0 = 0; k0 < K; k0 += 16) {
    int kg = k0 + kkA;
    #pragma unroll
    for (int i = 0; i < 8; ++i) {
      int m = mA + i * 16;
      float v = 0.f;
      if (kg < K) {
        v = A[(size_t)(m0 + m) * K + kg];
        if (ACT_A) v = LK(v);
      }
      sA[kkA][m] = v;
    }
    #pragma unroll
    for (int q = 0; q < 4; ++q) {
      int kk = kW + q * 4;
      int kgw = k0 + kk, n = n0 + nW;
      float v = 0.f;
      if (kgw < K && n < N) v = W[(size_t)kgw * N + n];
      sW[kk][nW] = v;
    }
    __syncthreads();
    #pragma unroll
    for (int kk = 0; kk < 16; ++kk) {
      float4 a0 = *(const float4*)&sA[kk][ty * 8];
      float4 a1 = *(const float4*)&sA[kk][ty * 8 + 4];
      float4 w  = *(const float4*)&sW[kk][tx * 4];
      float av[8] = {a0.x, a0.y, a0.z, a0.w, a1.x, a1.y, a1.z, a1.w};
      float wv[4] = {w.x, w.y, w.z, w.w};
      #pragma unroll
      for (int i = 0; i < 8; ++i)
        #pragma unroll
        for (int j = 0; j < 4; ++j)
          acc[i][j] += av[i] * wv[j];
    }
    __syncthreads();
  }
  int n = n0 + tx * 4;
  float bv[4] = {0.f, 0.f, 0.f, 0.f};
  if (HAS_BIAS) {
    #pragma unroll
    for (int j = 0; j < 4; ++j) if (n + j < N) bv[j] = bias[n + j];
  }
  #pragma unroll
  for (int i = 0; i < 8; ++i) {
    size_t m = (size_t)(m0 + ty * 8 + i);
    if (n + 3 < N) {
      float4 o;
      o.x = acc[i][0] + bv[0]; o.y = acc[i][1] + bv[1];
      o.z = acc[i][2] + bv[2]; o.w = acc[i][3] + bv[3];
      float4* cp = (float4*)(C + m * N + n);
      if (ACCUM) { float4 c = *cp; o.x += c.x; o.y += c.y; o.z += c.z; o.w += c.w; }
      *cp = o;
    } else {
      #pragma unroll
      for (int j = 0; j < 4; ++j) {
        if (n + j < N) {
          float v = acc[i][j] + bv[j];
          size_t off = m * N + n + j;
          if (ACCUM) v += C[off];
          C[off] = v;
        }
      }
    }
  }
}

// fp32 fused edge stage 2, K-tiled (proven 16-pt version) — layers 1,2
__global__ __launch_bounds__(256) void edge_stage2(
    const float* __restrict__ UV, const int* __restrict__ idx,
    const float* __restrict__ w2, const float* __restrict__ b2,
    float* __restrict__ out, int H1) {
  __shared__ float sH[16][68];
  __shared__ float sW[16][196];
  __shared__ int sJ[64];
  int tid = threadIdx.x;
  int g0 = blockIdx.x * 16;
  int bbase = (g0 >> 8) << 8;
  if (tid < 64) sJ[tid] = bbase + idx[(size_t)g0 * 4 + tid];
  int W2 = H1 * 2;
  int r = tid >> 2, seg = tid & 3;
  int gp_r = g0 + (r >> 2);
  int ty = tid >> 4, tx = tid & 15;
  int gp = g0 + ty;
  float acc[4][12] = {};
  int nKt = (H1 + 15) >> 4;
  for (int kt = 0; kt < nKt; ++kt) {
    int k0 = kt << 4;
    __syncthreads();
    {
      int c = k0 + (seg << 2);
      const float* up = UV + (size_t)gp_r * W2 + c;
      const float* vp = UV + (size_t)sJ[r] * W2 + H1 + c;
      float u[4], v[4];
      if (c + 3 < H1) {
        float4 uu = *(const float4*)up; float4 vv = *(const float4*)vp;
        u[0] = uu.x; u[1] = uu.y; u[2] = uu.z; u[3] = uu.w;
        v[0] = vv.x; v[1] = vv.y; v[2] = vv.z; v[3] = vv.w;
      } else {
        #pragma unroll
        for (int j = 0; j < 4; ++j) {
          u[j] = (c + j < H1) ? up[j] : 0.f;
          v[j] = (c + j < H1) ? vp[j] : 0.f;
        }
      }
      #pragma unroll
      for (int j = 0; j < 4; ++j) {
        float t = u[j] + v[j];
        sH[(seg << 2) + j][r] = (c + j < H1) ? LK(t) : 0.f;
      }
    }
    #pragma unroll
    for (int p = 0; p < 3; ++p) {
      int q = tid + (p << 8);
      int kk = q / 48;
      int c4 = q - kk * 48;
      int k = k0 + kk;
      float4 wv = {0.f, 0.f, 0.f, 0.f};
      if (k < H1) wv = *(const float4*)(w2 + (size_t)k * 192 + (c4 << 2));
      *(float4*)&sW[kk][c4 << 2] = wv;
    }
    __syncthreads();
    #pragma unroll
    for (int kk = 0; kk < 16; ++kk) {
      float4 a = *(const float4*)&sH[kk][ty << 2];
      float av[4] = {a.x, a.y, a.z, a.w};
      #pragma unroll
      for (int ct = 0; ct < 3; ++ct) {
        float4 w = *(const float4*)&sW[kk][ct * 64 + (tx << 2)];
        float wv[4] = {w.x, w.y, w.z, w.w};
        #pragma unroll
        for (int i = 0; i < 4; ++i)
          #pragma unroll
          for (int j = 0; j < 4; ++j)
            acc[i][ct * 4 + j] += av[i] * wv[j];
      }
    }
  }
  #pragma unroll
  for (int ct = 0; ct < 3; ++ct) {
    float o[4];
    #pragma unroll
    for (int j = 0; j < 4; ++j) {
      int col = ct * 64 + (tx << 2) + j;
      float bvv = b2[col];
      float s = 0.f;
      #pragma unroll
      for (int i = 0; i < 4; ++i) {
        float t = acc[i][ct * 4 + j] + bvv;
        s += LK(t);
      }
      o[j] = s;
    }
    float4 ov = {o[0], o[1], o[2], o[3]};
    *(float4*)(out + (size_t)gp * 192 + ct * 64 + (tx << 2)) = ov;
  }
}

// exact fp32 replica of stage2 for cols 0..2 ONLY (the KNN-feeding columns).
__global__ __launch_bounds__(256) void edge_exact3(
    const float* __restrict__ UV, const int* __restrict__ idx,
    const float* __restrict__ w2, const float* __restrict__ b2,
    float* __restrict__ out, int H1) {
  __shared__ float sw[252 * 4];
  int tid = threadIdx.x;
  for (int k = tid; k < H1; k += 256) {
    sw[k * 4 + 0] = w2[(size_t)k * 192 + 0];
    sw[k * 4 + 1] = w2[(size_t)k * 192 + 1];
    sw[k * 4 + 2] = w2[(size_t)k * 192 + 2];
    sw[k * 4 + 3] = 0.f;
  }
  __syncthreads();
  int p = blockIdx.x * 64 + (tid >> 2);   // chunk-local point
  int e = tid & 3;
  int bbase = (p >> 8) << 8;
  int j = bbase + idx[(size_t)p * 4 + e];
  int W2 = 2 * H1;
  const float* up = UV + (size_t)p * W2;
  const float* vp = UV + (size_t)j * W2 + H1;
  float a0 = 0.f, a1 = 0.f, a2 = 0.f;
  int k = 0;
  for (; k + 3 < H1; k += 4) {
    float4 u = *(const float4*)(up + k);
    float4 v = *(const float4*)(vp + k);
    float h0 = LK(u.x + v.x), h1 = LK(u.y + v.y);
    float h2 = LK(u.z + v.z), h3 = LK(u.w + v.w);
    float4 w0 = *(const float4*)&sw[(k + 0) * 4];
    float4 w1 = *(const float4*)&sw[(k + 1) * 4];
    float4 w2v = *(const float4*)&sw[(k + 2) * 4];
    float4 w3 = *(const float4*)&sw[(k + 3) * 4];
    a0 = __builtin_fmaf(h0, w0.x, a0); a1 = __builtin_fmaf(h0, w0.y, a1); a2 = __builtin_fmaf(h0, w0.z, a2);
    a0 = __builtin_fmaf(h1, w1.x, a0); a1 = __builtin_fmaf(h1, w1.y, a1); a2 = __builtin_fmaf(h1, w1.z, a2);
    a0 = __builtin_fmaf(h2, w2v.x, a0); a1 = __builtin_fmaf(h2, w2v.y, a1); a2 = __builtin_fmaf(h2, w2v.z, a2);
    a0 = __builtin_fmaf(h3, w3.x, a0); a1 = __builtin_fmaf(h3, w3.y, a1); a2 = __builtin_fmaf(h3, w3.z, a2);
  }
  for (; k < H1; ++k) {
    float h = LK(up[k] + vp[k]);
    a0 = __builtin_fmaf(h, sw[k * 4 + 0], a0);
    a1 = __builtin_fmaf(h, sw[k * 4 + 1], a1);
    a2 = __builtin_fmaf(h, sw[k * 4 + 2], a2);
  }
  float acc3[3] = {a0, a1, a2};
  #pragma unroll
  for (int c = 0; c < 3; ++c) {
    float t = acc3[c] + b2[c];
    float pc = LK(t);
    float q1 = __shfl_down(pc, 1);
    float q2 = __shfl_down(pc, 2);
    float q3 = __shfl_down(pc, 3);
    if (e == 0) {
      float s = ((pc + q1) + q2) + q3;   // e-ascending order, matches edge_stage2 epilogue
      out[(size_t)p * 192 + c] = s;
    }
  }
}

// ====================== fp16x3 MFMA path (noise-tolerant GEMMs) ======================

// Wp[n][k-octets]: [8 hi | 8 lo]; [wdiff | wbot] transposed. bcat = [b1|0]
__global__ void prep_wcatT(const float* __restrict__ w1, const float* __restrict__ b1,
                           int F, int H1, int Fpad, _Float16* __restrict__ Wp,
                           float* __restrict__ bcat) {
  int t = blockIdx.x * 256 + threadIdx.x;
  int NN = 2 * H1;
  if (t < NN * Fpad) {
    int n = t / Fpad, k = t - n * Fpad;
    float v = 0.f;
    if (k < F) {
      if (n < H1) v = w1[(size_t)k * H1 + n] - w1[(size_t)(F + k) * H1 + n];
      else        v = w1[(size_t)(F + k) * H1 + (n - H1)];
    }
    _Float16 h, l; dec2(v, h, l);
    size_t base = (size_t)n * 2 * Fpad + (size_t)(k >> 3) * 16 + (k & 7);
    Wp[base] = h; Wp[base + 8] = l;
  }
  if (t < NN) bcat[t] = (t < H1) ? b1[t] : 0.f;
}

__global__ void prep_wT(const float* __restrict__ W, int K, int N, int Kpad,
                        _Float16* __restrict__ Wp) {
  int t = blockIdx.x * 256 + threadIdx.x;
  if (t >= N * Kpad) return;
  int n = t / Kpad, k = t - n * Kpad;
  float v = (k < K) ? W[(size_t)k * N + n] : 0.f;
  _Float16 h, l; dec2(v, h, l);
  size_t base = (size_t)n * 2 * Kpad + (size_t)(k >> 3) * 16 + (k & 7);
  Wp[base] = h; Wp[base + 8] = l;
}

// fp16x3 MFMA GEMM. Block 128x128, 4 waves (2x2), K-step 32.
// PIPELINED (1-deep reg prefetch) + LDS-TRANSPOSE EPILOGUE (measured R7).
// CAT4: A is the concatenation [A0|A1|A2|A3], each 192 cols (fused nn1, K=768).
template<bool ACT_A, bool ACCUM, bool HAS_BIAS, bool XB, bool CAT4>
__global__ __launch_bounds__(256) void gemm3h(
    const float* __restrict__ A0, const float* __restrict__ A1,
    const float* __restrict__ A2, const float* __restrict__ A3, int w0,
    const _Float16* __restrict__ Wp, const float* __restrict__ bias,
    const float* __restrict__ X, const float* __restrict__ Wx,
    float* __restrict__ C, int M, int N, int K, int Kpad) {
  __shared__ _Float16 sAB[2 * 128 * 72];   // sA | sB ; reused as float sT[128][72]
  _Float16* sA = sAB;
  _Float16* sB = sAB + 128 * 72;
  float* sT = (float*)sAB;
  int tid = threadIdx.x;
  int m0 = blockIdx.y * 128, n0 = blockIdx.x * 128;
  int lane = tid & 63, wid = tid >> 6;
  int wy = wid >> 1, wx = wid & 1;
  int lm = lane & 15, lq = lane >> 4;
  int rA = tid >> 1, qA = (tid & 1) * 4;
  f32x4 acc[4][4];
  #pragma unroll
  for (int i = 0; i < 4; ++i)
    #pragma unroll
    for (int j = 0; j < 4; ++j) acc[i][j] = 0.f;

  float4 pa0, pa1, pa2, pa3, pb0, pb1, pb2, pb3;

#define LOADA_ONE(KL, DST)                                          \
  { int kl_ = (KL); float4 v_ = {0.f, 0.f, 0.f, 0.f};               \
    if (kl_ + 3 < wA) v_ = *(const float4*)(arow + kl_);            \
    else {                                                          \
      if (kl_ + 0 < wA) v_.x = arow[kl_ + 0];                       \
      if (kl_ + 1 < wA) v_.y = arow[kl_ + 1];                       \
      if (kl_ + 2 < wA) v_.z = arow[kl_ + 2]; }                     \
    DST = v_; }

#define LOAD_AB(K0)                                                 \
  { int k0_ = (K0);                                                 \
    const float* Ap; int kb, wA;                                    \
    if (CAT4) {                                                     \
      int s_ = k0_ / 192;                                           \
      Ap = (s_ == 0) ? A0 : (s_ == 1) ? A1 : (s_ == 2) ? A2 : A3;   \
      kb = k0_ - s_ * 192; wA = 192;                                \
    } else if (k0_ < w0) { Ap = A0; kb = k0_;      wA = w0; }       \
    else                 { Ap = A1; kb = k0_ - w0; wA = K - w0; }   \
    const float* arow = Ap + (size_t)(m0 + rA) * wA;                \
    LOADA_ONE(kb + (qA + 0) * 4, pa0)                               \
    LOADA_ONE(kb + (qA + 1) * 4, pa1)                               \
    LOADA_ONE(kb + (qA + 2) * 4, pa2)                               \
    LOADA_ONE(kb + (qA + 3) * 4, pa3)                               \
    int n_ = n0 + rA;                                               \
    const _Float16* src = Wp + (size_t)n_ * 2 * Kpad + (size_t)k0_ * 2; \
    float4 z_ = {0.f, 0.f, 0.f, 0.f};                               \
    if (n_ < N) {                                                   \
      pb0 = *(const float4*)(src + (qA + 0) * 8);                   \
      pb1 = *(const float4*)(src + (qA + 1) * 8);                   \
      pb2 = *(const float4*)(src + (qA + 2) * 8);                   \
      pb3 = *(const float4*)(src + (qA + 3) * 8);                   \
    } else { pb0 = z_; pb1 = z_; pb2 = z_; pb3 = z_; } }

#define ST_A(V, Q)                                                  \
  { float4 t_ = (V);                                                \
    if (ACT_A) { t_.x = LK(t_.x); t_.y = LK(t_.y);                  \
                 t_.z = LK(t_.z); t_.w = LK(t_.w); }                \
    _Float16 h0,h1,h2,h3,l0,l1,l2,l3;                               \
    dec2(t_.x,h0,l0); dec2(t_.y,h1,l1);                             \
    dec2(t_.z,h2,l2); dec2(t_.w,h3,l3);                             \
    int off_ = rA * 72 + ((Q) >> 1) * 16 + ((Q) & 1) * 4;           \
    f16x4 th; th[0]=h0; th[1]=h1; th[2]=h2; th[3]=h3;               \
    f16x4 tl; tl[0]=l0; tl[1]=l1; tl[2]=l2; tl[3]=l3;               \
    *(f16x4*)&sA[off_]     = th;                                    \
    *(f16x4*)&sA[off_ + 8] = tl; }

  LOAD_AB(0)

  for (int k0 = 0; k0 < Kpad; k0 += 32) {
    __syncthreads();
    ST_A(pa0, qA + 0)
    ST_A(pa1, qA + 1)
    ST_A(pa2, qA + 2)
    ST_A(pa3, qA + 3)
    *(float4*)&sB[rA * 72 + (qA + 0) * 8] = pb0;
    *(float4*)&sB[rA * 72 + (qA + 1) * 8] = pb1;
    *(float4*)&sB[rA * 72 + (qA + 2) * 8] = pb2;
    *(float4*)&sB[rA * 72 + (qA + 3) * 8] = pb3;
    if (k0 + 32 < Kpad) { LOAD_AB(k0 + 32) }
    __syncthreads();
    f16x8 af[4][2], bf[4][2];
    #pragma unroll
    for (int mt = 0; mt < 4; ++mt) {
      int row = wy * 64 + mt * 16 + lm;
      af[mt][0] = *(const f16x8*)&sA[row * 72 + lq * 16];
      af[mt][1] = *(const f16x8*)&sA[row * 72 + lq * 16 + 8];
    }
    #pragma unroll
    for (int nt = 0; nt < 4; ++nt) {
      int row = wx * 64 + nt * 16 + lm;
      bf[nt][0] = *(const f16x8*)&sB[row * 72 + lq * 16];
      bf[nt][1] = *(const f16x8*)&sB[row * 72 + lq * 16 + 8];
    }
    #pragma unroll
    for (int mt = 0; mt < 4; ++mt)
      #pragma unroll
      for (int nt = 0; nt < 4; ++nt) {
        acc[mt][nt] = __builtin_amdgcn_mfma_f32_16x16x32_f16(af[mt][0], bf[nt][0], acc[mt][nt], 0, 0, 0);
        acc[mt][nt] = __builtin_amdgcn_mfma_f32_16x16x32_f16(af[mt][0], bf[nt][1], acc[mt][nt], 0, 0, 0);
        acc[mt][nt] = __builtin_amdgcn_mfma_f32_16x16x32_f16(af[mt][1], bf[nt][0], acc[mt][nt], 0, 0, 0);
      }
  }
#undef LOADA_ONE
#undef LOAD_AB
#undef ST_A

  // ---- staged, coalesced epilogue: two wx-halves through LDS ----
  int rbase = tid >> 4;          // 0..15
  int c4 = (tid & 15) << 2;      // 0..60
  #pragma unroll
  for (int half = 0; half < 2; ++half) {
    __syncthreads();
    if (wx == half) {
      #pragma unroll
      for (int mt = 0; mt < 4; ++mt)
        #pragma unroll
        for (int nt = 0; nt < 4; ++nt)
          #pragma unroll
          for (int r = 0; r < 4; ++r)
            sT[(wy * 64 + mt * 16 + lq * 4 + r) * 72 + nt * 16 + lm] = acc[mt][nt][r];
    }
    __syncthreads();
    int n = n0 + half * 64 + c4;
    float bv[4] = {0.f, 0.f, 0.f, 0.f};
    if (HAS_BIAS || XB) {
      #pragma unroll
      for (int j = 0; j < 4; ++j) if (n + j < N) bv[j] = bias[n + j];
    }
    float wxv0[4], wxv1[4], wxv2[4], wxv3[4];
    if (XB) {
      #pragma unroll
      for (int j = 0; j < 4; ++j) {
        wxv0[j] = (n + j < N) ? Wx[n + j] : 0.f;
        wxv1[j] = (n + j < N) ? Wx[N + n + j] : 0.f;
        wxv2[j] = (n + j < N) ? Wx[2 * N + n + j] : 0.f;
        wxv3[j] = (n + j < N) ? Wx[3 * N + n + j] : 0.f;
      }
    }
    #pragma unroll
    for (int it = 0; it < 8; ++it) {
      int row = it * 16 + rbase;
      size_t m = (size_t)m0 + row;
      float4 t = *(const float4*)&sT[row * 72 + c4];
      float o[4] = {t.x, t.y, t.z, t.w};
      if (XB) {
        float4 xv = *(const float4*)(X + m * 4);
        #pragma unroll
        for (int j = 0; j < 4; ++j)
          o[j] = o[j] + bv[j] + (xv.x * wxv0[j] + xv.y * wxv1[j] + xv.z * wxv2[j] + xv.w * wxv3[j]);
      } else {
        #pragma unroll
        for (int j = 0; j < 4; ++j) o[j] += bv[j];
      }
      if (n + 3 < N) {
        float4* cp = (float4*)(C + m * N + n);
        if (ACCUM) { float4 c = *cp; o[0] += c.x; o[1] += c.y; o[2] += c.z; o[3] += c.w; }
        float4 ov = {o[0], o[1], o[2], o[3]};
        *cp = ov;
      } else {
        #pragma unroll
        for (int j = 0; j < 4; ++j) {
          if (n + j < N) {
            float v = o[j];
            size_t off = m * N + n + j;
            if (ACCUM) v += C[off];
            C[off] = v;
          }
        }
      }
    }
  }
}

// fp16x3 fused edge stage 2 (layers 3 cols + layer 4)
__global__ __launch_bounds__(256) void edge_stage2_m(
    const float* __restrict__ UV, const int* __restrict__ idx,
    const _Float16* __restrict__ Wp, const float* __restrict__ b2,
    float* __restrict__ out, int H1, int Kpad) {
  __shared__ _Float16 sH[64 * 72];
  __shared__ _Float16 sW[192 * 72];
  __shared__ int sJ[64];
  int tid = threadIdx.x;
  int g0 = blockIdx.x * 16;
  int bbase = (g0 >> 8) << 8;
  if (tid < 64) sJ[tid] = bbase + idx[(size_t)g0 * 4 + tid];
  int W2 = 2 * H1;
  int lane = tid & 63, w = tid >> 6;
  int lm = lane & 15, lq = lane >> 4;
  int rS = tid >> 2, qS = tid & 3;
  f32x4 acc[4][3];
  #pragma unroll
  for (int i = 0; i < 4; ++i)
    #pragma unroll
    for (int j = 0; j < 3; ++j) acc[i][j] = 0.f;

  for (int k0 = 0; k0 < Kpad; k0 += 32) {
    __syncthreads();
    {
      int gp_r = g0 + (rS >> 2);
      int jr = sJ[rS];
      const float* up = UV + (size_t)gp_r * W2;
      const float* vp = UV + (size_t)jr * W2 + H1;
      #pragma unroll
      for (int hf = 0; hf < 2; ++hf) {
        int k = k0 + qS * 8 + hf * 4;
        float4 u = {0.f,0.f,0.f,0.f}, v = {0.f,0.f,0.f,0.f};
        if (k + 3 < H1) { u = *(const float4*)(up + k); v = *(const float4*)(vp + k); }
        else {
          if (k + 0 < H1) { u.x = up[k+0]; v.x = vp[k+0]; }
          if (k + 1 < H1) { u.y = up[k+1]; v.y = vp[k+1]; }
          if (k + 2 < H1) { u.z = up[k+2]; v.z = vp[k+2]; }
        }
        float e0 = LK(u.x + v.x), e1 = LK(u.y + v.y), e2 = LK(u.z + v.z), e3 = LK(u.w + v.w);
        _Float16 h0,h1,h2,h3,l0,l1,l2,l3;
        dec2(e0,h0,l0); dec2(e1,h1,l1); dec2(e2,h2,l2); dec2(e3,h3,l3);
        int off = rS * 72 + qS * 16 + hf * 4;
        f16x4 th; th[0]=h0; th[1]=h1; th[2]=h2; th[3]=h3;
        f16x4 tl; tl[0]=l0; tl[1]=l1; tl[2]=l2; tl[3]=l3;
        *(f16x4*)&sH[off]     = th;
        *(f16x4*)&sH[off + 8] = tl;
      }
    }
    {
      const _Float16* src = Wp + (size_t)k0 * 2;
      #pragma unroll
      for (int p = 0; p < 6; ++p) {
        int e = tid + p * 256;
        int n = e >> 3, u = e & 7;
        *(float4*)&sW[n * 72 + u * 8] =
            *(const float4*)(src + (size_t)n * 2 * Kpad + u * 8);
      }
    }
    __syncthreads();
    f16x8 af[4][2], bf[3][2];
    #pragma unroll
    for (int mt = 0; mt < 4; ++mt) {
      int row = mt * 16 + lm;
      af[mt][0] = *(const f16x8*)&sH[row * 72 + lq * 16];
      af[mt][1] = *(const f16x8*)&sH[row * 72 + lq * 16 + 8];
    }
    #pragma unroll
    for (int t3 = 0; t3 < 3; ++t3) {
      int row = (w * 3 + t3) * 16 + lm;
      bf[t3][0] = *(const f16x8*)&sW[row * 72 + lq * 16];
      bf[t3][1] = *(const f16x8*)&sW[row * 72 + lq * 16 + 8];
    }
    #pragma unroll
    for (int mt = 0; mt < 4; ++mt)
      #pragma unroll
      for (int t3 = 0; t3 < 3; ++t3) {
        acc[mt][t3] = __builtin_amdgcn_mfma_f32_16x16x32_f16(af[mt][0], bf[t3][0], acc[mt][t3], 0, 0, 0);
        acc[mt][t3] = __builtin_amdgcn_mfma_f32_16x16x32_f16(af[mt][0], bf[t3][1], acc[mt][t3], 0, 0, 0);
        acc[mt][t3] = __builtin_amdgcn_mfma_f32_16x16x32_f16(af[mt][1], bf[t3][0], acc[mt][t3], 0, 0, 0);
      }
  }
  #pragma unroll
  for (int mt = 0; mt < 4; ++mt) {
    int gp = g0 + mt * 4 + lq;
    #pragma unroll
    for (int t3 = 0; t3 < 3; ++t3) {
      int col = (w * 3 + t3) * 16 + lm;
      float bv = b2[col];
      float s = 0.f;
      #pragma unroll
      for (int r = 0; r < 4; ++r) s += LK(acc[mt][t3][r] + bv);
      out[(size_t)gp * 192 + col] = s;
    }
  }
}

// ---------------- pooling ----------------
__global__ void pool_kernel(const float* __restrict__ h, float* __restrict__ pooled) {
  int b = blockIdx.x, ch = threadIdx.x;  // 192 threads
  const float* p = h + (size_t)b * N_ * 192 + ch;
  float mx = -INFINITY, mn = INFINITY, sm = 0.f;
  for (int n = 0; n < N_; ++n) {
    float v = p[(size_t)n * 192];
    mx = fmaxf(mx, v); mn = fminf(mn, v); sm += v;
  }
  float* o = pooled + (size_t)b * 768;
  o[ch]       = LK(mx);
  o[192 + ch] = LK(mn);
  o[384 + ch] = LK(sm);
  o[576 + ch] = LK(sm * (1.f / 256.f));
}

// ---------------- head ----------------
__global__ void head_kernel(const float* __restrict__ pooled,
                            const float* __restrict__ w3, const float* __restrict__ b3,
                            const float* __restrict__ w4, const float* __restrict__ b4,
                            float* __restrict__ out) {
  __shared__ float sp[768];
  __shared__ float st[96];
  int b = blockIdx.x, t = threadIdx.x;   // 128 threads
  for (int c = t; c < 768; c += 128) sp[c] = pooled[(size_t)b * 768 + c];
  __syncthreads();
  if (t < 96) {
    float s = b3[t];
    for (int r = 0; r < 768; ++r) s += sp[r] * w3[(size_t)r * 96 + t];
    s = LK(s);
    st[t] = s * w4[t];
  }
  __syncthreads();
  if (t == 0) {
    float s = b4[0];
    for (int i = 0; i < 96; ++i) s += st[i];
    out[b] = s;
  }
}

extern "C" void kernel_launch(void* const* d_in, const int* in_sizes, int n_in,
                              void* d_out, int out_size, void* d_ws, size_t ws_size,
                              hipStream_t stream) {
  (void)in_sizes; (void)n_in; (void)out_size;
  const float* x = (const float*)d_in[0];
  const float* P[25];
  for (int i = 0; i < 25; ++i) P[i] = (const float*)d_in[i];

  // Fused-nn1 layout needs a & b & c & d live simultaneously: 304,353,280 B.
  constexpr size_t SZ_IDX = 1048576, SZ_FEAT = 50331648, SZ_H1 = 66060288;
  constexpr size_t SZ_UV = 33030144, SZ_POOL = 786432, SZ_W = 1048576;
  constexpr size_t FUSED_WS = SZ_IDX + 4 * SZ_FEAT + SZ_H1 + SZ_UV + SZ_POOL + 2 * SZ_W + 4096;
  const bool fused = (ws_size >= FUSED_WS);

  char* ws = (char*)d_ws;
  int*   idx; float *A, *Bb, *Cb, *Db, *h1, *UV, *pooled; char *Wsl1, *Wsl2; float* bcat;
  if (fused) {
    size_t o = 0;
    idx    = (int*)  (ws + o); o += SZ_IDX;
    A      = (float*)(ws + o); o += SZ_FEAT;
    Bb     = (float*)(ws + o); o += SZ_FEAT;
    Cb     = (float*)(ws + o); o += SZ_FEAT;
    Db     = (float*)(ws + o); o += SZ_FEAT;
    h1     = (float*)(ws + o); o += SZ_H1;
    UV     = (float*)(ws + o); o += SZ_UV;
    pooled = (float*)(ws + o); o += SZ_POOL;
    Wsl1   =         (ws + o); o += SZ_W;
    Wsl2   =         (ws + o); o += SZ_W;
    bcat   = (float*)(ws + o);
  } else {
    // exact measured-R7 layout (peak ~203.7 MB)
    idx    = (int*)  (ws + 0);
    A      = (float*)(ws + 1048576);
    Bb     = (float*)(ws + 51380224);
    Cb     = A;  Db = Bb;                    // aliases (c overwrites a, d overwrites b)
    h1     = (float*)(ws + 101711872);
    UV     = (float*)(ws + 167772160);
    pooled = (float*)(ws + 200802304);
    Wsl1   =         (ws + 201588736);
    Wsl2   =         (ws + 202637312);
    bcat   = (float*)(ws + 203685888);
  }

  float*    wcat = (float*)   Wsl1;
  _Float16* WB1  = (_Float16*)Wsl1;
  _Float16* WB2  = (_Float16*)Wsl2;

  // ---- fp32 edge layer (layers 1,2: fully bit-exact) ----
  auto edge_layer_f32 = [&](const float* src, int F, int H1,
                            const float* w1, const float* b1,
                            const float* w2, const float* b2, float* dst) {
    knn_kernel<<<B_, N_, 0, stream>>>(src, F, idx);
    prep_uvw<<<(F * H1 + 255) / 256, 256, 0, stream>>>(w1, b1, F, H1, wcat, bcat);
    int W2 = 2 * H1;
    dim3 gUV((W2 + 63) / 64, CHUNK_ROWS / 128);
    for (int cb = 0; cb < B_; cb += CHUNK_B) {
      size_t base = (size_t)cb * N_;
      gemm_f32<false, false, true><<<gUV, 256, 0, stream>>>(src + base * F, wcat, bcat, UV, CHUNK_ROWS, W2, F);
      edge_stage2<<<CHUNK_ROWS / 16, 256, 0, stream>>>(UV, idx + base * 4, w2, b2, dst + base * 192, H1);
    }
  };

  // ---- fp16x3 edge layer (layer 4: output feeds no KNN) ----
  auto edge_layer_f16 = [&](const float* src, int F, int H1,
                            const float* w1, const float* b1,
                            const float* w2, const float* b2, float* dst) {
    int Fpad = (F + 31) & ~31;
    int KpadW2 = (H1 + 31) & ~31;
    int NN = 2 * H1;
    knn_kernel<<<B_, N_, 0, stream>>>(src, F, idx);
    prep_wcatT<<<(NN * Fpad + 255) / 256, 256, 0, stream>>>(w1, b1, F, H1, Fpad, WB1, bcat);
    prep_wT<<<(192 * KpadW2 + 255) / 256, 256, 0, stream>>>(w2, H1, 192, KpadW2, WB2);
    dim3 gUV((NN + 127) / 128, CHUNK_ROWS / 128);
    for (int cb = 0; cb < B_; cb += CHUNK_B) {
      size_t base = (size_t)cb * N_;
      gemm3h<false, false, true, false, false><<<gUV, 256, 0, stream>>>(
          src + base * F, src + base * F, nullptr, nullptr, F, WB1, bcat, nullptr, nullptr, UV, CHUNK_ROWS, NN, F, Fpad);
      edge_stage2_m<<<CHUNK_ROWS / 16, 256, 0, stream>>>(
          UV, idx + base * 4, WB2, b2, dst + base * 192, H1, KpadW2);
    }
  };

  // ---- hybrid c-layer: fp32 UV (exact) + fp16x3 stage2 + exact fp32 cols 0-2 ----
  auto edge_layer_c = [&](const float* src, float* dst) {
    const float* w1 = P[9]; const float* b1 = P[10];
    const float* w2 = P[11]; const float* b2 = P[12];
    int F = 192, H1 = 252, W2 = 504, KpadW2 = 256;
    knn_kernel<<<B_, N_, 0, stream>>>(src, F, idx);
    prep_uvw<<<(F * H1 + 255) / 256, 256, 0, stream>>>(w1, b1, F, H1, wcat, bcat);
    prep_wT<<<(192 * KpadW2 + 255) / 256, 256, 0, stream>>>(w2, H1, 192, KpadW2, WB2);
    dim3 gUV((W2 + 63) / 64, CHUNK_ROWS / 128);
    for (int cb = 0; cb < B_; cb += CHUNK_B) {
      size_t base = (size_t)cb * N_;
      gemm_f32<false, false, true><<<gUV, 256, 0, stream>>>(src + base * F, wcat, bcat, UV, CHUNK_ROWS, W2, F);
      edge_stage2_m<<<CHUNK_ROWS / 16, 256, 0, stream>>>(UV, idx + base * 4, WB2, b2, dst + base * 192, H1, KpadW2);
      edge_exact3<<<CHUNK_ROWS / 64, 256, 0, stream>>>(UV, idx + base * 4, w2, b2, dst + base * 192, H1);
    }
  };

  // a = edge(x) -> A ; b = edge(a) -> Bb      [fp32 exact: feed KNN 2,3 via full GEMMs]
  edge_layer_f32(x,  4,   96,  P[1], P[2], P[3], P[4], A);
  edge_layer_f32(A,  192, 252, P[5], P[6], P[7], P[8], Bb);

  if (fused) {
    // c = edge(b) -> Cb ; d = edge(c) -> Db  (a,b stay live)
    edge_layer_c(Bb, Cb);
    edge_layer_f16(Cb, 192, 252, P[13], P[14], P[15], P[16], Db);
    // h1 = [x|a|b|c|d] @ nn1w + nn1b in ONE K=768 pass (x-part in XB epilogue)
    prep_wT<<<(252 * 768 + 255) / 256, 256, 0, stream>>>(P[17] + 4 * 252, 768, 252, 768, WB1);
    dim3 g(2, BN / 128);
    gemm3h<false, false, true, true, true><<<g, 256, 0, stream>>>(
        A, Bb, Cb, Db, 0, WB1, P[18], x, P[17], h1, BN, 252, 768, 768);
  } else {
    // h1 = [x,a,b] @ nn1w[0:388] + nn1b
    prep_wT<<<(252 * 384 + 255) / 256, 256, 0, stream>>>(P[17] + 4 * 252, 384, 252, 384, WB1);
    dim3 g(2, BN / 128);
    gemm3h<false, false, true, true, false><<<g, 256, 0, stream>>>(
        A, Bb, nullptr, nullptr, 192, WB1, P[18], x, P[17], h1, BN, 252, 384, 384);
    // c = edge(b) -> A (overwrites a) ; d = edge(c) -> Bb
    edge_layer_c(Bb, Cb);
    edge_layer_f16(Cb, 192, 252, P[13], P[14], P[15], P[16], Db);
    // h1 += [c,d] @ nn1w[388:772]
    prep_wT<<<(252 * 384 + 255) / 256, 256, 0, stream>>>(P[17] + (size_t)388 * 252, 384, 252, 384, WB1);
    gemm3h<false, true, false, false, false><<<g, 256, 0, stream>>>(
        Cb, Db, nullptr, nullptr, 192, WB1, nullptr, nullptr, nullptr, h1, BN, 252, 384, 384);
  }

  // nn2: h2 = leaky(h1) @ nn2w + nn2b -> A   [fp16x3]
  {
    prep_wT<<<(192 * 256 + 255) / 256, 256, 0, stream>>>(P[19], 252, 192, 256, WB2);
    dim3 g(2, BN / 128);
    gemm3h<true, false, true, false, false><<<g, 256, 0, stream>>>(
        h1, h1, nullptr, nullptr, 252, WB2, P[20], nullptr, nullptr, A, BN, 192, 252, 256);
  }

  pool_kernel<<<B_, 192, 0, stream>>>(A, pooled);
  head_kernel<<<B_, 128, 0, stream>>>(pooled, P[21], P[22], P[23], P[24], (float*)d_out);
}

// Round 12
// 1971.243 us; speedup vs baseline: 1.0233x; 1.0233x over previous
//
#include <hip/hip_runtime.h>
#include <cstdint>
#include <cstddef>

#define LK(x) ((x) > 0.f ? (x) : 0.01f * (x))

typedef _Float16 f16x8 __attribute__((ext_vector_type(8)));
typedef _Float16 f16x4 __attribute__((ext_vector_type(4)));
typedef float f32x4 __attribute__((ext_vector_type(4)));

constexpr int B_ = 256;
constexpr int N_ = 256;
constexpr int BN = B_ * N_;
constexpr int CHUNK_B = 64;                 // batches per UV chunk
constexpr int CHUNK_ROWS = CHUNK_B * N_;    // 16384 rows

// fp16 2-way split (for fp16x3 path)
__device__ inline void dec2(float v, _Float16& h, _Float16& l) {
  _Float16 hh = (_Float16)v;
  h = hh;
  l = (_Float16)(v - (float)hh);
}

// ---------------- KNN: one block per batch, one thread per point ----------------
__global__ void knn_kernel(const float* __restrict__ feat, int F, int* __restrict__ idxout) {
  __shared__ float px[N_], py[N_], pz[N_];
  int b = blockIdx.x, t = threadIdx.x;
  const float* row = feat + ((size_t)b * N_ + t) * F;
  px[t] = row[0]; py[t] = row[1]; pz[t] = row[2];
  __syncthreads();
  float x = px[t], y = py[t], z = pz[t];
  float bd0 = INFINITY, bd1 = INFINITY, bd2 = INFINITY, bd3 = INFINITY;
  int bi0 = 0, bi1 = 0, bi2 = 0, bi3 = 0;
  for (int j = 0; j < N_; ++j) {
    #pragma clang fp contract(off)
    float dx = x - px[j], dy = y - py[j], dz = z - pz[j];
    float d = (dx * dx + dy * dy) + dz * dz;
    if (j == t) continue;
    if (d < bd3) {
      if (d < bd2) {
        bd3 = bd2; bi3 = bi2;
        if (d < bd1) {
          bd2 = bd1; bi2 = bi1;
          if (d < bd0) { bd1 = bd0; bi1 = bi0; bd0 = d; bi0 = j; }
          else         { bd1 = d; bi1 = j; }
        } else         { bd2 = d; bi2 = j; }
      } else           { bd3 = d; bi3 = j; }
    }
  }
  int* o = idxout + ((size_t)b * N_ + t) * 4;
  o[0] = bi0; o[1] = bi1; o[2] = bi2; o[3] = bi3;
}

// ============================ fp32 path (bit-exact chain) ============================

// wcat = [w1_top - w1_bot | w1_bot] (F x 2H1), bcat = [b1 | 0]
__global__ void prep_uvw(const float* __restrict__ w1, const float* __restrict__ b1,
                         int F, int H1, float* __restrict__ wcat, float* __restrict__ bcat) {
  int t = blockIdx.x * 256 + threadIdx.x;
  int FH = F * H1;
  if (t < FH) {
    int k = t / H1, c = t - k * H1;
    float top = w1[(size_t)k * H1 + c];
    float bot = w1[(size_t)(F + k) * H1 + c];
    wcat[(size_t)k * 2 * H1 + c]      = top - bot;
    wcat[(size_t)k * 2 * H1 + H1 + c] = bot;
  }
  if (t < H1) { bcat[t] = b1[t]; bcat[H1 + t] = 0.f; }
}

// fp32 GEMM: 128x64 tile, BK=16, 256 thr, 8x4 micro (proven R3 config)
template<bool ACT_A, bool ACCUM, bool HAS_BIAS>
__global__ __launch_bounds__(256) void gemm_f32(
    const float* __restrict__ A, const float* __restrict__ W,
    const float* __restrict__ bias, float* __restrict__ C,
    int M, int N, int K) {
  __shared__ float sA[16][132];
  __shared__ float sW[16][68];
  int tid = threadIdx.x;
  int m0 = blockIdx.y * 128;
  int n0 = blockIdx.x * 64;
  int kkA = tid & 15, mA = tid >> 4;
  int nW = tid & 63, kW = tid >> 6;
  int ty = tid >> 4, tx = tid & 15;
  float acc[8][4] = {};
  for (int k0 = 0; k0 < K; k0 += 16) {
    int kg = k0 + kkA;
    #pragma unroll
    for (int i = 0; i < 8; ++i) {
      int m = mA + i * 16;
      float v = 0.f;
      if (kg < K) {
        v = A[(size_t)(m0 + m) * K + kg];
        if (ACT_A) v = LK(v);
      }
      sA[kkA][m] = v;
    }
    #pragma unroll
    for (int q = 0; q < 4; ++q) {
      int kk = kW + q * 4;
      int kgw = k0 + kk, n = n0 + nW;
      float v = 0.f;
      if (kgw < K && n < N) v = W[(size_t)kgw * N + n];
      sW[kk][nW] = v;
    }
    __syncthreads();
    #pragma unroll
    for (int kk = 0; kk < 16; ++kk) {
      float4 a0 = *(const float4*)&sA[kk][ty * 8];
      float4 a1 = *(const float4*)&sA[kk][ty * 8 + 4];
      float4 w  = *(const float4*)&sW[kk][tx * 4];
      float av[8] = {a0.x, a0.y, a0.z, a0.w, a1.x, a1.y, a1.z, a1.w};
      float wv[4] = {w.x, w.y, w.z, w.w};
      #pragma unroll
      for (int i = 0; i < 8; ++i)
        #pragma unroll
        for (int j = 0; j < 4; ++j)
          acc[i][j] += av[i] * wv[j];
    }
    __syncthreads();
  }
  int n = n0 + tx * 4;
  float bv[4] = {0.f, 0.f, 0.f, 0.f};
  if (HAS_BIAS) {
    #pragma unroll
    for (int j = 0; j < 4; ++j) if (n + j < N) bv[j] = bias[n + j];
  }
  #pragma unroll
  for (int i = 0; i < 8; ++i) {
    size_t m = (size_t)(m0 + ty * 8 + i);
    if (n + 3 < N) {
      float4 o;
      o.x = acc[i][0] + bv[0]; o.y = acc[i][1] + bv[1];
      o.z = acc[i][2] + bv[2]; o.w = acc[i][3] + bv[3];
      float4* cp = (float4*)(C + m * N + n);
      if (ACCUM) { float4 c = *cp; o.x += c.x; o.y += c.y; o.z += c.z; o.w += c.w; }
      *cp = o;
    } else {
      #pragma unroll
      for (int j = 0; j < 4; ++j) {
        if (n + j < N) {
          float v = acc[i][j] + bv[j];
          size_t off = m * N + n + j;
          if (ACCUM) v += C[off];
          C[off] = v;
        }
      }
    }
  }
}

// fp32 fused edge stage 2, K-tiled (proven 16-pt version) — layers 1,2
__global__ __launch_bounds__(256) void edge_stage2(
    const float* __restrict__ UV, const int* __restrict__ idx,
    const float* __restrict__ w2, const float* __restrict__ b2,
    float* __restrict__ out, int H1) {
  __shared__ float sH[16][68];
  __shared__ float sW[16][196];
  __shared__ int sJ[64];
  int tid = threadIdx.x;
  int g0 = blockIdx.x * 16;
  int bbase = (g0 >> 8) << 8;
  if (tid < 64) sJ[tid] = bbase + idx[(size_t)g0 * 4 + tid];
  int W2 = H1 * 2;
  int r = tid >> 2, seg = tid & 3;
  int gp_r = g0 + (r >> 2);
  int ty = tid >> 4, tx = tid & 15;
  int gp = g0 + ty;
  float acc[4][12] = {};
  int nKt = (H1 + 15) >> 4;
  for (int kt = 0; kt < nKt; ++kt) {
    int k0 = kt << 4;
    __syncthreads();
    {
      int c = k0 + (seg << 2);
      const float* up = UV + (size_t)gp_r * W2 + c;
      const float* vp = UV + (size_t)sJ[r] * W2 + H1 + c;
      float u[4], v[4];
      if (c + 3 < H1) {
        float4 uu = *(const float4*)up; float4 vv = *(const float4*)vp;
        u[0] = uu.x; u[1] = uu.y; u[2] = uu.z; u[3] = uu.w;
        v[0] = vv.x; v[1] = vv.y; v[2] = vv.z; v[3] = vv.w;
      } else {
        #pragma unroll
        for (int j = 0; j < 4; ++j) {
          u[j] = (c + j < H1) ? up[j] : 0.f;
          v[j] = (c + j < H1) ? vp[j] : 0.f;
        }
      }
      #pragma unroll
      for (int j = 0; j < 4; ++j) {
        float t = u[j] + v[j];
        sH[(seg << 2) + j][r] = (c + j < H1) ? LK(t) : 0.f;
      }
    }
    #pragma unroll
    for (int p = 0; p < 3; ++p) {
      int q = tid + (p << 8);
      int kk = q / 48;
      int c4 = q - kk * 48;
      int k = k0 + kk;
      float4 wv = {0.f, 0.f, 0.f, 0.f};
      if (k < H1) wv = *(const float4*)(w2 + (size_t)k * 192 + (c4 << 2));
      *(float4*)&sW[kk][c4 << 2] = wv;
    }
    __syncthreads();
    #pragma unroll
    for (int kk = 0; kk < 16; ++kk) {
      float4 a = *(const float4*)&sH[kk][ty << 2];
      float av[4] = {a.x, a.y, a.z, a.w};
      #pragma unroll
      for (int ct = 0; ct < 3; ++ct) {
        float4 w = *(const float4*)&sW[kk][ct * 64 + (tx << 2)];
        float wv[4] = {w.x, w.y, w.z, w.w};
        #pragma unroll
        for (int i = 0; i < 4; ++i)
          #pragma unroll
          for (int j = 0; j < 4; ++j)
            acc[i][ct * 4 + j] += av[i] * wv[j];
      }
    }
  }
  #pragma unroll
  for (int ct = 0; ct < 3; ++ct) {
    float o[4];
    #pragma unroll
    for (int j = 0; j < 4; ++j) {
      int col = ct * 64 + (tx << 2) + j;
      float bvv = b2[col];
      float s = 0.f;
      #pragma unroll
      for (int i = 0; i < 4; ++i) {
        float t = acc[i][ct * 4 + j] + bvv;
        s += LK(t);
      }
      o[j] = s;
    }
    float4 ov = {o[0], o[1], o[2], o[3]};
    *(float4*)(out + (size_t)gp * 192 + ct * 64 + (tx << 2)) = ov;
  }
}

// exact fp32 replica of stage2 for cols 0..2 ONLY (the KNN-feeding columns).
__global__ __launch_bounds__(256) void edge_exact3(
    const float* __restrict__ UV, const int* __restrict__ idx,
    const float* __restrict__ w2, const float* __restrict__ b2,
    float* __restrict__ out, int H1) {
  __shared__ float sw[252 * 4];
  int tid = threadIdx.x;
  for (int k = tid; k < H1; k += 256) {
    sw[k * 4 + 0] = w2[(size_t)k * 192 + 0];
    sw[k * 4 + 1] = w2[(size_t)k * 192 + 1];
    sw[k * 4 + 2] = w2[(size_t)k * 192 + 2];
    sw[k * 4 + 3] = 0.f;
  }
  __syncthreads();
  int p = blockIdx.x * 64 + (tid >> 2);   // chunk-local point
  int e = tid & 3;
  int bbase = (p >> 8) << 8;
  int j = bbase + idx[(size_t)p * 4 + e];
  int W2 = 2 * H1;
  const float* up = UV + (size_t)p * W2;
  const float* vp = UV + (size_t)j * W2 + H1;
  float a0 = 0.f, a1 = 0.f, a2 = 0.f;
  int k = 0;
  for (; k + 3 < H1; k += 4) {
    float4 u = *(const float4*)(up + k);
    float4 v = *(const float4*)(vp + k);
    float h0 = LK(u.x + v.x), h1 = LK(u.y + v.y);
    float h2 = LK(u.z + v.z), h3 = LK(u.w + v.w);
    float4 w0 = *(const float4*)&sw[(k + 0) * 4];
    float4 w1 = *(const float4*)&sw[(k + 1) * 4];
    float4 w2v = *(const float4*)&sw[(k + 2) * 4];
    float4 w3 = *(const float4*)&sw[(k + 3) * 4];
    a0 = __builtin_fmaf(h0, w0.x, a0); a1 = __builtin_fmaf(h0, w0.y, a1); a2 = __builtin_fmaf(h0, w0.z, a2);
    a0 = __builtin_fmaf(h1, w1.x, a0); a1 = __builtin_fmaf(h1, w1.y, a1); a2 = __builtin_fmaf(h1, w1.z, a2);
    a0 = __builtin_fmaf(h2, w2v.x, a0); a1 = __builtin_fmaf(h2, w2v.y, a1); a2 = __builtin_fmaf(h2, w2v.z, a2);
    a0 = __builtin_fmaf(h3, w3.x, a0); a1 = __builtin_fmaf(h3, w3.y, a1); a2 = __builtin_fmaf(h3, w3.z, a2);
  }
  for (; k < H1; ++k) {
    float h = LK(up[k] + vp[k]);
    a0 = __builtin_fmaf(h, sw[k * 4 + 0], a0);
    a1 = __builtin_fmaf(h, sw[k * 4 + 1], a1);
    a2 = __builtin_fmaf(h, sw[k * 4 + 2], a2);
  }
  float acc3[3] = {a0, a1, a2};
  #pragma unroll
  for (int c = 0; c < 3; ++c) {
    float t = acc3[c] + b2[c];
    float pc = LK(t);
    float q1 = __shfl_down(pc, 1);
    float q2 = __shfl_down(pc, 2);
    float q3 = __shfl_down(pc, 3);
    if (e == 0) {
      float s = ((pc + q1) + q2) + q3;   // e-ascending order, matches edge_stage2 epilogue
      out[(size_t)p * 192 + c] = s;
    }
  }
}

// ====================== fp16x3 MFMA path (noise-tolerant GEMMs) ======================

// Wp[n][k-octets]: [8 hi | 8 lo]; [wdiff | wbot] transposed. bcat = [b1|0]
__global__ void prep_wcatT(const float* __restrict__ w1, const float* __restrict__ b1,
                           int F, int H1, int Fpad, _Float16* __restrict__ Wp,
                           float* __restrict__ bcat) {
  int t = blockIdx.x * 256 + threadIdx.x;
  int NN = 2 * H1;
  if (t < NN * Fpad) {
    int n = t / Fpad, k = t - n * Fpad;
    float v = 0.f;
    if (k < F) {
      if (n < H1) v = w1[(size_t)k * H1 + n] - w1[(size_t)(F + k) * H1 + n];
      else        v = w1[(size_t)(F + k) * H1 + (n - H1)];
    }
    _Float16 h, l; dec2(v, h, l);
    size_t base = (size_t)n * 2 * Fpad + (size_t)(k >> 3) * 16 + (k & 7);
    Wp[base] = h; Wp[base + 8] = l;
  }
  if (t < NN) bcat[t] = (t < H1) ? b1[t] : 0.f;
}

__global__ void prep_wT(const float* __restrict__ W, int K, int N, int Kpad,
                        _Float16* __restrict__ Wp) {
  int t = blockIdx.x * 256 + threadIdx.x;
  if (t >= N * Kpad) return;
  int n = t / Kpad, k = t - n * Kpad;
  float v = (k < K) ? W[(size_t)k * N + n] : 0.f;
  _Float16 h, l; dec2(v, h, l);
  size_t base = (size_t)n * 2 * Kpad + (size_t)(k >> 3) * 16 + (k & 7);
  Wp[base] = h; Wp[base + 8] = l;
}

// fp16x3 MFMA GEMM. Block 128x128, 4 waves (2x2), K-step 32.
// PIPELINED (1-deep reg prefetch) + LDS-TRANSPOSE EPILOGUE (measured R7).
// CAT4: A is the concatenation [A0|A1|A2|A3], each 192 cols (fused nn1, K=768).
template<bool ACT_A, bool ACCUM, bool HAS_BIAS, bool XB, bool CAT4>
__global__ __launch_bounds__(256) void gemm3h(
    const float* __restrict__ A0, const float* __restrict__ A1,
    const float* __restrict__ A2, const float* __restrict__ A3, int w0,
    const _Float16* __restrict__ Wp, const float* __restrict__ bias,
    const float* __restrict__ X, const float* __restrict__ Wx,
    float* __restrict__ C, int M, int N, int K, int Kpad) {
  __shared__ _Float16 sAB[2 * 128 * 72];   // sA | sB ; reused as float sT[128][72]
  _Float16* sA = sAB;
  _Float16* sB = sAB + 128 * 72;
  float* sT = (float*)sAB;
  int tid = threadIdx.x;
  int m0 = blockIdx.y * 128, n0 = blockIdx.x * 128;
  int lane = tid & 63, wid = tid >> 6;
  int wy = wid >> 1, wx = wid & 1;
  int lm = lane & 15, lq = lane >> 4;
  int rA = tid >> 1, qA = (tid & 1) * 4;
  f32x4 acc[4][4];
  #pragma unroll
  for (int i = 0; i < 4; ++i)
    #pragma unroll
    for (int j = 0; j < 4; ++j) acc[i][j] = 0.f;

  float4 pa0, pa1, pa2, pa3, pb0, pb1, pb2, pb3;

#define LOADA_ONE(KL, DST)                                          \
  { int kl_ = (KL); float4 v_ = {0.f, 0.f, 0.f, 0.f};               \
    if (kl_ + 3 < wA) v_ = *(const float4*)(arow + kl_);            \
    else {                                                          \
      if (kl_ + 0 < wA) v_.x = arow[kl_ + 0];                       \
      if (kl_ + 1 < wA) v_.y = arow[kl_ + 1];                       \
      if (kl_ + 2 < wA) v_.z = arow[kl_ + 2]; }                     \
    DST = v_; }

#define LOAD_AB(K0)                                                 \
  { int k0_ = (K0);                                                 \
    const float* Ap; int kb, wA;                                    \
    if (CAT4) {                                                     \
      int s_ = k0_ / 192;                                           \
      Ap = (s_ == 0) ? A0 : (s_ == 1) ? A1 : (s_ == 2) ? A2 : A3;   \
      kb = k0_ - s_ * 192; wA = 192;                                \
    } else if (k0_ < w0) { Ap = A0; kb = k0_;      wA = w0; }       \
    else                 { Ap = A1; kb = k0_ - w0; wA = K - w0; }   \
    const float* arow = Ap + (size_t)(m0 + rA) * wA;                \
    LOADA_ONE(kb + (qA + 0) * 4, pa0)                               \
    LOADA_ONE(kb + (qA + 1) * 4, pa1)                               \
    LOADA_ONE(kb + (qA + 2) * 4, pa2)                               \
    LOADA_ONE(kb + (qA + 3) * 4, pa3)                               \
    int n_ = n0 + rA;                                               \
    const _Float16* src = Wp + (size_t)n_ * 2 * Kpad + (size_t)k0_ * 2; \
    float4 z_ = {0.f, 0.f, 0.f, 0.f};                               \
    if (n_ < N) {                                                   \
      pb0 = *(const float4*)(src + (qA + 0) * 8);                   \
      pb1 = *(const float4*)(src + (qA + 1) * 8);                   \
      pb2 = *(const float4*)(src + (qA + 2) * 8);                   \
      pb3 = *(const float4*)(src + (qA + 3) * 8);                   \
    } else { pb0 = z_; pb1 = z_; pb2 = z_; pb3 = z_; } }

#define ST_A(V, Q)                                                  \
  { float4 t_ = (V);                                                \
    if (ACT_A) { t_.x = LK(t_.x); t_.y = LK(t_.y);                  \
                 t_.z = LK(t_.z); t_.w = LK(t_.w); }                \
    _Float16 h0,h1,h2,h3,l0,l1,l2,l3;                               \
    dec2(t_.x,h0,l0); dec2(t_.y,h1,l1);                             \
    dec2(t_.z,h2,l2); dec2(t_.w,h3,l3);                             \
    int off_ = rA * 72 + ((Q) >> 1) * 16 + ((Q) & 1) * 4;           \
    f16x4 th; th[0]=h0; th[1]=h1; th[2]=h2; th[3]=h3;               \
    f16x4 tl; tl[0]=l0; tl[1]=l1; tl[2]=l2; tl[3]=l3;               \
    *(f16x4*)&sA[off_]     = th;                                    \
    *(f16x4*)&sA[off_ + 8] = tl; }

  LOAD_AB(0)

  for (int k0 = 0; k0 < Kpad; k0 += 32) {
    __syncthreads();
    ST_A(pa0, qA + 0)
    ST_A(pa1, qA + 1)
    ST_A(pa2, qA + 2)
    ST_A(pa3, qA + 3)
    *(float4*)&sB[rA * 72 + (qA + 0) * 8] = pb0;
    *(float4*)&sB[rA * 72 + (qA + 1) * 8] = pb1;
    *(float4*)&sB[rA * 72 + (qA + 2) * 8] = pb2;
    *(float4*)&sB[rA * 72 + (qA + 3) * 8] = pb3;
    if (k0 + 32 < Kpad) { LOAD_AB(k0 + 32) }
    __syncthreads();
    f16x8 af[4][2], bf[4][2];
    #pragma unroll
    for (int mt = 0; mt < 4; ++mt) {
      int row = wy * 64 + mt * 16 + lm;
      af[mt][0] = *(const f16x8*)&sA[row * 72 + lq * 16];
      af[mt][1] = *(const f16x8*)&sA[row * 72 + lq * 16 + 8];
    }
    #pragma unroll
    for (int nt = 0; nt < 4; ++nt) {
      int row = wx * 64 + nt * 16 + lm;
      bf[nt][0] = *(const f16x8*)&sB[row * 72 + lq * 16];
      bf[nt][1] = *(const f16x8*)&sB[row * 72 + lq * 16 + 8];
    }
    #pragma unroll
    for (int mt = 0; mt < 4; ++mt)
      #pragma unroll
      for (int nt = 0; nt < 4; ++nt) {
        acc[mt][nt] = __builtin_amdgcn_mfma_f32_16x16x32_f16(af[mt][0], bf[nt][0], acc[mt][nt], 0, 0, 0);
        acc[mt][nt] = __builtin_amdgcn_mfma_f32_16x16x32_f16(af[mt][0], bf[nt][1], acc[mt][nt], 0, 0, 0);
        acc[mt][nt] = __builtin_amdgcn_mfma_f32_16x16x32_f16(af[mt][1], bf[nt][0], acc[mt][nt], 0, 0, 0);
      }
  }
#undef LOADA_ONE
#undef LOAD_AB
#undef ST_A

  // ---- staged, coalesced epilogue: two wx-halves through LDS ----
  int rbase = tid >> 4;          // 0..15
  int c4 = (tid & 15) << 2;      // 0..60
  #pragma unroll
  for (int half = 0; half < 2; ++half) {
    __syncthreads();
    if (wx == half) {
      #pragma unroll
      for (int mt = 0; mt < 4; ++mt)
        #pragma unroll
        for (int nt = 0; nt < 4; ++nt)
          #pragma unroll
          for (int r = 0; r < 4; ++r)
            sT[(wy * 64 + mt * 16 + lq * 4 + r) * 72 + nt * 16 + lm] = acc[mt][nt][r];
    }
    __syncthreads();
    int n = n0 + half * 64 + c4;
    float bv[4] = {0.f, 0.f, 0.f, 0.f};
    if (HAS_BIAS || XB) {
      #pragma unroll
      for (int j = 0; j < 4; ++j) if (n + j < N) bv[j] = bias[n + j];
    }
    float wxv0[4], wxv1[4], wxv2[4], wxv3[4];
    if (XB) {
      #pragma unroll
      for (int j = 0; j < 4; ++j) {
        wxv0[j] = (n + j < N) ? Wx[n + j] : 0.f;
        wxv1[j] = (n + j < N) ? Wx[N + n + j] : 0.f;
        wxv2[j] = (n + j < N) ? Wx[2 * N + n + j] : 0.f;
        wxv3[j] = (n + j < N) ? Wx[3 * N + n + j] : 0.f;
      }
    }
    #pragma unroll
    for (int it = 0; it < 8; ++it) {
      int row = it * 16 + rbase;
      size_t m = (size_t)m0 + row;
      float4 t = *(const float4*)&sT[row * 72 + c4];
      float o[4] = {t.x, t.y, t.z, t.w};
      if (XB) {
        float4 xv = *(const float4*)(X + m * 4);
        #pragma unroll
        for (int j = 0; j < 4; ++j)
          o[j] = o[j] + bv[j] + (xv.x * wxv0[j] + xv.y * wxv1[j] + xv.z * wxv2[j] + xv.w * wxv3[j]);
      } else {
        #pragma unroll
        for (int j = 0; j < 4; ++j) o[j] += bv[j];
      }
      if (n + 3 < N) {
        float4* cp = (float4*)(C + m * N + n);
        if (ACCUM) { float4 c = *cp; o[0] += c.x; o[1] += c.y; o[2] += c.z; o[3] += c.w; }
        float4 ov = {o[0], o[1], o[2], o[3]};
        *cp = ov;
      } else {
        #pragma unroll
        for (int j = 0; j < 4; ++j) {
          if (n + j < N) {
            float v = o[j];
            size_t off = m * N + n + j;
            if (ACCUM) v += C[off];
            C[off] = v;
          }
        }
      }
    }
  }
}

// fp16x3 fused edge stage 2 (layers 3 cols + layer 4)
__global__ __launch_bounds__(256) void edge_stage2_m(
    const float* __restrict__ UV, const int* __restrict__ idx,
    const _Float16* __restrict__ Wp, const float* __restrict__ b2,
    float* __restrict__ out, int H1, int Kpad) {
  __shared__ _Float16 sH[64 * 72];
  __shared__ _Float16 sW[192 * 72];
  __shared__ int sJ[64];
  int tid = threadIdx.x;
  int g0 = blockIdx.x * 16;
  int bbase = (g0 >> 8) << 8;
  if (tid < 64) sJ[tid] = bbase + idx[(size_t)g0 * 4 + tid];
  int W2 = 2 * H1;
  int lane = tid & 63, w = tid >> 6;
  int lm = lane & 15, lq = lane >> 4;
  int rS = tid >> 2, qS = tid & 3;
  f32x4 acc[4][3];
  #pragma unroll
  for (int i = 0; i < 4; ++i)
    #pragma unroll
    for (int j = 0; j < 3; ++j) acc[i][j] = 0.f;

  for (int k0 = 0; k0 < Kpad; k0 += 32) {
    __syncthreads();
    {
      int gp_r = g0 + (rS >> 2);
      int jr = sJ[rS];
      const float* up = UV + (size_t)gp_r * W2;
      const float* vp = UV + (size_t)jr * W2 + H1;
      #pragma unroll
      for (int hf = 0; hf < 2; ++hf) {
        int k = k0 + qS * 8 + hf * 4;
        float4 u = {0.f,0.f,0.f,0.f}, v = {0.f,0.f,0.f,0.f};
        if (k + 3 < H1) { u = *(const float4*)(up + k); v = *(const float4*)(vp + k); }
        else {
          if (k + 0 < H1) { u.x = up[k+0]; v.x = vp[k+0]; }
          if (k + 1 < H1) { u.y = up[k+1]; v.y = vp[k+1]; }
          if (k + 2 < H1) { u.z = up[k+2]; v.z = vp[k+2]; }
        }
        float e0 = LK(u.x + v.x), e1 = LK(u.y + v.y), e2 = LK(u.z + v.z), e3 = LK(u.w + v.w);
        _Float16 h0,h1,h2,h3,l0,l1,l2,l3;
        dec2(e0,h0,l0); dec2(e1,h1,l1); dec2(e2,h2,l2); dec2(e3,h3,l3);
        int off = rS * 72 + qS * 16 + hf * 4;
        f16x4 th; th[0]=h0; th[1]=h1; th[2]=h2; th[3]=h3;
        f16x4 tl; tl[0]=l0; tl[1]=l1; tl[2]=l2; tl[3]=l3;
        *(f16x4*)&sH[off]     = th;
        *(f16x4*)&sH[off + 8] = tl;
      }
    }
    {
      const _Float16* src = Wp + (size_t)k0 * 2;
      #pragma unroll
      for (int p = 0; p < 6; ++p) {
        int e = tid + p * 256;
        int n = e >> 3, u = e & 7;
        *(float4*)&sW[n * 72 + u * 8] =
            *(const float4*)(src + (size_t)n * 2 * Kpad + u * 8);
      }
    }
    __syncthreads();
    f16x8 af[4][2], bf[3][2];
    #pragma unroll
    for (int mt = 0; mt < 4; ++mt) {
      int row = mt * 16 + lm;
      af[mt][0] = *(const f16x8*)&sH[row * 72 + lq * 16];
      af[mt][1] = *(const f16x8*)&sH[row * 72 + lq * 16 + 8];
    }
    #pragma unroll
    for (int t3 = 0; t3 < 3; ++t3) {
      int row = (w * 3 + t3) * 16 + lm;
      bf[t3][0] = *(const f16x8*)&sW[row * 72 + lq * 16];
      bf[t3][1] = *(const f16x8*)&sW[row * 72 + lq * 16 + 8];
    }
    #pragma unroll
    for (int mt = 0; mt < 4; ++mt)
      #pragma unroll
      for (int t3 = 0; t3 < 3; ++t3) {
        acc[mt][t3] = __builtin_amdgcn_mfma_f32_16x16x32_f16(af[mt][0], bf[t3][0], acc[mt][t3], 0, 0, 0);
        acc[mt][t3] = __builtin_amdgcn_mfma_f32_16x16x32_f16(af[mt][0], bf[t3][1], acc[mt][t3], 0, 0, 0);
        acc[mt][t3] = __builtin_amdgcn_mfma_f32_16x16x32_f16(af[mt][1], bf[t3][0], acc[mt][t3], 0, 0, 0);
      }
  }
  #pragma unroll
  for (int mt = 0; mt < 4; ++mt) {
    int gp = g0 + mt * 4 + lq;
    #pragma unroll
    for (int t3 = 0; t3 < 3; ++t3) {
      int col = (w * 3 + t3) * 16 + lm;
      float bv = b2[col];
      float s = 0.f;
      #pragma unroll
      for (int r = 0; r < 4; ++r) s += LK(acc[mt][t3][r] + bv);
      out[(size_t)gp * 192 + col] = s;
    }
  }
}

// ---------------- pooling ----------------
__global__ void pool_kernel(const float* __restrict__ h, float* __restrict__ pooled) {
  int b = blockIdx.x, ch = threadIdx.x;  // 192 threads
  const float* p = h + (size_t)b * N_ * 192 + ch;
  float mx = -INFINITY, mn = INFINITY, sm = 0.f;
  for (int n = 0; n < N_; ++n) {
    float v = p[(size_t)n * 192];
    mx = fmaxf(mx, v); mn = fminf(mn, v); sm += v;
  }
  float* o = pooled + (size_t)b * 768;
  o[ch]       = LK(mx);
  o[192 + ch] = LK(mn);
  o[384 + ch] = LK(sm);
  o[576 + ch] = LK(sm * (1.f / 256.f));
}

// ---------------- head ----------------
__global__ void head_kernel(const float* __restrict__ pooled,
                            const float* __restrict__ w3, const float* __restrict__ b3,
                            const float* __restrict__ w4, const float* __restrict__ b4,
                            float* __restrict__ out) {
  __shared__ float sp[768];
  __shared__ float st[96];
  int b = blockIdx.x, t = threadIdx.x;   // 128 threads
  for (int c = t; c < 768; c += 128) sp[c] = pooled[(size_t)b * 768 + c];
  __syncthreads();
  if (t < 96) {
    float s = b3[t];
    for (int r = 0; r < 768; ++r) s += sp[r] * w3[(size_t)r * 96 + t];
    s = LK(s);
    st[t] = s * w4[t];
  }
  __syncthreads();
  if (t == 0) {
    float s = b4[0];
    for (int i = 0; i < 96; ++i) s += st[i];
    out[b] = s;
  }
}

extern "C" void kernel_launch(void* const* d_in, const int* in_sizes, int n_in,
                              void* d_out, int out_size, void* d_ws, size_t ws_size,
                              hipStream_t stream) {
  (void)in_sizes; (void)n_in; (void)out_size;
  const float* x = (const float*)d_in[0];
  const float* P[25];
  for (int i = 0; i < 25; ++i) P[i] = (const float*)d_in[i];

  // Fused-nn1 (M-chunked, UV/h1c shared region): 238,292,992 B needed.
  constexpr size_t SZ_IDX = 1048576, SZ_FEAT = 50331648;
  constexpr size_t SZ_R = 33030144;            // UV (16384x504 f32) == h1c (32768x252 f32)
  constexpr size_t SZ_POOL = 786432, SZ_W = 1048576;
  constexpr size_t FUSED_WS = SZ_IDX + 4 * SZ_FEAT + SZ_R + SZ_POOL + 2 * SZ_W + 4096;
  const bool fused = (ws_size >= FUSED_WS);

  char* ws = (char*)d_ws;
  int*   idx; float *A, *Bb, *Cb, *Db, *h1, *UV, *pooled; char *Wsl1, *Wsl2; float* bcat;
  if (fused) {
    size_t o = 0;
    idx    = (int*)  (ws + o); o += SZ_IDX;
    A      = (float*)(ws + o); o += SZ_FEAT;
    Bb     = (float*)(ws + o); o += SZ_FEAT;
    Cb     = (float*)(ws + o); o += SZ_FEAT;
    Db     = (float*)(ws + o); o += SZ_FEAT;
    UV     = (float*)(ws + o); h1 = UV; o += SZ_R;   // time-shared: UV dies before h1c born
    pooled = (float*)(ws + o); o += SZ_POOL;
    Wsl1   =         (ws + o); o += SZ_W;
    Wsl2   =         (ws + o); o += SZ_W;
    bcat   = (float*)(ws + o);
  } else {
    // exact measured-R7 layout (peak ~203.7 MB)
    idx    = (int*)  (ws + 0);
    A      = (float*)(ws + 1048576);
    Bb     = (float*)(ws + 51380224);
    Cb     = A;  Db = Bb;                    // aliases (c overwrites a, d overwrites b)
    h1     = (float*)(ws + 101711872);
    UV     = (float*)(ws + 167772160);
    pooled = (float*)(ws + 200802304);
    Wsl1   =         (ws + 201588736);
    Wsl2   =         (ws + 202637312);
    bcat   = (float*)(ws + 203685888);
  }

  float*    wcat = (float*)   Wsl1;
  _Float16* WB1  = (_Float16*)Wsl1;
  _Float16* WB2  = (_Float16*)Wsl2;

  // ---- fp32 edge layer (layers 1,2: fully bit-exact) ----
  auto edge_layer_f32 = [&](const float* src, int F, int H1,
                            const float* w1, const float* b1,
                            const float* w2, const float* b2, float* dst) {
    knn_kernel<<<B_, N_, 0, stream>>>(src, F, idx);
    prep_uvw<<<(F * H1 + 255) / 256, 256, 0, stream>>>(w1, b1, F, H1, wcat, bcat);
    int W2 = 2 * H1;
    dim3 gUV((W2 + 63) / 64, CHUNK_ROWS / 128);
    for (int cb = 0; cb < B_; cb += CHUNK_B) {
      size_t base = (size_t)cb * N_;
      gemm_f32<false, false, true><<<gUV, 256, 0, stream>>>(src + base * F, wcat, bcat, UV, CHUNK_ROWS, W2, F);
      edge_stage2<<<CHUNK_ROWS / 16, 256, 0, stream>>>(UV, idx + base * 4, w2, b2, dst + base * 192, H1);
    }
  };

  // ---- fp16x3 edge layer (layer 4: output feeds no KNN) ----
  auto edge_layer_f16 = [&](const float* src, int F, int H1,
                            const float* w1, const float* b1,
                            const float* w2, const float* b2, float* dst) {
    int Fpad = (F + 31) & ~31;
    int KpadW2 = (H1 + 31) & ~31;
    int NN = 2 * H1;
    knn_kernel<<<B_, N_, 0, stream>>>(src, F, idx);
    prep_wcatT<<<(NN * Fpad + 255) / 256, 256, 0, stream>>>(w1, b1, F, H1, Fpad, WB1, bcat);
    prep_wT<<<(192 * KpadW2 + 255) / 256, 256, 0, stream>>>(w2, H1, 192, KpadW2, WB2);
    dim3 gUV((NN + 127) / 128, CHUNK_ROWS / 128);
    for (int cb = 0; cb < B_; cb += CHUNK_B) {
      size_t base = (size_t)cb * N_;
      gemm3h<false, false, true, false, false><<<gUV, 256, 0, stream>>>(
          src + base * F, src + base * F, nullptr, nullptr, F, WB1, bcat, nullptr, nullptr, UV, CHUNK_ROWS, NN, F, Fpad);
      edge_stage2_m<<<CHUNK_ROWS / 16, 256, 0, stream>>>(
          UV, idx + base * 4, WB2, b2, dst + base * 192, H1, KpadW2);
    }
  };

  // ---- hybrid c-layer: fp32 UV (exact) + fp16x3 stage2 + exact fp32 cols 0-2 ----
  auto edge_layer_c = [&](const float* src, float* dst) {
    const float* w1 = P[9]; const float* b1 = P[10];
    const float* w2 = P[11]; const float* b2 = P[12];
    int F = 192, H1 = 252, W2 = 504, KpadW2 = 256;
    knn_kernel<<<B_, N_, 0, stream>>>(src, F, idx);
    prep_uvw<<<(F * H1 + 255) / 256, 256, 0, stream>>>(w1, b1, F, H1, wcat, bcat);
    prep_wT<<<(192 * KpadW2 + 255) / 256, 256, 0, stream>>>(w2, H1, 192, KpadW2, WB2);
    dim3 gUV((W2 + 63) / 64, CHUNK_ROWS / 128);
    for (int cb = 0; cb < B_; cb += CHUNK_B) {
      size_t base = (size_t)cb * N_;
      gemm_f32<false, false, true><<<gUV, 256, 0, stream>>>(src + base * F, wcat, bcat, UV, CHUNK_ROWS, W2, F);
      edge_stage2_m<<<CHUNK_ROWS / 16, 256, 0, stream>>>(UV, idx + base * 4, WB2, b2, dst + base * 192, H1, KpadW2);
      edge_exact3<<<CHUNK_ROWS / 64, 256, 0, stream>>>(UV, idx + base * 4, w2, b2, dst + base * 192, H1);
    }
  };

  // a = edge(x) -> A ; b = edge(a) -> Bb      [fp32 exact: feed KNN 2,3 via full GEMMs]
  edge_layer_f32(x,  4,   96,  P[1], P[2], P[3], P[4], A);
  edge_layer_f32(A,  192, 252, P[5], P[6], P[7], P[8], Bb);

  if (fused) {
    // c = edge(b) -> Cb ; d = edge(c) -> Db  (a,b stay live; UV region still in use)
    edge_layer_c(Bb, Cb);
    edge_layer_f16(Cb, 192, 252, P[13], P[14], P[15], P[16], Db);
    // Fused nn1 (K=768, one chain) + nn2, M-chunked at 32768 rows.
    // h1c shares the (now dead) UV region. nn2-chunk writes only A-rows its own
    // nn1-chunk already consumed; later nn1-chunks read higher rows only.
    prep_wT<<<(252 * 768 + 255) / 256, 256, 0, stream>>>(P[17] + 4 * 252, 768, 252, 768, WB1);
    prep_wT<<<(192 * 256 + 255) / 256, 256, 0, stream>>>(P[19], 252, 192, 256, WB2);
    dim3 g(2, 256);
    for (int mc = 0; mc < 2; ++mc) {
      size_t roff = (size_t)mc * 32768;
      gemm3h<false, false, true, true, true><<<g, 256, 0, stream>>>(
          A + roff * 192, Bb + roff * 192, Cb + roff * 192, Db + roff * 192, 0,
          WB1, P[18], x + roff * 4, P[17], h1, 32768, 252, 768, 768);
      gemm3h<true, false, true, false, false><<<g, 256, 0, stream>>>(
          h1, h1, nullptr, nullptr, 252, WB2, P[20], nullptr, nullptr,
          A + roff * 192, 32768, 192, 252, 256);
    }
  } else {
    // h1 = [x,a,b] @ nn1w[0:388] + nn1b
    prep_wT<<<(252 * 384 + 255) / 256, 256, 0, stream>>>(P[17] + 4 * 252, 384, 252, 384, WB1);
    dim3 g(2, BN / 128);
    gemm3h<false, false, true, true, false><<<g, 256, 0, stream>>>(
        A, Bb, nullptr, nullptr, 192, WB1, P[18], x, P[17], h1, BN, 252, 384, 384);
    // c = edge(b) -> A (overwrites a) ; d = edge(c) -> Bb
    edge_layer_c(Bb, Cb);
    edge_layer_f16(Cb, 192, 252, P[13], P[14], P[15], P[16], Db);
    // h1 += [c,d] @ nn1w[388:772]
    prep_wT<<<(252 * 384 + 255) / 256, 256, 0, stream>>>(P[17] + (size_t)388 * 252, 384, 252, 384, WB1);
    gemm3h<false, true, false, false, false><<<g, 256, 0, stream>>>(
        Cb, Db, nullptr, nullptr, 192, WB1, nullptr, nullptr, nullptr, h1, BN, 252, 384, 384);
    // nn2: h2 = leaky(h1) @ nn2w + nn2b -> A
    prep_wT<<<(192 * 256 + 255) / 256, 256, 0, stream>>>(P[19], 252, 192, 256, WB2);
    gemm3h<true, false, true, false, false><<<g, 256, 0, stream>>>(
        h1, h1, nullptr, nullptr, 252, WB2, P[20], nullptr, nullptr, A, BN, 192, 252, 256);
  }

  pool_kernel<<<B_, 192, 0, stream>>>(A, pooled);
  head_kernel<<<B_, 128, 0, stream>>>(pooled, P[21], P[22], P[23], P[24], (float*)d_out);
}

// Round 13
// 1913.766 us; speedup vs baseline: 1.0541x; 1.0300x over previous
//
#include <hip/hip_runtime.h>
#include <cstdint>
#include <cstddef>

#define LK(x) ((x) > 0.f ? (x) : 0.01f * (x))

typedef _Float16 f16x8 __attribute__((ext_vector_type(8)));
typedef _Float16 f16x4 __attribute__((ext_vector_type(4)));
typedef float f32x4 __attribute__((ext_vector_type(4)));

constexpr int B_ = 256;
constexpr int N_ = 256;
constexpr int BN = B_ * N_;
constexpr int CHUNK_B = 64;                 // batches per UV chunk
constexpr int CHUNK_ROWS = CHUNK_B * N_;    // 16384 rows

// fp16 2-way split (for fp16x3 path)
__device__ inline void dec2(float v, _Float16& h, _Float16& l) {
  _Float16 hh = (_Float16)v;
  h = hh;
  l = (_Float16)(v - (float)hh);
}

// ---------------- KNN: one block per batch, one thread per point ----------------
__global__ void knn_kernel(const float* __restrict__ feat, int F, int* __restrict__ idxout) {
  __shared__ float px[N_], py[N_], pz[N_];
  int b = blockIdx.x, t = threadIdx.x;
  const float* row = feat + ((size_t)b * N_ + t) * F;
  px[t] = row[0]; py[t] = row[1]; pz[t] = row[2];
  __syncthreads();
  float x = px[t], y = py[t], z = pz[t];
  float bd0 = INFINITY, bd1 = INFINITY, bd2 = INFINITY, bd3 = INFINITY;
  int bi0 = 0, bi1 = 0, bi2 = 0, bi3 = 0;
  for (int j = 0; j < N_; ++j) {
    #pragma clang fp contract(off)
    float dx = x - px[j], dy = y - py[j], dz = z - pz[j];
    float d = (dx * dx + dy * dy) + dz * dz;
    if (j == t) continue;
    if (d < bd3) {
      if (d < bd2) {
        bd3 = bd2; bi3 = bi2;
        if (d < bd1) {
          bd2 = bd1; bi2 = bi1;
          if (d < bd0) { bd1 = bd0; bi1 = bi0; bd0 = d; bi0 = j; }
          else         { bd1 = d; bi1 = j; }
        } else         { bd2 = d; bi2 = j; }
      } else           { bd3 = d; bi3 = j; }
    }
  }
  int* o = idxout + ((size_t)b * N_ + t) * 4;
  o[0] = bi0; o[1] = bi1; o[2] = bi2; o[3] = bi3;
}

// ============================ fp32 path (bit-exact chain) ============================

// wcat = [w1_top - w1_bot | w1_bot] (F x 2H1), bcat = [b1 | 0]
__global__ void prep_uvw(const float* __restrict__ w1, const float* __restrict__ b1,
                         int F, int H1, float* __restrict__ wcat, float* __restrict__ bcat) {
  int t = blockIdx.x * 256 + threadIdx.x;
  int FH = F * H1;
  if (t < FH) {
    int k = t / H1, c = t - k * H1;
    float top = w1[(size_t)k * H1 + c];
    float bot = w1[(size_t)(F + k) * H1 + c];
    wcat[(size_t)k * 2 * H1 + c]      = top - bot;
    wcat[(size_t)k * 2 * H1 + H1 + c] = bot;
  }
  if (t < H1) { bcat[t] = b1[t]; bcat[H1 + t] = 0.f; }
}

// fp32 GEMM: 128x64 tile, BK=16, 256 thr, 8x4 micro.
// 1-DEEP REGISTER PREFETCH (R4-validated pattern): next K-step's A/W global
// loads issued during this step's FMA phase. Values/guards/order identical ->
// bit-exact vs the measured R12 kernel.
template<bool ACT_A, bool ACCUM, bool HAS_BIAS>
__global__ __launch_bounds__(256) void gemm_f32(
    const float* __restrict__ A, const float* __restrict__ W,
    const float* __restrict__ bias, float* __restrict__ C,
    int M, int N, int K) {
  __shared__ float sA[16][132];
  __shared__ float sW[16][68];
  int tid = threadIdx.x;
  int m0 = blockIdx.y * 128;
  int n0 = blockIdx.x * 64;
  int kkA = tid & 15, mA = tid >> 4;
  int nW = tid & 63, kW = tid >> 6;
  int ty = tid >> 4, tx = tid & 15;
  float acc[8][4] = {};
  float pa[8], pw[4];

#define G_LD(K0)                                                  \
  { int kg_ = (K0) + kkA;                                         \
    _Pragma("unroll")                                             \
    for (int i = 0; i < 8; ++i) {                                 \
      int m = mA + i * 16;                                        \
      float v = 0.f;                                              \
      if (kg_ < K) {                                              \
        v = A[(size_t)(m0 + m) * K + kg_];                        \
        if (ACT_A) v = LK(v);                                     \
      }                                                           \
      pa[i] = v;                                                  \
    }                                                             \
    _Pragma("unroll")                                             \
    for (int q = 0; q < 4; ++q) {                                 \
      int kk = kW + q * 4;                                        \
      int kgw = (K0) + kk, n = n0 + nW;                           \
      float v = 0.f;                                              \
      if (kgw < K && n < N) v = W[(size_t)kgw * N + n];           \
      pw[q] = v;                                                  \
    } }

  G_LD(0)

  for (int k0 = 0; k0 < K; k0 += 16) {
    __syncthreads();           // previous compute finished reading LDS
    #pragma unroll
    for (int i = 0; i < 8; ++i) sA[kkA][mA + i * 16] = pa[i];
    #pragma unroll
    for (int q = 0; q < 4; ++q) sW[kW + q * 4][nW] = pw[q];
    if (k0 + 16 < K) { G_LD(k0 + 16) }
    __syncthreads();
    #pragma unroll
    for (int kk = 0; kk < 16; ++kk) {
      float4 a0 = *(const float4*)&sA[kk][ty * 8];
      float4 a1 = *(const float4*)&sA[kk][ty * 8 + 4];
      float4 w  = *(const float4*)&sW[kk][tx * 4];
      float av[8] = {a0.x, a0.y, a0.z, a0.w, a1.x, a1.y, a1.z, a1.w};
      float wv[4] = {w.x, w.y, w.z, w.w};
      #pragma unroll
      for (int i = 0; i < 8; ++i)
        #pragma unroll
        for (int j = 0; j < 4; ++j)
          acc[i][j] += av[i] * wv[j];
    }
  }
#undef G_LD
  int n = n0 + tx * 4;
  float bv[4] = {0.f, 0.f, 0.f, 0.f};
  if (HAS_BIAS) {
    #pragma unroll
    for (int j = 0; j < 4; ++j) if (n + j < N) bv[j] = bias[n + j];
  }
  #pragma unroll
  for (int i = 0; i < 8; ++i) {
    size_t m = (size_t)(m0 + ty * 8 + i);
    if (n + 3 < N) {
      float4 o;
      o.x = acc[i][0] + bv[0]; o.y = acc[i][1] + bv[1];
      o.z = acc[i][2] + bv[2]; o.w = acc[i][3] + bv[3];
      float4* cp = (float4*)(C + m * N + n);
      if (ACCUM) { float4 c = *cp; o.x += c.x; o.y += c.y; o.z += c.z; o.w += c.w; }
      *cp = o;
    } else {
      #pragma unroll
      for (int j = 0; j < 4; ++j) {
        if (n + j < N) {
          float v = acc[i][j] + bv[j];
          size_t off = m * N + n + j;
          if (ACCUM) v += C[off];
          C[off] = v;
        }
      }
    }
  }
}

// fp32 fused edge stage 2, K-tiled — layers 1,2.
// 1-DEEP REGISTER PREFETCH of u/v/w staging loads + hoisted /48 address math.
// Same loads, guards, and fp32 accumulation order -> bit-exact vs R12.
__global__ __launch_bounds__(256) void edge_stage2(
    const float* __restrict__ UV, const int* __restrict__ idx,
    const float* __restrict__ w2, const float* __restrict__ b2,
    float* __restrict__ out, int H1) {
  __shared__ float sH[16][68];
  __shared__ float sW[16][196];
  __shared__ int sJ[64];
  int tid = threadIdx.x;
  int g0 = blockIdx.x * 16;
  int bbase = (g0 >> 8) << 8;
  if (tid < 64) sJ[tid] = bbase + idx[(size_t)g0 * 4 + tid];
  int W2 = H1 * 2;
  int r = tid >> 2, seg = tid & 3;
  int gp_r = g0 + (r >> 2);
  int ty = tid >> 4, tx = tid & 15;
  int gp = g0 + ty;
  // hoisted sW staging indices (kt-invariant)
  int kkW[3], c4W[3];
  #pragma unroll
  for (int p = 0; p < 3; ++p) {
    int q = tid + (p << 8);
    kkW[p] = q / 48;
    c4W[p] = (q - kkW[p] * 48) << 2;
  }
  float acc[4][12] = {};
  int nKt = (H1 + 15) >> 4;

  __syncthreads();   // sJ visible before prefetch reads it

  const float* up = UV + (size_t)gp_r * W2;
  const float* vp = UV + (size_t)sJ[r] * W2 + H1;

  float u0[4], v0[4];
  float4 wp0[3];

#define E_LD(K0)                                                  \
  { int c_ = (K0) + (seg << 2);                                   \
    if (c_ + 3 < H1) {                                            \
      float4 uu = *(const float4*)(up + c_);                      \
      float4 vv = *(const float4*)(vp + c_);                      \
      u0[0]=uu.x; u0[1]=uu.y; u0[2]=uu.z; u0[3]=uu.w;             \
      v0[0]=vv.x; v0[1]=vv.y; v0[2]=vv.z; v0[3]=vv.w;             \
    } else {                                                      \
      _Pragma("unroll")                                           \
      for (int j = 0; j < 4; ++j) {                               \
        u0[j] = (c_ + j < H1) ? up[c_ + j] : 0.f;                 \
        v0[j] = (c_ + j < H1) ? vp[c_ + j] : 0.f;                 \
      }                                                           \
    }                                                             \
    _Pragma("unroll")                                             \
    for (int p = 0; p < 3; ++p) {                                 \
      int k_ = (K0) + kkW[p];                                     \
      float4 wv = {0.f, 0.f, 0.f, 0.f};                           \
      if (k_ < H1) wv = *(const float4*)(w2 + (size_t)k_ * 192 + c4W[p]); \
      wp0[p] = wv;                                                \
    } }

  E_LD(0)

  for (int kt = 0; kt < nKt; ++kt) {
    int k0 = kt << 4;
    __syncthreads();           // previous compute finished reading LDS
    {
      int c = k0 + (seg << 2);
      #pragma unroll
      for (int j = 0; j < 4; ++j) {
        float t = u0[j] + v0[j];
        sH[(seg << 2) + j][r] = (c + j < H1) ? LK(t) : 0.f;
      }
      #pragma unroll
      for (int p = 0; p < 3; ++p)
        *(float4*)&sW[kkW[p]][c4W[p]] = wp0[p];
    }
    if (kt + 1 < nKt) { E_LD((kt + 1) << 4) }
    __syncthreads();
    #pragma unroll
    for (int kk = 0; kk < 16; ++kk) {
      float4 a = *(const float4*)&sH[kk][ty << 2];
      float av[4] = {a.x, a.y, a.z, a.w};
      #pragma unroll
      for (int ct = 0; ct < 3; ++ct) {
        float4 w = *(const float4*)&sW[kk][ct * 64 + (tx << 2)];
        float wv[4] = {w.x, w.y, w.z, w.w};
        #pragma unroll
        for (int i = 0; i < 4; ++i)
          #pragma unroll
          for (int j = 0; j < 4; ++j)
            acc[i][ct * 4 + j] += av[i] * wv[j];
      }
    }
  }
#undef E_LD
  #pragma unroll
  for (int ct = 0; ct < 3; ++ct) {
    float o[4];
    #pragma unroll
    for (int j = 0; j < 4; ++j) {
      int col = ct * 64 + (tx << 2) + j;
      float bvv = b2[col];
      float s = 0.f;
      #pragma unroll
      for (int i = 0; i < 4; ++i) {
        float t = acc[i][ct * 4 + j] + bvv;
        s += LK(t);
      }
      o[j] = s;
    }
    float4 ov = {o[0], o[1], o[2], o[3]};
    *(float4*)(out + (size_t)gp * 192 + ct * 64 + (tx << 2)) = ov;
  }
}

// exact fp32 replica of stage2 for cols 0..2 ONLY (the KNN-feeding columns).
__global__ __launch_bounds__(256) void edge_exact3(
    const float* __restrict__ UV, const int* __restrict__ idx,
    const float* __restrict__ w2, const float* __restrict__ b2,
    float* __restrict__ out, int H1) {
  __shared__ float sw[252 * 4];
  int tid = threadIdx.x;
  for (int k = tid; k < H1; k += 256) {
    sw[k * 4 + 0] = w2[(size_t)k * 192 + 0];
    sw[k * 4 + 1] = w2[(size_t)k * 192 + 1];
    sw[k * 4 + 2] = w2[(size_t)k * 192 + 2];
    sw[k * 4 + 3] = 0.f;
  }
  __syncthreads();
  int p = blockIdx.x * 64 + (tid >> 2);   // chunk-local point
  int e = tid & 3;
  int bbase = (p >> 8) << 8;
  int j = bbase + idx[(size_t)p * 4 + e];
  int W2 = 2 * H1;
  const float* up = UV + (size_t)p * W2;
  const float* vp = UV + (size_t)j * W2 + H1;
  float a0 = 0.f, a1 = 0.f, a2 = 0.f;
  int k = 0;
  for (; k + 3 < H1; k += 4) {
    float4 u = *(const float4*)(up + k);
    float4 v = *(const float4*)(vp + k);
    float h0 = LK(u.x + v.x), h1 = LK(u.y + v.y);
    float h2 = LK(u.z + v.z), h3 = LK(u.w + v.w);
    float4 w0 = *(const float4*)&sw[(k + 0) * 4];
    float4 w1 = *(const float4*)&sw[(k + 1) * 4];
    float4 w2v = *(const float4*)&sw[(k + 2) * 4];
    float4 w3 = *(const float4*)&sw[(k + 3) * 4];
    a0 = __builtin_fmaf(h0, w0.x, a0); a1 = __builtin_fmaf(h0, w0.y, a1); a2 = __builtin_fmaf(h0, w0.z, a2);
    a0 = __builtin_fmaf(h1, w1.x, a0); a1 = __builtin_fmaf(h1, w1.y, a1); a2 = __builtin_fmaf(h1, w1.z, a2);
    a0 = __builtin_fmaf(h2, w2v.x, a0); a1 = __builtin_fmaf(h2, w2v.y, a1); a2 = __builtin_fmaf(h2, w2v.z, a2);
    a0 = __builtin_fmaf(h3, w3.x, a0); a1 = __builtin_fmaf(h3, w3.y, a1); a2 = __builtin_fmaf(h3, w3.z, a2);
  }
  for (; k < H1; ++k) {
    float h = LK(up[k] + vp[k]);
    a0 = __builtin_fmaf(h, sw[k * 4 + 0], a0);
    a1 = __builtin_fmaf(h, sw[k * 4 + 1], a1);
    a2 = __builtin_fmaf(h, sw[k * 4 + 2], a2);
  }
  float acc3[3] = {a0, a1, a2};
  #pragma unroll
  for (int c = 0; c < 3; ++c) {
    float t = acc3[c] + b2[c];
    float pc = LK(t);
    float q1 = __shfl_down(pc, 1);
    float q2 = __shfl_down(pc, 2);
    float q3 = __shfl_down(pc, 3);
    if (e == 0) {
      float s = ((pc + q1) + q2) + q3;   // e-ascending order, matches edge_stage2 epilogue
      out[(size_t)p * 192 + c] = s;
    }
  }
}

// ====================== fp16x3 MFMA path (noise-tolerant GEMMs) ======================

// Wp[n][k-octets]: [8 hi | 8 lo]; [wdiff | wbot] transposed. bcat = [b1|0]
__global__ void prep_wcatT(const float* __restrict__ w1, const float* __restrict__ b1,
                           int F, int H1, int Fpad, _Float16* __restrict__ Wp,
                           float* __restrict__ bcat) {
  int t = blockIdx.x * 256 + threadIdx.x;
  int NN = 2 * H1;
  if (t < NN * Fpad) {
    int n = t / Fpad, k = t - n * Fpad;
    float v = 0.f;
    if (k < F) {
      if (n < H1) v = w1[(size_t)k * H1 + n] - w1[(size_t)(F + k) * H1 + n];
      else        v = w1[(size_t)(F + k) * H1 + (n - H1)];
    }
    _Float16 h, l; dec2(v, h, l);
    size_t base = (size_t)n * 2 * Fpad + (size_t)(k >> 3) * 16 + (k & 7);
    Wp[base] = h; Wp[base + 8] = l;
  }
  if (t < NN) bcat[t] = (t < H1) ? b1[t] : 0.f;
}

__global__ void prep_wT(const float* __restrict__ W, int K, int N, int Kpad,
                        _Float16* __restrict__ Wp) {
  int t = blockIdx.x * 256 + threadIdx.x;
  if (t >= N * Kpad) return;
  int n = t / Kpad, k = t - n * Kpad;
  float v = (k < K) ? W[(size_t)k * N + n] : 0.f;
  _Float16 h, l; dec2(v, h, l);
  size_t base = (size_t)n * 2 * Kpad + (size_t)(k >> 3) * 16 + (k & 7);
  Wp[base] = h; Wp[base + 8] = l;
}

// fp16x3 MFMA GEMM. Block 128x128, 4 waves (2x2), K-step 32.
// PIPELINED (1-deep reg prefetch) + LDS-TRANSPOSE EPILOGUE (measured R7).
// CAT4: A is the concatenation [A0|A1|A2|A3], each 192 cols (fused nn1, K=768).
template<bool ACT_A, bool ACCUM, bool HAS_BIAS, bool XB, bool CAT4>
__global__ __launch_bounds__(256) void gemm3h(
    const float* __restrict__ A0, const float* __restrict__ A1,
    const float* __restrict__ A2, const float* __restrict__ A3, int w0,
    const _Float16* __restrict__ Wp, const float* __restrict__ bias,
    const float* __restrict__ X, const float* __restrict__ Wx,
    float* __restrict__ C, int M, int N, int K, int Kpad) {
  __shared__ _Float16 sAB[2 * 128 * 72];   // sA | sB ; reused as float sT[128][72]
  _Float16* sA = sAB;
  _Float16* sB = sAB + 128 * 72;
  float* sT = (float*)sAB;
  int tid = threadIdx.x;
  int m0 = blockIdx.y * 128, n0 = blockIdx.x * 128;
  int lane = tid & 63, wid = tid >> 6;
  int wy = wid >> 1, wx = wid & 1;
  int lm = lane & 15, lq = lane >> 4;
  int rA = tid >> 1, qA = (tid & 1) * 4;
  f32x4 acc[4][4];
  #pragma unroll
  for (int i = 0; i < 4; ++i)
    #pragma unroll
    for (int j = 0; j < 4; ++j) acc[i][j] = 0.f;

  float4 pa0, pa1, pa2, pa3, pb0, pb1, pb2, pb3;

#define LOADA_ONE(KL, DST)                                          \
  { int kl_ = (KL); float4 v_ = {0.f, 0.f, 0.f, 0.f};               \
    if (kl_ + 3 < wA) v_ = *(const float4*)(arow + kl_);            \
    else {                                                          \
      if (kl_ + 0 < wA) v_.x = arow[kl_ + 0];                       \
      if (kl_ + 1 < wA) v_.y = arow[kl_ + 1];                       \
      if (kl_ + 2 < wA) v_.z = arow[kl_ + 2]; }                     \
    DST = v_; }

#define LOAD_AB(K0)                                                 \
  { int k0_ = (K0);                                                 \
    const float* Ap; int kb, wA;                                    \
    if (CAT4) {                                                     \
      int s_ = k0_ / 192;                                           \
      Ap = (s_ == 0) ? A0 : (s_ == 1) ? A1 : (s_ == 2) ? A2 : A3;   \
      kb = k0_ - s_ * 192; wA = 192;                                \
    } else if (k0_ < w0) { Ap = A0; kb = k0_;      wA = w0; }       \
    else                 { Ap = A1; kb = k0_ - w0; wA = K - w0; }   \
    const float* arow = Ap + (size_t)(m0 + rA) * wA;                \
    LOADA_ONE(kb + (qA + 0) * 4, pa0)                               \
    LOADA_ONE(kb + (qA + 1) * 4, pa1)                               \
    LOADA_ONE(kb + (qA + 2) * 4, pa2)                               \
    LOADA_ONE(kb + (qA + 3) * 4, pa3)                               \
    int n_ = n0 + rA;                                               \
    const _Float16* src = Wp + (size_t)n_ * 2 * Kpad + (size_t)k0_ * 2; \
    float4 z_ = {0.f, 0.f, 0.f, 0.f};                               \
    if (n_ < N) {                                                   \
      pb0 = *(const float4*)(src + (qA + 0) * 8);                   \
      pb1 = *(const float4*)(src + (qA + 1) * 8);                   \
      pb2 = *(const float4*)(src + (qA + 2) * 8);                   \
      pb3 = *(const float4*)(src + (qA + 3) * 8);                   \
    } else { pb0 = z_; pb1 = z_; pb2 = z_; pb3 = z_; } }

#define ST_A(V, Q)                                                  \
  { float4 t_ = (V);                                                \
    if (ACT_A) { t_.x = LK(t_.x); t_.y = LK(t_.y);                  \
                 t_.z = LK(t_.z); t_.w = LK(t_.w); }                \
    _Float16 h0,h1,h2,h3,l0,l1,l2,l3;                               \
    dec2(t_.x,h0,l0); dec2(t_.y,h1,l1);                             \
    dec2(t_.z,h2,l2); dec2(t_.w,h3,l3);                             \
    int off_ = rA * 72 + ((Q) >> 1) * 16 + ((Q) & 1) * 4;           \
    f16x4 th; th[0]=h0; th[1]=h1; th[2]=h2; th[3]=h3;               \
    f16x4 tl; tl[0]=l0; tl[1]=l1; tl[2]=l2; tl[3]=l3;               \
    *(f16x4*)&sA[off_]     = th;                                    \
    *(f16x4*)&sA[off_ + 8] = tl; }

  LOAD_AB(0)

  for (int k0 = 0; k0 < Kpad; k0 += 32) {
    __syncthreads();
    ST_A(pa0, qA + 0)
    ST_A(pa1, qA + 1)
    ST_A(pa2, qA + 2)
    ST_A(pa3, qA + 3)
    *(float4*)&sB[rA * 72 + (qA + 0) * 8] = pb0;
    *(float4*)&sB[rA * 72 + (qA + 1) * 8] = pb1;
    *(float4*)&sB[rA * 72 + (qA + 2) * 8] = pb2;
    *(float4*)&sB[rA * 72 + (qA + 3) * 8] = pb3;
    if (k0 + 32 < Kpad) { LOAD_AB(k0 + 32) }
    __syncthreads();
    f16x8 af[4][2], bf[4][2];
    #pragma unroll
    for (int mt = 0; mt < 4; ++mt) {
      int row = wy * 64 + mt * 16 + lm;
      af[mt][0] = *(const f16x8*)&sA[row * 72 + lq * 16];
      af[mt][1] = *(const f16x8*)&sA[row * 72 + lq * 16 + 8];
    }
    #pragma unroll
    for (int nt = 0; nt < 4; ++nt) {
      int row = wx * 64 + nt * 16 + lm;
      bf[nt][0] = *(const f16x8*)&sB[row * 72 + lq * 16];
      bf[nt][1] = *(const f16x8*)&sB[row * 72 + lq * 16 + 8];
    }
    #pragma unroll
    for (int mt = 0; mt < 4; ++mt)
      #pragma unroll
      for (int nt = 0; nt < 4; ++nt) {
        acc[mt][nt] = __builtin_amdgcn_mfma_f32_16x16x32_f16(af[mt][0], bf[nt][0], acc[mt][nt], 0, 0, 0);
        acc[mt][nt] = __builtin_amdgcn_mfma_f32_16x16x32_f16(af[mt][0], bf[nt][1], acc[mt][nt], 0, 0, 0);
        acc[mt][nt] = __builtin_amdgcn_mfma_f32_16x16x32_f16(af[mt][1], bf[nt][0], acc[mt][nt], 0, 0, 0);
      }
  }
#undef LOADA_ONE
#undef LOAD_AB
#undef ST_A

  // ---- staged, coalesced epilogue: two wx-halves through LDS ----
  int rbase = tid >> 4;          // 0..15
  int c4 = (tid & 15) << 2;      // 0..60
  #pragma unroll
  for (int half = 0; half < 2; ++half) {
    __syncthreads();
    if (wx == half) {
      #pragma unroll
      for (int mt = 0; mt < 4; ++mt)
        #pragma unroll
        for (int nt = 0; nt < 4; ++nt)
          #pragma unroll
          for (int r = 0; r < 4; ++r)
            sT[(wy * 64 + mt * 16 + lq * 4 + r) * 72 + nt * 16 + lm] = acc[mt][nt][r];
    }
    __syncthreads();
    int n = n0 + half * 64 + c4;
    float bv[4] = {0.f, 0.f, 0.f, 0.f};
    if (HAS_BIAS || XB) {
      #pragma unroll
      for (int j = 0; j < 4; ++j) if (n + j < N) bv[j] = bias[n + j];
    }
    float wxv0[4], wxv1[4], wxv2[4], wxv3[4];
    if (XB) {
      #pragma unroll
      for (int j = 0; j < 4; ++j) {
        wxv0[j] = (n + j < N) ? Wx[n + j] : 0.f;
        wxv1[j] = (n + j < N) ? Wx[N + n + j] : 0.f;
        wxv2[j] = (n + j < N) ? Wx[2 * N + n + j] : 0.f;
        wxv3[j] = (n + j < N) ? Wx[3 * N + n + j] : 0.f;
      }
    }
    #pragma unroll
    for (int it = 0; it < 8; ++it) {
      int row = it * 16 + rbase;
      size_t m = (size_t)m0 + row;
      float4 t = *(const float4*)&sT[row * 72 + c4];
      float o[4] = {t.x, t.y, t.z, t.w};
      if (XB) {
        float4 xv = *(const float4*)(X + m * 4);
        #pragma unroll
        for (int j = 0; j < 4; ++j)
          o[j] = o[j] + bv[j] + (xv.x * wxv0[j] + xv.y * wxv1[j] + xv.z * wxv2[j] + xv.w * wxv3[j]);
      } else {
        #pragma unroll
        for (int j = 0; j < 4; ++j) o[j] += bv[j];
      }
      if (n + 3 < N) {
        float4* cp = (float4*)(C + m * N + n);
        if (ACCUM) { float4 c = *cp; o[0] += c.x; o[1] += c.y; o[2] += c.z; o[3] += c.w; }
        float4 ov = {o[0], o[1], o[2], o[3]};
        *cp = ov;
      } else {
        #pragma unroll
        for (int j = 0; j < 4; ++j) {
          if (n + j < N) {
            float v = o[j];
            size_t off = m * N + n + j;
            if (ACCUM) v += C[off];
            C[off] = v;
          }
        }
      }
    }
  }
}

// fp16x3 fused edge stage 2 (layers 3 cols + layer 4)
__global__ __launch_bounds__(256) void edge_stage2_m(
    const float* __restrict__ UV, const int* __restrict__ idx,
    const _Float16* __restrict__ Wp, const float* __restrict__ b2,
    float* __restrict__ out, int H1, int Kpad) {
  __shared__ _Float16 sH[64 * 72];
  __shared__ _Float16 sW[192 * 72];
  __shared__ int sJ[64];
  int tid = threadIdx.x;
  int g0 = blockIdx.x * 16;
  int bbase = (g0 >> 8) << 8;
  if (tid < 64) sJ[tid] = bbase + idx[(size_t)g0 * 4 + tid];
  int W2 = 2 * H1;
  int lane = tid & 63, w = tid >> 6;
  int lm = lane & 15, lq = lane >> 4;
  int rS = tid >> 2, qS = tid & 3;
  f32x4 acc[4][3];
  #pragma unroll
  for (int i = 0; i < 4; ++i)
    #pragma unroll
    for (int j = 0; j < 3; ++j) acc[i][j] = 0.f;

  for (int k0 = 0; k0 < Kpad; k0 += 32) {
    __syncthreads();
    {
      int gp_r = g0 + (rS >> 2);
      int jr = sJ[rS];
      const float* up = UV + (size_t)gp_r * W2;
      const float* vp = UV + (size_t)jr * W2 + H1;
      #pragma unroll
      for (int hf = 0; hf < 2; ++hf) {
        int k = k0 + qS * 8 + hf * 4;
        float4 u = {0.f,0.f,0.f,0.f}, v = {0.f,0.f,0.f,0.f};
        if (k + 3 < H1) { u = *(const float4*)(up + k); v = *(const float4*)(vp + k); }
        else {
          if (k + 0 < H1) { u.x = up[k+0]; v.x = vp[k+0]; }
          if (k + 1 < H1) { u.y = up[k+1]; v.y = vp[k+1]; }
          if (k + 2 < H1) { u.z = up[k+2]; v.z = vp[k+2]; }
        }
        float e0 = LK(u.x + v.x), e1 = LK(u.y + v.y), e2 = LK(u.z + v.z), e3 = LK(u.w + v.w);
        _Float16 h0,h1,h2,h3,l0,l1,l2,l3;
        dec2(e0,h0,l0); dec2(e1,h1,l1); dec2(e2,h2,l2); dec2(e3,h3,l3);
        int off = rS * 72 + qS * 16 + hf * 4;
        f16x4 th; th[0]=h0; th[1]=h1; th[2]=h2; th[3]=h3;
        f16x4 tl; tl[0]=l0; tl[1]=l1; tl[2]=l2; tl[3]=l3;
        *(f16x4*)&sH[off]     = th;
        *(f16x4*)&sH[off + 8] = tl;
      }
    }
    {
      const _Float16* src = Wp + (size_t)k0 * 2;
      #pragma unroll
      for (int p = 0; p < 6; ++p) {
        int e = tid + p * 256;
        int n = e >> 3, u = e & 7;
        *(float4*)&sW[n * 72 + u * 8] =
            *(const float4*)(src + (size_t)n * 2 * Kpad + u * 8);
      }
    }
    __syncthreads();
    f16x8 af[4][2], bf[3][2];
    #pragma unroll
    for (int mt = 0; mt < 4; ++mt) {
      int row = mt * 16 + lm;
      af[mt][0] = *(const f16x8*)&sH[row * 72 + lq * 16];
      af[mt][1] = *(const f16x8*)&sH[row * 72 + lq * 16 + 8];
    }
    #pragma unroll
    for (int t3 = 0; t3 < 3; ++t3) {
      int row = (w * 3 + t3) * 16 + lm;
      bf[t3][0] = *(const f16x8*)&sW[row * 72 + lq * 16];
      bf[t3][1] = *(const f16x8*)&sW[row * 72 + lq * 16 + 8];
    }
    #pragma unroll
    for (int mt = 0; mt < 4; ++mt)
      #pragma unroll
      for (int t3 = 0; t3 < 3; ++t3) {
        acc[mt][t3] = __builtin_amdgcn_mfma_f32_16x16x32_f16(af[mt][0], bf[t3][0], acc[mt][t3], 0, 0, 0);
        acc[mt][t3] = __builtin_amdgcn_mfma_f32_16x16x32_f16(af[mt][0], bf[t3][1], acc[mt][t3], 0, 0, 0);
        acc[mt][t3] = __builtin_amdgcn_mfma_f32_16x16x32_f16(af[mt][1], bf[t3][0], acc[mt][t3], 0, 0, 0);
      }
  }
  #pragma unroll
  for (int mt = 0; mt < 4; ++mt) {
    int gp = g0 + mt * 4 + lq;
    #pragma unroll
    for (int t3 = 0; t3 < 3; ++t3) {
      int col = (w * 3 + t3) * 16 + lm;
      float bv = b2[col];
      float s = 0.f;
      #pragma unroll
      for (int r = 0; r < 4; ++r) s += LK(acc[mt][t3][r] + bv);
      out[(size_t)gp * 192 + col] = s;
    }
  }
}

// ---------------- pooling ----------------
__global__ void pool_kernel(const float* __restrict__ h, float* __restrict__ pooled) {
  int b = blockIdx.x, ch = threadIdx.x;  // 192 threads
  const float* p = h + (size_t)b * N_ * 192 + ch;
  float mx = -INFINITY, mn = INFINITY, sm = 0.f;
  for (int n = 0; n < N_; ++n) {
    float v = p[(size_t)n * 192];
    mx = fmaxf(mx, v); mn = fminf(mn, v); sm += v;
  }
  float* o = pooled + (size_t)b * 768;
  o[ch]       = LK(mx);
  o[192 + ch] = LK(mn);
  o[384 + ch] = LK(sm);
  o[576 + ch] = LK(sm * (1.f / 256.f));
}

// ---------------- head ----------------
__global__ void head_kernel(const float* __restrict__ pooled,
                            const float* __restrict__ w3, const float* __restrict__ b3,
                            const float* __restrict__ w4, const float* __restrict__ b4,
                            float* __restrict__ out) {
  __shared__ float sp[768];
  __shared__ float st[96];
  int b = blockIdx.x, t = threadIdx.x;   // 128 threads
  for (int c = t; c < 768; c += 128) sp[c] = pooled[(size_t)b * 768 + c];
  __syncthreads();
  if (t < 96) {
    float s = b3[t];
    for (int r = 0; r < 768; ++r) s += sp[r] * w3[(size_t)r * 96 + t];
    s = LK(s);
    st[t] = s * w4[t];
  }
  __syncthreads();
  if (t == 0) {
    float s = b4[0];
    for (int i = 0; i < 96; ++i) s += st[i];
    out[b] = s;
  }
}

extern "C" void kernel_launch(void* const* d_in, const int* in_sizes, int n_in,
                              void* d_out, int out_size, void* d_ws, size_t ws_size,
                              hipStream_t stream) {
  (void)in_sizes; (void)n_in; (void)out_size;
  const float* x = (const float*)d_in[0];
  const float* P[25];
  for (int i = 0; i < 25; ++i) P[i] = (const float*)d_in[i];

  // Fused-nn1 (M-chunked, UV/h1c shared region): 238,292,992 B needed.
  constexpr size_t SZ_IDX = 1048576, SZ_FEAT = 50331648;
  constexpr size_t SZ_R = 33030144;            // UV (16384x504 f32) == h1c (32768x252 f32)
  constexpr size_t SZ_POOL = 786432, SZ_W = 1048576;
  constexpr size_t FUSED_WS = SZ_IDX + 4 * SZ_FEAT + SZ_R + SZ_POOL + 2 * SZ_W + 4096;
  const bool fused = (ws_size >= FUSED_WS);

  char* ws = (char*)d_ws;
  int*   idx; float *A, *Bb, *Cb, *Db, *h1, *UV, *pooled; char *Wsl1, *Wsl2; float* bcat;
  if (fused) {
    size_t o = 0;
    idx    = (int*)  (ws + o); o += SZ_IDX;
    A      = (float*)(ws + o); o += SZ_FEAT;
    Bb     = (float*)(ws + o); o += SZ_FEAT;
    Cb     = (float*)(ws + o); o += SZ_FEAT;
    Db     = (float*)(ws + o); o += SZ_FEAT;
    UV     = (float*)(ws + o); h1 = UV; o += SZ_R;   // time-shared: UV dies before h1c born
    pooled = (float*)(ws + o); o += SZ_POOL;
    Wsl1   =         (ws + o); o += SZ_W;
    Wsl2   =         (ws + o); o += SZ_W;
    bcat   = (float*)(ws + o);
  } else {
    // exact measured-R7 layout (peak ~203.7 MB)
    idx    = (int*)  (ws + 0);
    A      = (float*)(ws + 1048576);
    Bb     = (float*)(ws + 51380224);
    Cb     = A;  Db = Bb;                    // aliases (c overwrites a, d overwrites b)
    h1     = (float*)(ws + 101711872);
    UV     = (float*)(ws + 167772160);
    pooled = (float*)(ws + 200802304);
    Wsl1   =         (ws + 201588736);
    Wsl2   =         (ws + 202637312);
    bcat   = (float*)(ws + 203685888);
  }

  float*    wcat = (float*)   Wsl1;
  _Float16* WB1  = (_Float16*)Wsl1;
  _Float16* WB2  = (_Float16*)Wsl2;

  // ---- fp32 edge layer (layers 1,2: fully bit-exact) ----
  auto edge_layer_f32 = [&](const float* src, int F, int H1,
                            const float* w1, const float* b1,
                            const float* w2, const float* b2, float* dst) {
    knn_kernel<<<B_, N_, 0, stream>>>(src, F, idx);
    prep_uvw<<<(F * H1 + 255) / 256, 256, 0, stream>>>(w1, b1, F, H1, wcat, bcat);
    int W2 = 2 * H1;
    dim3 gUV((W2 + 63) / 64, CHUNK_ROWS / 128);
    for (int cb = 0; cb < B_; cb += CHUNK_B) {
      size_t base = (size_t)cb * N_;
      gemm_f32<false, false, true><<<gUV, 256, 0, stream>>>(src + base * F, wcat, bcat, UV, CHUNK_ROWS, W2, F);
      edge_stage2<<<CHUNK_ROWS / 16, 256, 0, stream>>>(UV, idx + base * 4, w2, b2, dst + base * 192, H1);
    }
  };

  // ---- fp16x3 edge layer (layer 4: output feeds no KNN) ----
  auto edge_layer_f16 = [&](const float* src, int F, int H1,
                            const float* w1, const float* b1,
                            const float* w2, const float* b2, float* dst) {
    int Fpad = (F + 31) & ~31;
    int KpadW2 = (H1 + 31) & ~31;
    int NN = 2 * H1;
    knn_kernel<<<B_, N_, 0, stream>>>(src, F, idx);
    prep_wcatT<<<(NN * Fpad + 255) / 256, 256, 0, stream>>>(w1, b1, F, H1, Fpad, WB1, bcat);
    prep_wT<<<(192 * KpadW2 + 255) / 256, 256, 0, stream>>>(w2, H1, 192, KpadW2, WB2);
    dim3 gUV((NN + 127) / 128, CHUNK_ROWS / 128);
    for (int cb = 0; cb < B_; cb += CHUNK_B) {
      size_t base = (size_t)cb * N_;
      gemm3h<false, false, true, false, false><<<gUV, 256, 0, stream>>>(
          src + base * F, src + base * F, nullptr, nullptr, F, WB1, bcat, nullptr, nullptr, UV, CHUNK_ROWS, NN, F, Fpad);
      edge_stage2_m<<<CHUNK_ROWS / 16, 256, 0, stream>>>(
          UV, idx + base * 4, WB2, b2, dst + base * 192, H1, KpadW2);
    }
  };

  // ---- hybrid c-layer: fp32 UV (exact) + fp16x3 stage2 + exact fp32 cols 0-2 ----
  auto edge_layer_c = [&](const float* src, float* dst) {
    const float* w1 = P[9]; const float* b1 = P[10];
    const float* w2 = P[11]; const float* b2 = P[12];
    int F = 192, H1 = 252, W2 = 504, KpadW2 = 256;
    knn_kernel<<<B_, N_, 0, stream>>>(src, F, idx);
    prep_uvw<<<(F * H1 + 255) / 256, 256, 0, stream>>>(w1, b1, F, H1, wcat, bcat);
    prep_wT<<<(192 * KpadW2 + 255) / 256, 256, 0, stream>>>(w2, H1, 192, KpadW2, WB2);
    dim3 gUV((W2 + 63) / 64, CHUNK_ROWS / 128);
    for (int cb = 0; cb < B_; cb += CHUNK_B) {
      size_t base = (size_t)cb * N_;
      gemm_f32<false, false, true><<<gUV, 256, 0, stream>>>(src + base * F, wcat, bcat, UV, CHUNK_ROWS, W2, F);
      edge_stage2_m<<<CHUNK_ROWS / 16, 256, 0, stream>>>(UV, idx + base * 4, WB2, b2, dst + base * 192, H1, KpadW2);
      edge_exact3<<<CHUNK_ROWS / 64, 256, 0, stream>>>(UV, idx + base * 4, w2, b2, dst + base * 192, H1);
    }
  };

  // a = edge(x) -> A ; b = edge(a) -> Bb      [fp32 exact: feed KNN 2,3 via full GEMMs]
  edge_layer_f32(x,  4,   96,  P[1], P[2], P[3], P[4], A);
  edge_layer_f32(A,  192, 252, P[5], P[6], P[7], P[8], Bb);

  if (fused) {
    // c = edge(b) -> Cb ; d = edge(c) -> Db  (a,b stay live; UV region still in use)
    edge_layer_c(Bb, Cb);
    edge_layer_f16(Cb, 192, 252, P[13], P[14], P[15], P[16], Db);
    // Fused nn1 (K=768, one chain) + nn2, M-chunked at 32768 rows.
    // h1c shares the (now dead) UV region. nn2-chunk writes only A-rows its own
    // nn1-chunk already consumed; later nn1-chunks read higher rows only.
    prep_wT<<<(252 * 768 + 255) / 256, 256, 0, stream>>>(P[17] + 4 * 252, 768, 252, 768, WB1);
    prep_wT<<<(192 * 256 + 255) / 256, 256, 0, stream>>>(P[19], 252, 192, 256, WB2);
    dim3 g(2, 256);
    for (int mc = 0; mc < 2; ++mc) {
      size_t roff = (size_t)mc * 32768;
      gemm3h<false, false, true, true, true><<<g, 256, 0, stream>>>(
          A + roff * 192, Bb + roff * 192, Cb + roff * 192, Db + roff * 192, 0,
          WB1, P[18], x + roff * 4, P[17], h1, 32768, 252, 768, 768);
      gemm3h<true, false, true, false, false><<<g, 256, 0, stream>>>(
          h1, h1, nullptr, nullptr, 252, WB2, P[20], nullptr, nullptr,
          A + roff * 192, 32768, 192, 252, 256);
    }
  } else {
    // h1 = [x,a,b] @ nn1w[0:388] + nn1b
    prep_wT<<<(252 * 384 + 255) / 256, 256, 0, stream>>>(P[17] + 4 * 252, 384, 252, 384, WB1);
    dim3 g(2, BN / 128);
    gemm3h<false, false, true, true, false><<<g, 256, 0, stream>>>(
        A, Bb, nullptr, nullptr, 192, WB1, P[18], x, P[17], h1, BN, 252, 384, 384);
    // c = edge(b) -> A (overwrites a) ; d = edge(c) -> Bb
    edge_layer_c(Bb, Cb);
    edge_layer_f16(Cb, 192, 252, P[13], P[14], P[15], P[16], Db);
    // h1 += [c,d] @ nn1w[388:772]
    prep_wT<<<(252 * 384 + 255) / 256, 256, 0, stream>>>(P[17] + (size_t)388 * 252, 384, 252, 384, WB1);
    gemm3h<false, true, false, false, false><<<g, 256, 0, stream>>>(
        Cb, Db, nullptr, nullptr, 192, WB1, nullptr, nullptr, nullptr, h1, BN, 252, 384, 384);
    // nn2: h2 = leaky(h1) @ nn2w + nn2b -> A
    prep_wT<<<(192 * 256 + 255) / 256, 256, 0, stream>>>(P[19], 252, 192, 256, WB2);
    gemm3h<true, false, true, false, false><<<g, 256, 0, stream>>>(
        h1, h1, nullptr, nullptr, 252, WB2, P[20], nullptr, nullptr, A, BN, 192, 252, 256);
  }

  pool_kernel<<<B_, 192, 0, stream>>>(A, pooled);
  head_kernel<<<B_, 128, 0, stream>>>(pooled, P[21], P[22], P[23], P[24], (float*)d_out);
}

// Round 14
// 1895.036 us; speedup vs baseline: 1.0645x; 1.0099x over previous
//
#include <hip/hip_runtime.h>
#include <cstdint>
#include <cstddef>

#define LK(x) ((x) > 0.f ? (x) : 0.01f * (x))

typedef _Float16 f16x8 __attribute__((ext_vector_type(8)));
typedef _Float16 f16x4 __attribute__((ext_vector_type(4)));
typedef float f32x4 __attribute__((ext_vector_type(4)));

constexpr int B_ = 256;
constexpr int N_ = 256;
constexpr int BN = B_ * N_;
constexpr int CHUNK_B = 64;                 // batches per UV chunk
constexpr int CHUNK_ROWS = CHUNK_B * N_;    // 16384 rows

// fp16 2-way split (for fp16x3 path)
__device__ inline void dec2(float v, _Float16& h, _Float16& l) {
  _Float16 hh = (_Float16)v;
  h = hh;
  l = (_Float16)(v - (float)hh);
}

// ---------------- KNN: one block per batch, one thread per point ----------------
__global__ void knn_kernel(const float* __restrict__ feat, int F, int* __restrict__ idxout) {
  __shared__ float px[N_], py[N_], pz[N_];
  int b = blockIdx.x, t = threadIdx.x;
  const float* row = feat + ((size_t)b * N_ + t) * F;
  px[t] = row[0]; py[t] = row[1]; pz[t] = row[2];
  __syncthreads();
  float x = px[t], y = py[t], z = pz[t];
  float bd0 = INFINITY, bd1 = INFINITY, bd2 = INFINITY, bd3 = INFINITY;
  int bi0 = 0, bi1 = 0, bi2 = 0, bi3 = 0;
  for (int j = 0; j < N_; ++j) {
    #pragma clang fp contract(off)
    float dx = x - px[j], dy = y - py[j], dz = z - pz[j];
    float d = (dx * dx + dy * dy) + dz * dz;
    if (j == t) continue;
    if (d < bd3) {
      if (d < bd2) {
        bd3 = bd2; bi3 = bi2;
        if (d < bd1) {
          bd2 = bd1; bi2 = bi1;
          if (d < bd0) { bd1 = bd0; bi1 = bi0; bd0 = d; bi0 = j; }
          else         { bd1 = d; bi1 = j; }
        } else         { bd2 = d; bi2 = j; }
      } else           { bd3 = d; bi3 = j; }
    }
  }
  int* o = idxout + ((size_t)b * N_ + t) * 4;
  o[0] = bi0; o[1] = bi1; o[2] = bi2; o[3] = bi3;
}

// ============================ fp32 path (bit-exact chain) ============================

// wcat = [w1_top - w1_bot | w1_bot] (F x 2H1), bcat = [b1 | 0]
__global__ void prep_uvw(const float* __restrict__ w1, const float* __restrict__ b1,
                         int F, int H1, float* __restrict__ wcat, float* __restrict__ bcat) {
  int t = blockIdx.x * 256 + threadIdx.x;
  int FH = F * H1;
  if (t < FH) {
    int k = t / H1, c = t - k * H1;
    float top = w1[(size_t)k * H1 + c];
    float bot = w1[(size_t)(F + k) * H1 + c];
    wcat[(size_t)k * 2 * H1 + c]      = top - bot;
    wcat[(size_t)k * 2 * H1 + H1 + c] = bot;
  }
  if (t < H1) { bcat[t] = b1[t]; bcat[H1 + t] = 0.f; }
}

// fp32 GEMM: 128x64 tile, BK=16, 256 thr, 8x4 micro.
// 1-DEEP REGISTER PREFETCH (R13-measured WIN: kept verbatim).
template<bool ACT_A, bool ACCUM, bool HAS_BIAS>
__global__ __launch_bounds__(256) void gemm_f32(
    const float* __restrict__ A, const float* __restrict__ W,
    const float* __restrict__ bias, float* __restrict__ C,
    int M, int N, int K) {
  __shared__ float sA[16][132];
  __shared__ float sW[16][68];
  int tid = threadIdx.x;
  int m0 = blockIdx.y * 128;
  int n0 = blockIdx.x * 64;
  int kkA = tid & 15, mA = tid >> 4;
  int nW = tid & 63, kW = tid >> 6;
  int ty = tid >> 4, tx = tid & 15;
  float acc[8][4] = {};
  float pa[8], pw[4];

#define G_LD(K0)                                                  \
  { int kg_ = (K0) + kkA;                                         \
    _Pragma("unroll")                                             \
    for (int i = 0; i < 8; ++i) {                                 \
      int m = mA + i * 16;                                        \
      float v = 0.f;                                              \
      if (kg_ < K) {                                              \
        v = A[(size_t)(m0 + m) * K + kg_];                        \
        if (ACT_A) v = LK(v);                                     \
      }                                                           \
      pa[i] = v;                                                  \
    }                                                             \
    _Pragma("unroll")                                             \
    for (int q = 0; q < 4; ++q) {                                 \
      int kk = kW + q * 4;                                        \
      int kgw = (K0) + kk, n = n0 + nW;                           \
      float v = 0.f;                                              \
      if (kgw < K && n < N) v = W[(size_t)kgw * N + n];           \
      pw[q] = v;                                                  \
    } }

  G_LD(0)

  for (int k0 = 0; k0 < K; k0 += 16) {
    __syncthreads();           // previous compute finished reading LDS
    #pragma unroll
    for (int i = 0; i < 8; ++i) sA[kkA][mA + i * 16] = pa[i];
    #pragma unroll
    for (int q = 0; q < 4; ++q) sW[kW + q * 4][nW] = pw[q];
    if (k0 + 16 < K) { G_LD(k0 + 16) }
    __syncthreads();
    #pragma unroll
    for (int kk = 0; kk < 16; ++kk) {
      float4 a0 = *(const float4*)&sA[kk][ty * 8];
      float4 a1 = *(const float4*)&sA[kk][ty * 8 + 4];
      float4 w  = *(const float4*)&sW[kk][tx * 4];
      float av[8] = {a0.x, a0.y, a0.z, a0.w, a1.x, a1.y, a1.z, a1.w};
      float wv[4] = {w.x, w.y, w.z, w.w};
      #pragma unroll
      for (int i = 0; i < 8; ++i)
        #pragma unroll
        for (int j = 0; j < 4; ++j)
          acc[i][j] += av[i] * wv[j];
    }
  }
#undef G_LD
  int n = n0 + tx * 4;
  float bv[4] = {0.f, 0.f, 0.f, 0.f};
  if (HAS_BIAS) {
    #pragma unroll
    for (int j = 0; j < 4; ++j) if (n + j < N) bv[j] = bias[n + j];
  }
  #pragma unroll
  for (int i = 0; i < 8; ++i) {
    size_t m = (size_t)(m0 + ty * 8 + i);
    if (n + 3 < N) {
      float4 o;
      o.x = acc[i][0] + bv[0]; o.y = acc[i][1] + bv[1];
      o.z = acc[i][2] + bv[2]; o.w = acc[i][3] + bv[3];
      float4* cp = (float4*)(C + m * N + n);
      if (ACCUM) { float4 c = *cp; o.x += c.x; o.y += c.y; o.z += c.z; o.w += c.w; }
      *cp = o;
    } else {
      #pragma unroll
      for (int j = 0; j < 4; ++j) {
        if (n + j < N) {
          float v = acc[i][j] + bv[j];
          size_t off = m * N + n + j;
          if (ACCUM) v += C[off];
          C[off] = v;
        }
      }
    }
  }
}

// fp32 fused edge stage 2, K-tiled — layers 1,2.
// REVERTED to the R12-measured 16-pt version (VGPR 52, occ ~31%, 91.4 us):
// R13's prefetch pushed VGPR 52->88, occupancy 31->19%, and regressed it.
__global__ __launch_bounds__(256) void edge_stage2(
    const float* __restrict__ UV, const int* __restrict__ idx,
    const float* __restrict__ w2, const float* __restrict__ b2,
    float* __restrict__ out, int H1) {
  __shared__ float sH[16][68];
  __shared__ float sW[16][196];
  __shared__ int sJ[64];
  int tid = threadIdx.x;
  int g0 = blockIdx.x * 16;
  int bbase = (g0 >> 8) << 8;
  if (tid < 64) sJ[tid] = bbase + idx[(size_t)g0 * 4 + tid];
  int W2 = H1 * 2;
  int r = tid >> 2, seg = tid & 3;
  int gp_r = g0 + (r >> 2);
  int ty = tid >> 4, tx = tid & 15;
  int gp = g0 + ty;
  float acc[4][12] = {};
  int nKt = (H1 + 15) >> 4;
  for (int kt = 0; kt < nKt; ++kt) {
    int k0 = kt << 4;
    __syncthreads();
    {
      int c = k0 + (seg << 2);
      const float* up = UV + (size_t)gp_r * W2 + c;
      const float* vp = UV + (size_t)sJ[r] * W2 + H1 + c;
      float u[4], v[4];
      if (c + 3 < H1) {
        float4 uu = *(const float4*)up; float4 vv = *(const float4*)vp;
        u[0] = uu.x; u[1] = uu.y; u[2] = uu.z; u[3] = uu.w;
        v[0] = vv.x; v[1] = vv.y; v[2] = vv.z; v[3] = vv.w;
      } else {
        #pragma unroll
        for (int j = 0; j < 4; ++j) {
          u[j] = (c + j < H1) ? up[j] : 0.f;
          v[j] = (c + j < H1) ? vp[j] : 0.f;
        }
      }
      #pragma unroll
      for (int j = 0; j < 4; ++j) {
        float t = u[j] + v[j];
        sH[(seg << 2) + j][r] = (c + j < H1) ? LK(t) : 0.f;
      }
    }
    #pragma unroll
    for (int p = 0; p < 3; ++p) {
      int q = tid + (p << 8);
      int kk = q / 48;
      int c4 = q - kk * 48;
      int k = k0 + kk;
      float4 wv = {0.f, 0.f, 0.f, 0.f};
      if (k < H1) wv = *(const float4*)(w2 + (size_t)k * 192 + (c4 << 2));
      *(float4*)&sW[kk][c4 << 2] = wv;
    }
    __syncthreads();
    #pragma unroll
    for (int kk = 0; kk < 16; ++kk) {
      float4 a = *(const float4*)&sH[kk][ty << 2];
      float av[4] = {a.x, a.y, a.z, a.w};
      #pragma unroll
      for (int ct = 0; ct < 3; ++ct) {
        float4 w = *(const float4*)&sW[kk][ct * 64 + (tx << 2)];
        float wv[4] = {w.x, w.y, w.z, w.w};
        #pragma unroll
        for (int i = 0; i < 4; ++i)
          #pragma unroll
          for (int j = 0; j < 4; ++j)
            acc[i][ct * 4 + j] += av[i] * wv[j];
      }
    }
  }
  #pragma unroll
  for (int ct = 0; ct < 3; ++ct) {
    float o[4];
    #pragma unroll
    for (int j = 0; j < 4; ++j) {
      int col = ct * 64 + (tx << 2) + j;
      float bvv = b2[col];
      float s = 0.f;
      #pragma unroll
      for (int i = 0; i < 4; ++i) {
        float t = acc[i][ct * 4 + j] + bvv;
        s += LK(t);
      }
      o[j] = s;
    }
    float4 ov = {o[0], o[1], o[2], o[3]};
    *(float4*)(out + (size_t)gp * 192 + ct * 64 + (tx << 2)) = ov;
  }
}

// exact fp32 replica of stage2 for cols 0..2 ONLY (the KNN-feeding columns).
__global__ __launch_bounds__(256) void edge_exact3(
    const float* __restrict__ UV, const int* __restrict__ idx,
    const float* __restrict__ w2, const float* __restrict__ b2,
    float* __restrict__ out, int H1) {
  __shared__ float sw[252 * 4];
  int tid = threadIdx.x;
  for (int k = tid; k < H1; k += 256) {
    sw[k * 4 + 0] = w2[(size_t)k * 192 + 0];
    sw[k * 4 + 1] = w2[(size_t)k * 192 + 1];
    sw[k * 4 + 2] = w2[(size_t)k * 192 + 2];
    sw[k * 4 + 3] = 0.f;
  }
  __syncthreads();
  int p = blockIdx.x * 64 + (tid >> 2);   // chunk-local point
  int e = tid & 3;
  int bbase = (p >> 8) << 8;
  int j = bbase + idx[(size_t)p * 4 + e];
  int W2 = 2 * H1;
  const float* up = UV + (size_t)p * W2;
  const float* vp = UV + (size_t)j * W2 + H1;
  float a0 = 0.f, a1 = 0.f, a2 = 0.f;
  int k = 0;
  for (; k + 3 < H1; k += 4) {
    float4 u = *(const float4*)(up + k);
    float4 v = *(const float4*)(vp + k);
    float h0 = LK(u.x + v.x), h1 = LK(u.y + v.y);
    float h2 = LK(u.z + v.z), h3 = LK(u.w + v.w);
    float4 w0 = *(const float4*)&sw[(k + 0) * 4];
    float4 w1 = *(const float4*)&sw[(k + 1) * 4];
    float4 w2v = *(const float4*)&sw[(k + 2) * 4];
    float4 w3 = *(const float4*)&sw[(k + 3) * 4];
    a0 = __builtin_fmaf(h0, w0.x, a0); a1 = __builtin_fmaf(h0, w0.y, a1); a2 = __builtin_fmaf(h0, w0.z, a2);
    a0 = __builtin_fmaf(h1, w1.x, a0); a1 = __builtin_fmaf(h1, w1.y, a1); a2 = __builtin_fmaf(h1, w1.z, a2);
    a0 = __builtin_fmaf(h2, w2v.x, a0); a1 = __builtin_fmaf(h2, w2v.y, a1); a2 = __builtin_fmaf(h2, w2v.z, a2);
    a0 = __builtin_fmaf(h3, w3.x, a0); a1 = __builtin_fmaf(h3, w3.y, a1); a2 = __builtin_fmaf(h3, w3.z, a2);
  }
  for (; k < H1; ++k) {
    float h = LK(up[k] + vp[k]);
    a0 = __builtin_fmaf(h, sw[k * 4 + 0], a0);
    a1 = __builtin_fmaf(h, sw[k * 4 + 1], a1);
    a2 = __builtin_fmaf(h, sw[k * 4 + 2], a2);
  }
  float acc3[3] = {a0, a1, a2};
  #pragma unroll
  for (int c = 0; c < 3; ++c) {
    float t = acc3[c] + b2[c];
    float pc = LK(t);
    float q1 = __shfl_down(pc, 1);
    float q2 = __shfl_down(pc, 2);
    float q3 = __shfl_down(pc, 3);
    if (e == 0) {
      float s = ((pc + q1) + q2) + q3;   // e-ascending order, matches edge_stage2 epilogue
      out[(size_t)p * 192 + c] = s;
    }
  }
}

// ====================== fp16x3 MFMA path (noise-tolerant GEMMs) ======================

// Wp[n][k-octets]: [8 hi | 8 lo]; [wdiff | wbot] transposed. bcat = [b1|0]
__global__ void prep_wcatT(const float* __restrict__ w1, const float* __restrict__ b1,
                           int F, int H1, int Fpad, _Float16* __restrict__ Wp,
                           float* __restrict__ bcat) {
  int t = blockIdx.x * 256 + threadIdx.x;
  int NN = 2 * H1;
  if (t < NN * Fpad) {
    int n = t / Fpad, k = t - n * Fpad;
    float v = 0.f;
    if (k < F) {
      if (n < H1) v = w1[(size_t)k * H1 + n] - w1[(size_t)(F + k) * H1 + n];
      else        v = w1[(size_t)(F + k) * H1 + (n - H1)];
    }
    _Float16 h, l; dec2(v, h, l);
    size_t base = (size_t)n * 2 * Fpad + (size_t)(k >> 3) * 16 + (k & 7);
    Wp[base] = h; Wp[base + 8] = l;
  }
  if (t < NN) bcat[t] = (t < H1) ? b1[t] : 0.f;
}

__global__ void prep_wT(const float* __restrict__ W, int K, int N, int Kpad,
                        _Float16* __restrict__ Wp) {
  int t = blockIdx.x * 256 + threadIdx.x;
  if (t >= N * Kpad) return;
  int n = t / Kpad, k = t - n * Kpad;
  float v = (k < K) ? W[(size_t)k * N + n] : 0.f;
  _Float16 h, l; dec2(v, h, l);
  size_t base = (size_t)n * 2 * Kpad + (size_t)(k >> 3) * 16 + (k & 7);
  Wp[base] = h; Wp[base + 8] = l;
}

// fp16x3 MFMA GEMM. Block 128x128, 4 waves (2x2), K-step 32.
// PIPELINED (1-deep reg prefetch) + LDS-TRANSPOSE EPILOGUE (measured R7).
// CAT4: A is the concatenation [A0|A1|A2|A3], each 192 cols (fused nn1, K=768).
template<bool ACT_A, bool ACCUM, bool HAS_BIAS, bool XB, bool CAT4>
__global__ __launch_bounds__(256) void gemm3h(
    const float* __restrict__ A0, const float* __restrict__ A1,
    const float* __restrict__ A2, const float* __restrict__ A3, int w0,
    const _Float16* __restrict__ Wp, const float* __restrict__ bias,
    const float* __restrict__ X, const float* __restrict__ Wx,
    float* __restrict__ C, int M, int N, int K, int Kpad) {
  __shared__ _Float16 sAB[2 * 128 * 72];   // sA | sB ; reused as float sT[128][72]
  _Float16* sA = sAB;
  _Float16* sB = sAB + 128 * 72;
  float* sT = (float*)sAB;
  int tid = threadIdx.x;
  int m0 = blockIdx.y * 128, n0 = blockIdx.x * 128;
  int lane = tid & 63, wid = tid >> 6;
  int wy = wid >> 1, wx = wid & 1;
  int lm = lane & 15, lq = lane >> 4;
  int rA = tid >> 1, qA = (tid & 1) * 4;
  f32x4 acc[4][4];
  #pragma unroll
  for (int i = 0; i < 4; ++i)
    #pragma unroll
    for (int j = 0; j < 4; ++j) acc[i][j] = 0.f;

  float4 pa0, pa1, pa2, pa3, pb0, pb1, pb2, pb3;

#define LOADA_ONE(KL, DST)                                          \
  { int kl_ = (KL); float4 v_ = {0.f, 0.f, 0.f, 0.f};               \
    if (kl_ + 3 < wA) v_ = *(const float4*)(arow + kl_);            \
    else {                                                          \
      if (kl_ + 0 < wA) v_.x = arow[kl_ + 0];                       \
      if (kl_ + 1 < wA) v_.y = arow[kl_ + 1];                       \
      if (kl_ + 2 < wA) v_.z = arow[kl_ + 2]; }                     \
    DST = v_; }

#define LOAD_AB(K0)                                                 \
  { int k0_ = (K0);                                                 \
    const float* Ap; int kb, wA;                                    \
    if (CAT4) {                                                     \
      int s_ = k0_ / 192;                                           \
      Ap = (s_ == 0) ? A0 : (s_ == 1) ? A1 : (s_ == 2) ? A2 : A3;   \
      kb = k0_ - s_ * 192; wA = 192;                                \
    } else if (k0_ < w0) { Ap = A0; kb = k0_;      wA = w0; }       \
    else                 { Ap = A1; kb = k0_ - w0; wA = K - w0; }   \
    const float* arow = Ap + (size_t)(m0 + rA) * wA;                \
    LOADA_ONE(kb + (qA + 0) * 4, pa0)                               \
    LOADA_ONE(kb + (qA + 1) * 4, pa1)                               \
    LOADA_ONE(kb + (qA + 2) * 4, pa2)                               \
    LOADA_ONE(kb + (qA + 3) * 4, pa3)                               \
    int n_ = n0 + rA;                                               \
    const _Float16* src = Wp + (size_t)n_ * 2 * Kpad + (size_t)k0_ * 2; \
    float4 z_ = {0.f, 0.f, 0.f, 0.f};                               \
    if (n_ < N) {                                                   \
      pb0 = *(const float4*)(src + (qA + 0) * 8);                   \
      pb1 = *(const float4*)(src + (qA + 1) * 8);                   \
      pb2 = *(const float4*)(src + (qA + 2) * 8);                   \
      pb3 = *(const float4*)(src + (qA + 3) * 8);                   \
    } else { pb0 = z_; pb1 = z_; pb2 = z_; pb3 = z_; } }

#define ST_A(V, Q)                                                  \
  { float4 t_ = (V);                                                \
    if (ACT_A) { t_.x = LK(t_.x); t_.y = LK(t_.y);                  \
                 t_.z = LK(t_.z); t_.w = LK(t_.w); }                \
    _Float16 h0,h1,h2,h3,l0,l1,l2,l3;                               \
    dec2(t_.x,h0,l0); dec2(t_.y,h1,l1);                             \
    dec2(t_.z,h2,l2); dec2(t_.w,h3,l3);                             \
    int off_ = rA * 72 + ((Q) >> 1) * 16 + ((Q) & 1) * 4;           \
    f16x4 th; th[0]=h0; th[1]=h1; th[2]=h2; th[3]=h3;               \
    f16x4 tl; tl[0]=l0; tl[1]=l1; tl[2]=l2; tl[3]=l3;               \
    *(f16x4*)&sA[off_]     = th;                                    \
    *(f16x4*)&sA[off_ + 8] = tl; }

  LOAD_AB(0)

  for (int k0 = 0; k0 < Kpad; k0 += 32) {
    __syncthreads();
    ST_A(pa0, qA + 0)
    ST_A(pa1, qA + 1)
    ST_A(pa2, qA + 2)
    ST_A(pa3, qA + 3)
    *(float4*)&sB[rA * 72 + (qA + 0) * 8] = pb0;
    *(float4*)&sB[rA * 72 + (qA + 1) * 8] = pb1;
    *(float4*)&sB[rA * 72 + (qA + 2) * 8] = pb2;
    *(float4*)&sB[rA * 72 + (qA + 3) * 8] = pb3;
    if (k0 + 32 < Kpad) { LOAD_AB(k0 + 32) }
    __syncthreads();
    f16x8 af[4][2], bf[4][2];
    #pragma unroll
    for (int mt = 0; mt < 4; ++mt) {
      int row = wy * 64 + mt * 16 + lm;
      af[mt][0] = *(const f16x8*)&sA[row * 72 + lq * 16];
      af[mt][1] = *(const f16x8*)&sA[row * 72 + lq * 16 + 8];
    }
    #pragma unroll
    for (int nt = 0; nt < 4; ++nt) {
      int row = wx * 64 + nt * 16 + lm;
      bf[nt][0] = *(const f16x8*)&sB[row * 72 + lq * 16];
      bf[nt][1] = *(const f16x8*)&sB[row * 72 + lq * 16 + 8];
    }
    #pragma unroll
    for (int mt = 0; mt < 4; ++mt)
      #pragma unroll
      for (int nt = 0; nt < 4; ++nt) {
        acc[mt][nt] = __builtin_amdgcn_mfma_f32_16x16x32_f16(af[mt][0], bf[nt][0], acc[mt][nt], 0, 0, 0);
        acc[mt][nt] = __builtin_amdgcn_mfma_f32_16x16x32_f16(af[mt][0], bf[nt][1], acc[mt][nt], 0, 0, 0);
        acc[mt][nt] = __builtin_amdgcn_mfma_f32_16x16x32_f16(af[mt][1], bf[nt][0], acc[mt][nt], 0, 0, 0);
      }
  }
#undef LOADA_ONE
#undef LOAD_AB
#undef ST_A

  // ---- staged, coalesced epilogue: two wx-halves through LDS ----
  int rbase = tid >> 4;          // 0..15
  int c4 = (tid & 15) << 2;      // 0..60
  #pragma unroll
  for (int half = 0; half < 2; ++half) {
    __syncthreads();
    if (wx == half) {
      #pragma unroll
      for (int mt = 0; mt < 4; ++mt)
        #pragma unroll
        for (int nt = 0; nt < 4; ++nt)
          #pragma unroll
          for (int r = 0; r < 4; ++r)
            sT[(wy * 64 + mt * 16 + lq * 4 + r) * 72 + nt * 16 + lm] = acc[mt][nt][r];
    }
    __syncthreads();
    int n = n0 + half * 64 + c4;
    float bv[4] = {0.f, 0.f, 0.f, 0.f};
    if (HAS_BIAS || XB) {
      #pragma unroll
      for (int j = 0; j < 4; ++j) if (n + j < N) bv[j] = bias[n + j];
    }
    float wxv0[4], wxv1[4], wxv2[4], wxv3[4];
    if (XB) {
      #pragma unroll
      for (int j = 0; j < 4; ++j) {
        wxv0[j] = (n + j < N) ? Wx[n + j] : 0.f;
        wxv1[j] = (n + j < N) ? Wx[N + n + j] : 0.f;
        wxv2[j] = (n + j < N) ? Wx[2 * N + n + j] : 0.f;
        wxv3[j] = (n + j < N) ? Wx[3 * N + n + j] : 0.f;
      }
    }
    #pragma unroll
    for (int it = 0; it < 8; ++it) {
      int row = it * 16 + rbase;
      size_t m = (size_t)m0 + row;
      float4 t = *(const float4*)&sT[row * 72 + c4];
      float o[4] = {t.x, t.y, t.z, t.w};
      if (XB) {
        float4 xv = *(const float4*)(X + m * 4);
        #pragma unroll
        for (int j = 0; j < 4; ++j)
          o[j] = o[j] + bv[j] + (xv.x * wxv0[j] + xv.y * wxv1[j] + xv.z * wxv2[j] + xv.w * wxv3[j]);
      } else {
        #pragma unroll
        for (int j = 0; j < 4; ++j) o[j] += bv[j];
      }
      if (n + 3 < N) {
        float4* cp = (float4*)(C + m * N + n);
        if (ACCUM) { float4 c = *cp; o[0] += c.x; o[1] += c.y; o[2] += c.z; o[3] += c.w; }
        float4 ov = {o[0], o[1], o[2], o[3]};
        *cp = ov;
      } else {
        #pragma unroll
        for (int j = 0; j < 4; ++j) {
          if (n + j < N) {
            float v = o[j];
            size_t off = m * N + n + j;
            if (ACCUM) v += C[off];
            C[off] = v;
          }
        }
      }
    }
  }
}

// fp16x3 fused edge stage 2 (layers 3 cols + layer 4)
__global__ __launch_bounds__(256) void edge_stage2_m(
    const float* __restrict__ UV, const int* __restrict__ idx,
    const _Float16* __restrict__ Wp, const float* __restrict__ b2,
    float* __restrict__ out, int H1, int Kpad) {
  __shared__ _Float16 sH[64 * 72];
  __shared__ _Float16 sW[192 * 72];
  __shared__ int sJ[64];
  int tid = threadIdx.x;
  int g0 = blockIdx.x * 16;
  int bbase = (g0 >> 8) << 8;
  if (tid < 64) sJ[tid] = bbase + idx[(size_t)g0 * 4 + tid];
  int W2 = 2 * H1;
  int lane = tid & 63, w = tid >> 6;
  int lm = lane & 15, lq = lane >> 4;
  int rS = tid >> 2, qS = tid & 3;
  f32x4 acc[4][3];
  #pragma unroll
  for (int i = 0; i < 4; ++i)
    #pragma unroll
    for (int j = 0; j < 3; ++j) acc[i][j] = 0.f;

  for (int k0 = 0; k0 < Kpad; k0 += 32) {
    __syncthreads();
    {
      int gp_r = g0 + (rS >> 2);
      int jr = sJ[rS];
      const float* up = UV + (size_t)gp_r * W2;
      const float* vp = UV + (size_t)jr * W2 + H1;
      #pragma unroll
      for (int hf = 0; hf < 2; ++hf) {
        int k = k0 + qS * 8 + hf * 4;
        float4 u = {0.f,0.f,0.f,0.f}, v = {0.f,0.f,0.f,0.f};
        if (k + 3 < H1) { u = *(const float4*)(up + k); v = *(const float4*)(vp + k); }
        else {
          if (k + 0 < H1) { u.x = up[k+0]; v.x = vp[k+0]; }
          if (k + 1 < H1) { u.y = up[k+1]; v.y = vp[k+1]; }
          if (k + 2 < H1) { u.z = up[k+2]; v.z = vp[k+2]; }
        }
        float e0 = LK(u.x + v.x), e1 = LK(u.y + v.y), e2 = LK(u.z + v.z), e3 = LK(u.w + v.w);
        _Float16 h0,h1,h2,h3,l0,l1,l2,l3;
        dec2(e0,h0,l0); dec2(e1,h1,l1); dec2(e2,h2,l2); dec2(e3,h3,l3);
        int off = rS * 72 + qS * 16 + hf * 4;
        f16x4 th; th[0]=h0; th[1]=h1; th[2]=h2; th[3]=h3;
        f16x4 tl; tl[0]=l0; tl[1]=l1; tl[2]=l2; tl[3]=l3;
        *(f16x4*)&sH[off]     = th;
        *(f16x4*)&sH[off + 8] = tl;
      }
    }
    {
      const _Float16* src = Wp + (size_t)k0 * 2;
      #pragma unroll
      for (int p = 0; p < 6; ++p) {
        int e = tid + p * 256;
        int n = e >> 3, u = e & 7;
        *(float4*)&sW[n * 72 + u * 8] =
            *(const float4*)(src + (size_t)n * 2 * Kpad + u * 8);
      }
    }
    __syncthreads();
    f16x8 af[4][2], bf[3][2];
    #pragma unroll
    for (int mt = 0; mt < 4; ++mt) {
      int row = mt * 16 + lm;
      af[mt][0] = *(const f16x8*)&sH[row * 72 + lq * 16];
      af[mt][1] = *(const f16x8*)&sH[row * 72 + lq * 16 + 8];
    }
    #pragma unroll
    for (int t3 = 0; t3 < 3; ++t3) {
      int row = (w * 3 + t3) * 16 + lm;
      bf[t3][0] = *(const f16x8*)&sW[row * 72 + lq * 16];
      bf[t3][1] = *(const f16x8*)&sW[row * 72 + lq * 16 + 8];
    }
    #pragma unroll
    for (int mt = 0; mt < 4; ++mt)
      #pragma unroll
      for (int t3 = 0; t3 < 3; ++t3) {
        acc[mt][t3] = __builtin_amdgcn_mfma_f32_16x16x32_f16(af[mt][0], bf[t3][0], acc[mt][t3], 0, 0, 0);
        acc[mt][t3] = __builtin_amdgcn_mfma_f32_16x16x32_f16(af[mt][0], bf[t3][1], acc[mt][t3], 0, 0, 0);
        acc[mt][t3] = __builtin_amdgcn_mfma_f32_16x16x32_f16(af[mt][1], bf[t3][0], acc[mt][t3], 0, 0, 0);
      }
  }
  #pragma unroll
  for (int mt = 0; mt < 4; ++mt) {
    int gp = g0 + mt * 4 + lq;
    #pragma unroll
    for (int t3 = 0; t3 < 3; ++t3) {
      int col = (w * 3 + t3) * 16 + lm;
      float bv = b2[col];
      float s = 0.f;
      #pragma unroll
      for (int r = 0; r < 4; ++r) s += LK(acc[mt][t3][r] + bv);
      out[(size_t)gp * 192 + col] = s;
    }
  }
}

// ---------------- pooling ----------------
__global__ void pool_kernel(const float* __restrict__ h, float* __restrict__ pooled) {
  int b = blockIdx.x, ch = threadIdx.x;  // 192 threads
  const float* p = h + (size_t)b * N_ * 192 + ch;
  float mx = -INFINITY, mn = INFINITY, sm = 0.f;
  for (int n = 0; n < N_; ++n) {
    float v = p[(size_t)n * 192];
    mx = fmaxf(mx, v); mn = fminf(mn, v); sm += v;
  }
  float* o = pooled + (size_t)b * 768;
  o[ch]       = LK(mx);
  o[192 + ch] = LK(mn);
  o[384 + ch] = LK(sm);
  o[576 + ch] = LK(sm * (1.f / 256.f));
}

// ---------------- head ----------------
__global__ void head_kernel(const float* __restrict__ pooled,
                            const float* __restrict__ w3, const float* __restrict__ b3,
                            const float* __restrict__ w4, const float* __restrict__ b4,
                            float* __restrict__ out) {
  __shared__ float sp[768];
  __shared__ float st[96];
  int b = blockIdx.x, t = threadIdx.x;   // 128 threads
  for (int c = t; c < 768; c += 128) sp[c] = pooled[(size_t)b * 768 + c];
  __syncthreads();
  if (t < 96) {
    float s = b3[t];
    for (int r = 0; r < 768; ++r) s += sp[r] * w3[(size_t)r * 96 + t];
    s = LK(s);
    st[t] = s * w4[t];
  }
  __syncthreads();
  if (t == 0) {
    float s = b4[0];
    for (int i = 0; i < 96; ++i) s += st[i];
    out[b] = s;
  }
}

extern "C" void kernel_launch(void* const* d_in, const int* in_sizes, int n_in,
                              void* d_out, int out_size, void* d_ws, size_t ws_size,
                              hipStream_t stream) {
  (void)in_sizes; (void)n_in; (void)out_size;
  const float* x = (const float*)d_in[0];
  const float* P[25];
  for (int i = 0; i < 25; ++i) P[i] = (const float*)d_in[i];

  // Fused-nn1 (M-chunked, UV/h1c shared region): 238,292,992 B needed.
  constexpr size_t SZ_IDX = 1048576, SZ_FEAT = 50331648;
  constexpr size_t SZ_R = 33030144;            // UV (16384x504 f32) == h1c (32768x252 f32)
  constexpr size_t SZ_POOL = 786432, SZ_W = 1048576;
  constexpr size_t FUSED_WS = SZ_IDX + 4 * SZ_FEAT + SZ_R + SZ_POOL + 2 * SZ_W + 4096;
  const bool fused = (ws_size >= FUSED_WS);

  char* ws = (char*)d_ws;
  int*   idx; float *A, *Bb, *Cb, *Db, *h1, *UV, *pooled; char *Wsl1, *Wsl2; float* bcat;
  if (fused) {
    size_t o = 0;
    idx    = (int*)  (ws + o); o += SZ_IDX;
    A      = (float*)(ws + o); o += SZ_FEAT;
    Bb     = (float*)(ws + o); o += SZ_FEAT;
    Cb     = (float*)(ws + o); o += SZ_FEAT;
    Db     = (float*)(ws + o); o += SZ_FEAT;
    UV     = (float*)(ws + o); h1 = UV; o += SZ_R;   // time-shared: UV dies before h1c born
    pooled = (float*)(ws + o); o += SZ_POOL;
    Wsl1   =         (ws + o); o += SZ_W;
    Wsl2   =         (ws + o); o += SZ_W;
    bcat   = (float*)(ws + o);
  } else {
    // exact measured-R7 layout (peak ~203.7 MB)
    idx    = (int*)  (ws + 0);
    A      = (float*)(ws + 1048576);
    Bb     = (float*)(ws + 51380224);
    Cb     = A;  Db = Bb;                    // aliases (c overwrites a, d overwrites b)
    h1     = (float*)(ws + 101711872);
    UV     = (float*)(ws + 167772160);
    pooled = (float*)(ws + 200802304);
    Wsl1   =         (ws + 201588736);
    Wsl2   =         (ws + 202637312);
    bcat   = (float*)(ws + 203685888);
  }

  float*    wcat = (float*)   Wsl1;
  _Float16* WB1  = (_Float16*)Wsl1;
  _Float16* WB2  = (_Float16*)Wsl2;

  // ---- fp32 edge layer (layers 1,2: fully bit-exact) ----
  auto edge_layer_f32 = [&](const float* src, int F, int H1,
                            const float* w1, const float* b1,
                            const float* w2, const float* b2, float* dst) {
    knn_kernel<<<B_, N_, 0, stream>>>(src, F, idx);
    prep_uvw<<<(F * H1 + 255) / 256, 256, 0, stream>>>(w1, b1, F, H1, wcat, bcat);
    int W2 = 2 * H1;
    dim3 gUV((W2 + 63) / 64, CHUNK_ROWS / 128);
    for (int cb = 0; cb < B_; cb += CHUNK_B) {
      size_t base = (size_t)cb * N_;
      gemm_f32<false, false, true><<<gUV, 256, 0, stream>>>(src + base * F, wcat, bcat, UV, CHUNK_ROWS, W2, F);
      edge_stage2<<<CHUNK_ROWS / 16, 256, 0, stream>>>(UV, idx + base * 4, w2, b2, dst + base * 192, H1);
    }
  };

  // ---- fp16x3 edge layer (layer 4: output feeds no KNN) ----
  auto edge_layer_f16 = [&](const float* src, int F, int H1,
                            const float* w1, const float* b1,
                            const float* w2, const float* b2, float* dst) {
    int Fpad = (F + 31) & ~31;
    int KpadW2 = (H1 + 31) & ~31;
    int NN = 2 * H1;
    knn_kernel<<<B_, N_, 0, stream>>>(src, F, idx);
    prep_wcatT<<<(NN * Fpad + 255) / 256, 256, 0, stream>>>(w1, b1, F, H1, Fpad, WB1, bcat);
    prep_wT<<<(192 * KpadW2 + 255) / 256, 256, 0, stream>>>(w2, H1, 192, KpadW2, WB2);
    dim3 gUV((NN + 127) / 128, CHUNK_ROWS / 128);
    for (int cb = 0; cb < B_; cb += CHUNK_B) {
      size_t base = (size_t)cb * N_;
      gemm3h<false, false, true, false, false><<<gUV, 256, 0, stream>>>(
          src + base * F, src + base * F, nullptr, nullptr, F, WB1, bcat, nullptr, nullptr, UV, CHUNK_ROWS, NN, F, Fpad);
      edge_stage2_m<<<CHUNK_ROWS / 16, 256, 0, stream>>>(
          UV, idx + base * 4, WB2, b2, dst + base * 192, H1, KpadW2);
    }
  };

  // ---- hybrid c-layer: fp32 UV (exact) + fp16x3 stage2 + exact fp32 cols 0-2 ----
  auto edge_layer_c = [&](const float* src, float* dst) {
    const float* w1 = P[9]; const float* b1 = P[10];
    const float* w2 = P[11]; const float* b2 = P[12];
    int F = 192, H1 = 252, W2 = 504, KpadW2 = 256;
    knn_kernel<<<B_, N_, 0, stream>>>(src, F, idx);
    prep_uvw<<<(F * H1 + 255) / 256, 256, 0, stream>>>(w1, b1, F, H1, wcat, bcat);
    prep_wT<<<(192 * KpadW2 + 255) / 256, 256, 0, stream>>>(w2, H1, 192, KpadW2, WB2);
    dim3 gUV((W2 + 63) / 64, CHUNK_ROWS / 128);
    for (int cb = 0; cb < B_; cb += CHUNK_B) {
      size_t base = (size_t)cb * N_;
      gemm_f32<false, false, true><<<gUV, 256, 0, stream>>>(src + base * F, wcat, bcat, UV, CHUNK_ROWS, W2, F);
      edge_stage2_m<<<CHUNK_ROWS / 16, 256, 0, stream>>>(UV, idx + base * 4, WB2, b2, dst + base * 192, H1, KpadW2);
      edge_exact3<<<CHUNK_ROWS / 64, 256, 0, stream>>>(UV, idx + base * 4, w2, b2, dst + base * 192, H1);
    }
  };

  // a = edge(x) -> A ; b = edge(a) -> Bb      [fp32 exact: feed KNN 2,3 via full GEMMs]
  edge_layer_f32(x,  4,   96,  P[1], P[2], P[3], P[4], A);
  edge_layer_f32(A,  192, 252, P[5], P[6], P[7], P[8], Bb);

  if (fused) {
    // c = edge(b) -> Cb ; d = edge(c) -> Db  (a,b stay live; UV region still in use)
    edge_layer_c(Bb, Cb);
    edge_layer_f16(Cb, 192, 252, P[13], P[14], P[15], P[16], Db);
    // Fused nn1 (K=768, one chain) + nn2, M-chunked at 32768 rows.
    // h1c shares the (now dead) UV region. nn2-chunk writes only A-rows its own
    // nn1-chunk already consumed; later nn1-chunks read higher rows only.
    prep_wT<<<(252 * 768 + 255) / 256, 256, 0, stream>>>(P[17] + 4 * 252, 768, 252, 768, WB1);
    prep_wT<<<(192 * 256 + 255) / 256, 256, 0, stream>>>(P[19], 252, 192, 256, WB2);
    dim3 g(2, 256);
    for (int mc = 0; mc < 2; ++mc) {
      size_t roff = (size_t)mc * 32768;
      gemm3h<false, false, true, true, true><<<g, 256, 0, stream>>>(
          A + roff * 192, Bb + roff * 192, Cb + roff * 192, Db + roff * 192, 0,
          WB1, P[18], x + roff * 4, P[17], h1, 32768, 252, 768, 768);
      gemm3h<true, false, true, false, false><<<g, 256, 0, stream>>>(
          h1, h1, nullptr, nullptr, 252, WB2, P[20], nullptr, nullptr,
          A + roff * 192, 32768, 192, 252, 256);
    }
  } else {
    // h1 = [x,a,b] @ nn1w[0:388] + nn1b
    prep_wT<<<(252 * 384 + 255) / 256, 256, 0, stream>>>(P[17] + 4 * 252, 384, 252, 384, WB1);
    dim3 g(2, BN / 128);
    gemm3h<false, false, true, true, false><<<g, 256, 0, stream>>>(
        A, Bb, nullptr, nullptr, 192, WB1, P[18], x, P[17], h1, BN, 252, 384, 384);
    // c = edge(b) -> A (overwrites a) ; d = edge(c) -> Bb
    edge_layer_c(Bb, Cb);
    edge_layer_f16(Cb, 192, 252, P[13], P[14], P[15], P[16], Db);
    // h1 += [c,d] @ nn1w[388:772]
    prep_wT<<<(252 * 384 + 255) / 256, 256, 0, stream>>>(P[17] + (size_t)388 * 252, 384, 252, 384, WB1);
    gemm3h<false, true, false, false, false><<<g, 256, 0, stream>>>(
        Cb, Db, nullptr, nullptr, 192, WB1, nullptr, nullptr, nullptr, h1, BN, 252, 384, 384);
    // nn2: h2 = leaky(h1) @ nn2w + nn2b -> A
    prep_wT<<<(192 * 256 + 255) / 256, 256, 0, stream>>>(P[19], 252, 192, 256, WB2);
    gemm3h<true, false, true, false, false><<<g, 256, 0, stream>>>(
        h1, h1, nullptr, nullptr, 252, WB2, P[20], nullptr, nullptr, A, BN, 192, 252, 256);
  }

  pool_kernel<<<B_, 192, 0, stream>>>(A, pooled);
  head_kernel<<<B_, 128, 0, stream>>>(pooled, P[21], P[22], P[23], P[24], (float*)d_out);
}

// Round 16
// 1865.755 us; speedup vs baseline: 1.0812x; 1.0157x over previous
//
#include <hip/hip_runtime.h>
#include <cstdint>
#include <cstddef>

#define LK(x) ((x) > 0.f ? (x) : 0.01f * (x))

typedef _Float16 f16x8 __attribute__((ext_vector_type(8)));
typedef _Float16 f16x4 __attribute__((ext_vector_type(4)));
typedef float f32x4 __attribute__((ext_vector_type(4)));

constexpr int B_ = 256;
constexpr int N_ = 256;
constexpr int BN = B_ * N_;

// fp16 2-way split (for fp16x3 path)
__device__ inline void dec2(float v, _Float16& h, _Float16& l) {
  _Float16 hh = (_Float16)v;
  h = hh;
  l = (_Float16)(v - (float)hh);
}

// ---------------- KNN: one block per batch, one thread per point ----------------
__global__ void knn_kernel(const float* __restrict__ feat, int F, int* __restrict__ idxout) {
  __shared__ float px[N_], py[N_], pz[N_];
  int b = blockIdx.x, t = threadIdx.x;
  const float* row = feat + ((size_t)b * N_ + t) * F;
  px[t] = row[0]; py[t] = row[1]; pz[t] = row[2];
  __syncthreads();
  float x = px[t], y = py[t], z = pz[t];
  float bd0 = INFINITY, bd1 = INFINITY, bd2 = INFINITY, bd3 = INFINITY;
  int bi0 = 0, bi1 = 0, bi2 = 0, bi3 = 0;
  for (int j = 0; j < N_; ++j) {
    #pragma clang fp contract(off)
    float dx = x - px[j], dy = y - py[j], dz = z - pz[j];
    float d = (dx * dx + dy * dy) + dz * dz;
    if (j == t) continue;
    if (d < bd3) {
      if (d < bd2) {
        bd3 = bd2; bi3 = bi2;
        if (d < bd1) {
          bd2 = bd1; bi2 = bi1;
          if (d < bd0) { bd1 = bd0; bi1 = bi0; bd0 = d; bi0 = j; }
          else         { bd1 = d; bi1 = j; }
        } else         { bd2 = d; bi2 = j; }
      } else           { bd3 = d; bi3 = j; }
    }
  }
  int* o = idxout + ((size_t)b * N_ + t) * 4;
  o[0] = bi0; o[1] = bi1; o[2] = bi2; o[3] = bi3;
}

// ============================ fp32 path (bit-exact chain) ============================

// wcat = [w1_top - w1_bot | w1_bot] (F x 2H1), bcat = [b1 | 0]
__global__ void prep_uvw(const float* __restrict__ w1, const float* __restrict__ b1,
                         int F, int H1, float* __restrict__ wcat, float* __restrict__ bcat) {
  int t = blockIdx.x * 256 + threadIdx.x;
  int FH = F * H1;
  if (t < FH) {
    int k = t / H1, c = t - k * H1;
    float top = w1[(size_t)k * H1 + c];
    float bot = w1[(size_t)(F + k) * H1 + c];
    wcat[(size_t)k * 2 * H1 + c]      = top - bot;
    wcat[(size_t)k * 2 * H1 + H1 + c] = bot;
  }
  if (t < H1) { bcat[t] = b1[t]; bcat[H1 + t] = 0.f; }
}

// fp32 GEMM: 128x64 tile, BK=16, 256 thr, 8x4 micro.
// 1-DEEP REGISTER PREFETCH (R13-measured WIN: kept verbatim).
template<bool ACT_A, bool ACCUM, bool HAS_BIAS>
__global__ __launch_bounds__(256) void gemm_f32(
    const float* __restrict__ A, const float* __restrict__ W,
    const float* __restrict__ bias, float* __restrict__ C,
    int M, int N, int K) {
  __shared__ float sA[16][132];
  __shared__ float sW[16][68];
  int tid = threadIdx.x;
  int m0 = blockIdx.y * 128;
  int n0 = blockIdx.x * 64;
  int kkA = tid & 15, mA = tid >> 4;
  int nW = tid & 63, kW = tid >> 6;
  int ty = tid >> 4, tx = tid & 15;
  float acc[8][4] = {};
  float pa[8], pw[4];

#define G_LD(K0)                                                  \
  { int kg_ = (K0) + kkA;                                         \
    _Pragma("unroll")                                             \
    for (int i = 0; i < 8; ++i) {                                 \
      int m = mA + i * 16;                                        \
      float v = 0.f;                                              \
      if (kg_ < K) {                                              \
        v = A[(size_t)(m0 + m) * K + kg_];                        \
        if (ACT_A) v = LK(v);                                     \
      }                                                           \
      pa[i] = v;                                                  \
    }                                                             \
    _Pragma("unroll")                                             \
    for (int q = 0; q < 4; ++q) {                                 \
      int kk = kW + q * 4;                                        \
      int kgw = (K0) + kk, n = n0 + nW;                           \
      float v = 0.f;                                              \
      if (kgw < K && n < N) v = W[(size_t)kgw * N + n];           \
      pw[q] = v;                                                  \
    } }

  G_LD(0)

  for (int k0 = 0; k0 < K; k0 += 16) {
    __syncthreads();           // previous compute finished reading LDS
    #pragma unroll
    for (int i = 0; i < 8; ++i) sA[kkA][mA + i * 16] = pa[i];
    #pragma unroll
    for (int q = 0; q < 4; ++q) sW[kW + q * 4][nW] = pw[q];
    if (k0 + 16 < K) { G_LD(k0 + 16) }
    __syncthreads();
    #pragma unroll
    for (int kk = 0; kk < 16; ++kk) {
      float4 a0 = *(const float4*)&sA[kk][ty * 8];
      float4 a1 = *(const float4*)&sA[kk][ty * 8 + 4];
      float4 w  = *(const float4*)&sW[kk][tx * 4];
      float av[8] = {a0.x, a0.y, a0.z, a0.w, a1.x, a1.y, a1.z, a1.w};
      float wv[4] = {w.x, w.y, w.z, w.w};
      #pragma unroll
      for (int i = 0; i < 8; ++i)
        #pragma unroll
        for (int j = 0; j < 4; ++j)
          acc[i][j] += av[i] * wv[j];
    }
  }
#undef G_LD
  int n = n0 + tx * 4;
  float bv[4] = {0.f, 0.f, 0.f, 0.f};
  if (HAS_BIAS) {
    #pragma unroll
    for (int j = 0; j < 4; ++j) if (n + j < N) bv[j] = bias[n + j];
  }
  #pragma unroll
  for (int i = 0; i < 8; ++i) {
    size_t m = (size_t)(m0 + ty * 8 + i);
    if (n + 3 < N) {
      float4 o;
      o.x = acc[i][0] + bv[0]; o.y = acc[i][1] + bv[1];
      o.z = acc[i][2] + bv[2]; o.w = acc[i][3] + bv[3];
      float4* cp = (float4*)(C + m * N + n);
      if (ACCUM) { float4 c = *cp; o.x += c.x; o.y += c.y; o.z += c.z; o.w += c.w; }
      *cp = o;
    } else {
      #pragma unroll
      for (int j = 0; j < 4; ++j) {
        if (n + j < N) {
          float v = acc[i][j] + bv[j];
          size_t off = m * N + n + j;
          if (ACCUM) v += C[off];
          C[off] = v;
        }
      }
    }
  }
}

// fp32 fused edge stage 2, K-tiled (R12-measured 16-pt version, VGPR 52) — layers 1,2
__global__ __launch_bounds__(256) void edge_stage2(
    const float* __restrict__ UV, const int* __restrict__ idx,
    const float* __restrict__ w2, const float* __restrict__ b2,
    float* __restrict__ out, int H1) {
  __shared__ float sH[16][68];
  __shared__ float sW[16][196];
  __shared__ int sJ[64];
  int tid = threadIdx.x;
  int g0 = blockIdx.x * 16;
  int bbase = (g0 >> 8) << 8;
  if (tid < 64) sJ[tid] = bbase + idx[(size_t)g0 * 4 + tid];
  int W2 = H1 * 2;
  int r = tid >> 2, seg = tid & 3;
  int gp_r = g0 + (r >> 2);
  int ty = tid >> 4, tx = tid & 15;
  int gp = g0 + ty;
  float acc[4][12] = {};
  int nKt = (H1 + 15) >> 4;
  for (int kt = 0; kt < nKt; ++kt) {
    int k0 = kt << 4;
    __syncthreads();
    {
      int c = k0 + (seg << 2);
      const float* up = UV + (size_t)gp_r * W2 + c;
      const float* vp = UV + (size_t)sJ[r] * W2 + H1 + c;
      float u[4], v[4];
      if (c + 3 < H1) {
        float4 uu = *(const float4*)up; float4 vv = *(const float4*)vp;
        u[0] = uu.x; u[1] = uu.y; u[2] = uu.z; u[3] = uu.w;
        v[0] = vv.x; v[1] = vv.y; v[2] = vv.z; v[3] = vv.w;
      } else {
        #pragma unroll
        for (int j = 0; j < 4; ++j) {
          u[j] = (c + j < H1) ? up[j] : 0.f;
          v[j] = (c + j < H1) ? vp[j] : 0.f;
        }
      }
      #pragma unroll
      for (int j = 0; j < 4; ++j) {
        float t = u[j] + v[j];
        sH[(seg << 2) + j][r] = (c + j < H1) ? LK(t) : 0.f;
      }
    }
    #pragma unroll
    for (int p = 0; p < 3; ++p) {
      int q = tid + (p << 8);
      int kk = q / 48;
      int c4 = q - kk * 48;
      int k = k0 + kk;
      float4 wv = {0.f, 0.f, 0.f, 0.f};
      if (k < H1) wv = *(const float4*)(w2 + (size_t)k * 192 + (c4 << 2));
      *(float4*)&sW[kk][c4 << 2] = wv;
    }
    __syncthreads();
    #pragma unroll
    for (int kk = 0; kk < 16; ++kk) {
      float4 a = *(const float4*)&sH[kk][ty << 2];
      float av[4] = {a.x, a.y, a.z, a.w};
      #pragma unroll
      for (int ct = 0; ct < 3; ++ct) {
        float4 w = *(const float4*)&sW[kk][ct * 64 + (tx << 2)];
        float wv[4] = {w.x, w.y, w.z, w.w};
        #pragma unroll
        for (int i = 0; i < 4; ++i)
          #pragma unroll
          for (int j = 0; j < 4; ++j)
            acc[i][ct * 4 + j] += av[i] * wv[j];
      }
    }
  }
  #pragma unroll
  for (int ct = 0; ct < 3; ++ct) {
    float o[4];
    #pragma unroll
    for (int j = 0; j < 4; ++j) {
      int col = ct * 64 + (tx << 2) + j;
      float bvv = b2[col];
      float s = 0.f;
      #pragma unroll
      for (int i = 0; i < 4; ++i) {
        float t = acc[i][ct * 4 + j] + bvv;
        s += LK(t);
      }
      o[j] = s;
    }
    float4 ov = {o[0], o[1], o[2], o[3]};
    *(float4*)(out + (size_t)gp * 192 + ct * 64 + (tx << 2)) = ov;
  }
}

// exact fp32 replica of stage2 for cols 0..2 ONLY (the KNN-feeding columns).
__global__ __launch_bounds__(256) void edge_exact3(
    const float* __restrict__ UV, const int* __restrict__ idx,
    const float* __restrict__ w2, const float* __restrict__ b2,
    float* __restrict__ out, int H1) {
  __shared__ float sw[252 * 4];
  int tid = threadIdx.x;
  for (int k = tid; k < H1; k += 256) {
    sw[k * 4 + 0] = w2[(size_t)k * 192 + 0];
    sw[k * 4 + 1] = w2[(size_t)k * 192 + 1];
    sw[k * 4 + 2] = w2[(size_t)k * 192 + 2];
    sw[k * 4 + 3] = 0.f;
  }
  __syncthreads();
  int p = blockIdx.x * 64 + (tid >> 2);   // chunk-local point
  int e = tid & 3;
  int bbase = (p >> 8) << 8;
  int j = bbase + idx[(size_t)p * 4 + e];
  int W2 = 2 * H1;
  const float* up = UV + (size_t)p * W2;
  const float* vp = UV + (size_t)j * W2 + H1;
  float a0 = 0.f, a1 = 0.f, a2 = 0.f;
  int k = 0;
  for (; k + 3 < H1; k += 4) {
    float4 u = *(const float4*)(up + k);
    float4 v = *(const float4*)(vp + k);
    float h0 = LK(u.x + v.x), h1 = LK(u.y + v.y);
    float h2 = LK(u.z + v.z), h3 = LK(u.w + v.w);
    float4 w0 = *(const float4*)&sw[(k + 0) * 4];
    float4 w1 = *(const float4*)&sw[(k + 1) * 4];
    float4 w2v = *(const float4*)&sw[(k + 2) * 4];
    float4 w3 = *(const float4*)&sw[(k + 3) * 4];
    a0 = __builtin_fmaf(h0, w0.x, a0); a1 = __builtin_fmaf(h0, w0.y, a1); a2 = __builtin_fmaf(h0, w0.z, a2);
    a0 = __builtin_fmaf(h1, w1.x, a0); a1 = __builtin_fmaf(h1, w1.y, a1); a2 = __builtin_fmaf(h1, w1.z, a2);
    a0 = __builtin_fmaf(h2, w2v.x, a0); a1 = __builtin_fmaf(h2, w2v.y, a1); a2 = __builtin_fmaf(h2, w2v.z, a2);
    a0 = __builtin_fmaf(h3, w3.x, a0); a1 = __builtin_fmaf(h3, w3.y, a1); a2 = __builtin_fmaf(h3, w3.z, a2);
  }
  for (; k < H1; ++k) {
    float h = LK(up[k] + vp[k]);
    a0 = __builtin_fmaf(h, sw[k * 4 + 0], a0);
    a1 = __builtin_fmaf(h, sw[k * 4 + 1], a1);
    a2 = __builtin_fmaf(h, sw[k * 4 + 2], a2);
  }
  float acc3[3] = {a0, a1, a2};
  #pragma unroll
  for (int c = 0; c < 3; ++c) {
    float t = acc3[c] + b2[c];
    float pc = LK(t);
    float q1 = __shfl_down(pc, 1);
    float q2 = __shfl_down(pc, 2);
    float q3 = __shfl_down(pc, 3);
    if (e == 0) {
      float s = ((pc + q1) + q2) + q3;   // e-ascending order, matches edge_stage2 epilogue
      out[(size_t)p * 192 + c] = s;
    }
  }
}

// ====================== fp16x3 MFMA path (noise-tolerant GEMMs) ======================

// Wp[n][k-octets]: [8 hi | 8 lo]; [wdiff | wbot] transposed. bcat = [b1|0]
__global__ void prep_wcatT(const float* __restrict__ w1, const float* __restrict__ b1,
                           int F, int H1, int Fpad, _Float16* __restrict__ Wp,
                           float* __restrict__ bcat) {
  int t = blockIdx.x * 256 + threadIdx.x;
  int NN = 2 * H1;
  if (t < NN * Fpad) {
    int n = t / Fpad, k = t - n * Fpad;
    float v = 0.f;
    if (k < F) {
      if (n < H1) v = w1[(size_t)k * H1 + n] - w1[(size_t)(F + k) * H1 + n];
      else        v = w1[(size_t)(F + k) * H1 + (n - H1)];
    }
    _Float16 h, l; dec2(v, h, l);
    size_t base = (size_t)n * 2 * Fpad + (size_t)(k >> 3) * 16 + (k & 7);
    Wp[base] = h; Wp[base + 8] = l;
  }
  if (t < NN) bcat[t] = (t < H1) ? b1[t] : 0.f;
}

__global__ void prep_wT(const float* __restrict__ W, int K, int N, int Kpad,
                        _Float16* __restrict__ Wp) {
  int t = blockIdx.x * 256 + threadIdx.x;
  if (t >= N * Kpad) return;
  int n = t / Kpad, k = t - n * Kpad;
  float v = (k < K) ? W[(size_t)k * N + n] : 0.f;
  _Float16 h, l; dec2(v, h, l);
  size_t base = (size_t)n * 2 * Kpad + (size_t)(k >> 3) * 16 + (k & 7);
  Wp[base] = h; Wp[base + 8] = l;
}

// fp16x3 MFMA GEMM. Block 128x128, 4 waves (2x2), K-step 32.
// PIPELINED (1-deep reg prefetch) + LDS-TRANSPOSE EPILOGUE (measured R7).
// CAT4: A is the concatenation [A0|A1|A2|A3], each 192 cols (fused nn1, K=768).
template<bool ACT_A, bool ACCUM, bool HAS_BIAS, bool XB, bool CAT4>
__global__ __launch_bounds__(256) void gemm3h(
    const float* __restrict__ A0, const float* __restrict__ A1,
    const float* __restrict__ A2, const float* __restrict__ A3, int w0,
    const _Float16* __restrict__ Wp, const float* __restrict__ bias,
    const float* __restrict__ X, const float* __restrict__ Wx,
    float* __restrict__ C, int M, int N, int K, int Kpad) {
  __shared__ _Float16 sAB[2 * 128 * 72];   // sA | sB ; reused as float sT[128][72]
  _Float16* sA = sAB;
  _Float16* sB = sAB + 128 * 72;
  float* sT = (float*)sAB;
  int tid = threadIdx.x;
  int m0 = blockIdx.y * 128, n0 = blockIdx.x * 128;
  int lane = tid & 63, wid = tid >> 6;
  int wy = wid >> 1, wx = wid & 1;
  int lm = lane & 15, lq = lane >> 4;
  int rA = tid >> 1, qA = (tid & 1) * 4;
  f32x4 acc[4][4];
  #pragma unroll
  for (int i = 0; i < 4; ++i)
    #pragma unroll
    for (int j = 0; j < 4; ++j) acc[i][j] = 0.f;

  float4 pa0, pa1, pa2, pa3, pb0, pb1, pb2, pb3;

#define LOADA_ONE(KL, DST)                                          \
  { int kl_ = (KL); float4 v_ = {0.f, 0.f, 0.f, 0.f};               \
    if (kl_ + 3 < wA) v_ = *(const float4*)(arow + kl_);            \
    else {                                                          \
      if (kl_ + 0 < wA) v_.x = arow[kl_ + 0];                       \
      if (kl_ + 1 < wA) v_.y = arow[kl_ + 1];                       \
      if (kl_ + 2 < wA) v_.z = arow[kl_ + 2]; }                     \
    DST = v_; }

#define LOAD_AB(K0)                                                 \
  { int k0_ = (K0);                                                 \
    const float* Ap; int kb, wA;                                    \
    if (CAT4) {                                                     \
      int s_ = k0_ / 192;                                           \
      Ap = (s_ == 0) ? A0 : (s_ == 1) ? A1 : (s_ == 2) ? A2 : A3;   \
      kb = k0_ - s_ * 192; wA = 192;                                \
    } else if (k0_ < w0) { Ap = A0; kb = k0_;      wA = w0; }       \
    else                 { Ap = A1; kb = k0_ - w0; wA = K - w0; }   \
    const float* arow = Ap + (size_t)(m0 + rA) * wA;                \
    LOADA_ONE(kb + (qA + 0) * 4, pa0)                               \
    LOADA_ONE(kb + (qA + 1) * 4, pa1)                               \
    LOADA_ONE(kb + (qA + 2) * 4, pa2)                               \
    LOADA_ONE(kb + (qA + 3) * 4, pa3)                               \
    int n_ = n0 + rA;                                               \
    const _Float16* src = Wp + (size_t)n_ * 2 * Kpad + (size_t)k0_ * 2; \
    float4 z_ = {0.f, 0.f, 0.f, 0.f};                               \
    if (n_ < N) {                                                   \
      pb0 = *(const float4*)(src + (qA + 0) * 8);                   \
      pb1 = *(const float4*)(src + (qA + 1) * 8);                   \
      pb2 = *(const float4*)(src + (qA + 2) * 8);                   \
      pb3 = *(const float4*)(src + (qA + 3) * 8);                   \
    } else { pb0 = z_; pb1 = z_; pb2 = z_; pb3 = z_; } }

#define ST_A(V, Q)                                                  \
  { float4 t_ = (V);                                                \
    if (ACT_A) { t_.x = LK(t_.x); t_.y = LK(t_.y);                  \
                 t_.z = LK(t_.z); t_.w = LK(t_.w); }                \
    _Float16 h0,h1,h2,h3,l0,l1,l2,l3;                               \
    dec2(t_.x,h0,l0); dec2(t_.y,h1,l1);                             \
    dec2(t_.z,h2,l2); dec2(t_.w,h3,l3);                             \
    int off_ = rA * 72 + ((Q) >> 1) * 16 + ((Q) & 1) * 4;           \
    f16x4 th; th[0]=h0; th[1]=h1; th[2]=h2; th[3]=h3;               \
    f16x4 tl; tl[0]=l0; tl[1]=l1; tl[2]=l2; tl[3]=l3;               \
    *(f16x4*)&sA[off_]     = th;                                    \
    *(f16x4*)&sA[off_ + 8] = tl; }

  LOAD_AB(0)

  for (int k0 = 0; k0 < Kpad; k0 += 32) {
    __syncthreads();
    ST_A(pa0, qA + 0)
    ST_A(pa1, qA + 1)
    ST_A(pa2, qA + 2)
    ST_A(pa3, qA + 3)
    *(float4*)&sB[rA * 72 + (qA + 0) * 8] = pb0;
    *(float4*)&sB[rA * 72 + (qA + 1) * 8] = pb1;
    *(float4*)&sB[rA * 72 + (qA + 2) * 8] = pb2;
    *(float4*)&sB[rA * 72 + (qA + 3) * 8] = pb3;
    if (k0 + 32 < Kpad) { LOAD_AB(k0 + 32) }
    __syncthreads();
    f16x8 af[4][2], bf[4][2];
    #pragma unroll
    for (int mt = 0; mt < 4; ++mt) {
      int row = wy * 64 + mt * 16 + lm;
      af[mt][0] = *(const f16x8*)&sA[row * 72 + lq * 16];
      af[mt][1] = *(const f16x8*)&sA[row * 72 + lq * 16 + 8];
    }
    #pragma unroll
    for (int nt = 0; nt < 4; ++nt) {
      int row = wx * 64 + nt * 16 + lm;
      bf[nt][0] = *(const f16x8*)&sB[row * 72 + lq * 16];
      bf[nt][1] = *(const f16x8*)&sB[row * 72 + lq * 16 + 8];
    }
    #pragma unroll
    for (int mt = 0; mt < 4; ++mt)
      #pragma unroll
      for (int nt = 0; nt < 4; ++nt) {
        acc[mt][nt] = __builtin_amdgcn_mfma_f32_16x16x32_f16(af[mt][0], bf[nt][0], acc[mt][nt], 0, 0, 0);
        acc[mt][nt] = __builtin_amdgcn_mfma_f32_16x16x32_f16(af[mt][0], bf[nt][1], acc[mt][nt], 0, 0, 0);
        acc[mt][nt] = __builtin_amdgcn_mfma_f32_16x16x32_f16(af[mt][1], bf[nt][0], acc[mt][nt], 0, 0, 0);
      }
  }
#undef LOADA_ONE
#undef LOAD_AB
#undef ST_A

  // ---- staged, coalesced epilogue: two wx-halves through LDS ----
  int rbase = tid >> 4;          // 0..15
  int c4 = (tid & 15) << 2;      // 0..60
  #pragma unroll
  for (int half = 0; half < 2; ++half) {
    __syncthreads();
    if (wx == half) {
      #pragma unroll
      for (int mt = 0; mt < 4; ++mt)
        #pragma unroll
        for (int nt = 0; nt < 4; ++nt)
          #pragma unroll
          for (int r = 0; r < 4; ++r)
            sT[(wy * 64 + mt * 16 + lq * 4 + r) * 72 + nt * 16 + lm] = acc[mt][nt][r];
    }
    __syncthreads();
    int n = n0 + half * 64 + c4;
    float bv[4] = {0.f, 0.f, 0.f, 0.f};
    if (HAS_BIAS || XB) {
      #pragma unroll
      for (int j = 0; j < 4; ++j) if (n + j < N) bv[j] = bias[n + j];
    }
    float wxv0[4], wxv1[4], wxv2[4], wxv3[4];
    if (XB) {
      #pragma unroll
      for (int j = 0; j < 4; ++j) {
        wxv0[j] = (n + j < N) ? Wx[n + j] : 0.f;
        wxv1[j] = (n + j < N) ? Wx[N + n + j] : 0.f;
        wxv2[j] = (n + j < N) ? Wx[2 * N + n + j] : 0.f;
        wxv3[j] = (n + j < N) ? Wx[3 * N + n + j] : 0.f;
      }
    }
    #pragma unroll
    for (int it = 0; it < 8; ++it) {
      int row = it * 16 + rbase;
      size_t m = (size_t)m0 + row;
      float4 t = *(const float4*)&sT[row * 72 + c4];
      float o[4] = {t.x, t.y, t.z, t.w};
      if (XB) {
        float4 xv = *(const float4*)(X + m * 4);
        #pragma unroll
        for (int j = 0; j < 4; ++j)
          o[j] = o[j] + bv[j] + (xv.x * wxv0[j] + xv.y * wxv1[j] + xv.z * wxv2[j] + xv.w * wxv3[j]);
      } else {
        #pragma unroll
        for (int j = 0; j < 4; ++j) o[j] += bv[j];
      }
      if (n + 3 < N) {
        float4* cp = (float4*)(C + m * N + n);
        if (ACCUM) { float4 c = *cp; o[0] += c.x; o[1] += c.y; o[2] += c.z; o[3] += c.w; }
        float4 ov = {o[0], o[1], o[2], o[3]};
        *cp = ov;
      } else {
        #pragma unroll
        for (int j = 0; j < 4; ++j) {
          if (n + j < N) {
            float v = o[j];
            size_t off = m * N + n + j;
            if (ACCUM) v += C[off];
            C[off] = v;
          }
        }
      }
    }
  }
}

// fp16x3 fused edge stage 2 (layers 3 cols + layer 4)
__global__ __launch_bounds__(256) void edge_stage2_m(
    const float* __restrict__ UV, const int* __restrict__ idx,
    const _Float16* __restrict__ Wp, const float* __restrict__ b2,
    float* __restrict__ out, int H1, int Kpad) {
  __shared__ _Float16 sH[64 * 72];
  __shared__ _Float16 sW[192 * 72];
  __shared__ int sJ[64];
  int tid = threadIdx.x;
  int g0 = blockIdx.x * 16;
  int bbase = (g0 >> 8) << 8;
  if (tid < 64) sJ[tid] = bbase + idx[(size_t)g0 * 4 + tid];
  int W2 = 2 * H1;
  int lane = tid & 63, w = tid >> 6;
  int lm = lane & 15, lq = lane >> 4;
  int rS = tid >> 2, qS = tid & 3;
  f32x4 acc[4][3];
  #pragma unroll
  for (int i = 0; i < 4; ++i)
    #pragma unroll
    for (int j = 0; j < 3; ++j) acc[i][j] = 0.f;

  for (int k0 = 0; k0 < Kpad; k0 += 32) {
    __syncthreads();
    {
      int gp_r = g0 + (rS >> 2);
      int jr = sJ[rS];
      const float* up = UV + (size_t)gp_r * W2;
      const float* vp = UV + (size_t)jr * W2 + H1;
      #pragma unroll
      for (int hf = 0; hf < 2; ++hf) {
        int k = k0 + qS * 8 + hf * 4;
        float4 u = {0.f,0.f,0.f,0.f}, v = {0.f,0.f,0.f,0.f};
        if (k + 3 < H1) { u = *(const float4*)(up + k); v = *(const float4*)(vp + k); }
        else {
          if (k + 0 < H1) { u.x = up[k+0]; v.x = vp[k+0]; }
          if (k + 1 < H1) { u.y = up[k+1]; v.y = vp[k+1]; }
          if (k + 2 < H1) { u.z = up[k+2]; v.z = vp[k+2]; }
        }
        float e0 = LK(u.x + v.x), e1 = LK(u.y + v.y), e2 = LK(u.z + v.z), e3 = LK(u.w + v.w);
        _Float16 h0,h1,h2,h3,l0,l1,l2,l3;
        dec2(e0,h0,l0); dec2(e1,h1,l1); dec2(e2,h2,l2); dec2(e3,h3,l3);
        int off = rS * 72 + qS * 16 + hf * 4;
        f16x4 th; th[0]=h0; th[1]=h1; th[2]=h2; th[3]=h3;
        f16x4 tl; tl[0]=l0; tl[1]=l1; tl[2]=l2; tl[3]=l3;
        *(f16x4*)&sH[off]     = th;
        *(f16x4*)&sH[off + 8] = tl;
      }
    }
    {
      const _Float16* src = Wp + (size_t)k0 * 2;
      #pragma unroll
      for (int p = 0; p < 6; ++p) {
        int e = tid + p * 256;
        int n = e >> 3, u = e & 7;
        *(float4*)&sW[n * 72 + u * 8] =
            *(const float4*)(src + (size_t)n * 2 * Kpad + u * 8);
      }
    }
    __syncthreads();
    f16x8 af[4][2], bf[3][2];
    #pragma unroll
    for (int mt = 0; mt < 4; ++mt) {
      int row = mt * 16 + lm;
      af[mt][0] = *(const f16x8*)&sH[row * 72 + lq * 16];
      af[mt][1] = *(const f16x8*)&sH[row * 72 + lq * 16 + 8];
    }
    #pragma unroll
    for (int t3 = 0; t3 < 3; ++t3) {
      int row = (w * 3 + t3) * 16 + lm;
      bf[t3][0] = *(const f16x8*)&sW[row * 72 + lq * 16];
      bf[t3][1] = *(const f16x8*)&sW[row * 72 + lq * 16 + 8];
    }
    #pragma unroll
    for (int mt = 0; mt < 4; ++mt)
      #pragma unroll
      for (int t3 = 0; t3 < 3; ++t3) {
        acc[mt][t3] = __builtin_amdgcn_mfma_f32_16x16x32_f16(af[mt][0], bf[t3][0], acc[mt][t3], 0, 0, 0);
        acc[mt][t3] = __builtin_amdgcn_mfma_f32_16x16x32_f16(af[mt][0], bf[t3][1], acc[mt][t3], 0, 0, 0);
        acc[mt][t3] = __builtin_amdgcn_mfma_f32_16x16x32_f16(af[mt][1], bf[t3][0], acc[mt][t3], 0, 0, 0);
      }
  }
  #pragma unroll
  for (int mt = 0; mt < 4; ++mt) {
    int gp = g0 + mt * 4 + lq;
    #pragma unroll
    for (int t3 = 0; t3 < 3; ++t3) {
      int col = (w * 3 + t3) * 16 + lm;
      float bv = b2[col];
      float s = 0.f;
      #pragma unroll
      for (int r = 0; r < 4; ++r) s += LK(acc[mt][t3][r] + bv);
      out[(size_t)gp * 192 + col] = s;
    }
  }
}

// ---------------- pooling ----------------
__global__ void pool_kernel(const float* __restrict__ h, float* __restrict__ pooled) {
  int b = blockIdx.x, ch = threadIdx.x;  // 192 threads
  const float* p = h + (size_t)b * N_ * 192 + ch;
  float mx = -INFINITY, mn = INFINITY, sm = 0.f;
  for (int n = 0; n < N_; ++n) {
    float v = p[(size_t)n * 192];
    mx = fmaxf(mx, v); mn = fminf(mn, v); sm += v;
  }
  float* o = pooled + (size_t)b * 768;
  o[ch]       = LK(mx);
  o[192 + ch] = LK(mn);
  o[384 + ch] = LK(sm);
  o[576 + ch] = LK(sm * (1.f / 256.f));
}

// ---------------- head ----------------
__global__ void head_kernel(const float* __restrict__ pooled,
                            const float* __restrict__ w3, const float* __restrict__ b3,
                            const float* __restrict__ w4, const float* __restrict__ b4,
                            float* __restrict__ out) {
  __shared__ float sp[768];
  __shared__ float st[96];
  int b = blockIdx.x, t = threadIdx.x;   // 128 threads
  for (int c = t; c < 768; c += 128) sp[c] = pooled[(size_t)b * 768 + c];
  __syncthreads();
  if (t < 96) {
    float s = b3[t];
    for (int r = 0; r < 768; ++r) s += sp[r] * w3[(size_t)r * 96 + t];
    s = LK(s);
    st[t] = s * w4[t];
  }
  __syncthreads();
  if (t == 0) {
    float s = b4[0];
    for (int i = 0; i < 96; ++i) s += st[i];
    out[b] = s;
  }
}

extern "C" void kernel_launch(void* const* d_in, const int* in_sizes, int n_in,
                              void* d_out, int out_size, void* d_ws, size_t ws_size,
                              hipStream_t stream) {
  (void)in_sizes; (void)n_in; (void)out_size;
  const float* x = (const float*)d_in[0];
  const float* P[25];
  for (int i = 0; i < 25; ++i) P[i] = (const float*)d_in[i];

  // Workspace tiers:
  //  T2 (>=271.3 MB): fused nn1 + CHUNK_B=128 (UV=66 MB; 2048-block grids -> 8 blocks/CU)
  //  T1 (>=238.3 MB): fused nn1 + CHUNK_B=64  (measured R12/R14 path)
  //  T0: R7 fallback layout, CHUNK_B=64
  constexpr size_t SZ_IDX = 1048576, SZ_FEAT = 50331648;
  constexpr size_t SZ_R1 = 33030144;           // UV(64ch) == h1c
  constexpr size_t SZ_R2 = 66060288;           // UV(128ch)
  constexpr size_t SZ_POOL = 786432, SZ_W = 1048576;
  constexpr size_t FUSED_WS1 = SZ_IDX + 4 * SZ_FEAT + SZ_R1 + SZ_POOL + 2 * SZ_W + 4096;
  constexpr size_t FUSED_WS2 = SZ_IDX + 4 * SZ_FEAT + SZ_R2 + SZ_POOL + 2 * SZ_W + 4096;
  const bool fused = (ws_size >= FUSED_WS1);
  const int chunk_b = (ws_size >= FUSED_WS2) ? 128 : 64;
  const int crows = chunk_b * N_;

  char* ws = (char*)d_ws;
  int*   idx; float *A, *Bb, *Cb, *Db, *h1, *UV, *pooled; char *Wsl1, *Wsl2; float* bcat;
  if (fused) {
    size_t szR = (chunk_b == 128) ? SZ_R2 : SZ_R1;
    size_t o = 0;
    idx    = (int*)  (ws + o); o += SZ_IDX;
    A      = (float*)(ws + o); o += SZ_FEAT;
    Bb     = (float*)(ws + o); o += SZ_FEAT;
    Cb     = (float*)(ws + o); o += SZ_FEAT;
    Db     = (float*)(ws + o); o += SZ_FEAT;
    UV     = (float*)(ws + o); h1 = UV; o += szR;   // time-shared: UV dies before h1c born
    pooled = (float*)(ws + o); o += SZ_POOL;
    Wsl1   =         (ws + o); o += SZ_W;
    Wsl2   =         (ws + o); o += SZ_W;
    bcat   = (float*)(ws + o);
  } else {
    // exact measured-R7 layout (peak ~203.7 MB); chunk_b is 64 here by construction
    idx    = (int*)  (ws + 0);
    A      = (float*)(ws + 1048576);
    Bb     = (float*)(ws + 51380224);
    Cb     = A;  Db = Bb;                    // aliases (c overwrites a, d overwrites b)
    h1     = (float*)(ws + 101711872);
    UV     = (float*)(ws + 167772160);
    pooled = (float*)(ws + 200802304);
    Wsl1   =         (ws + 201588736);
    Wsl2   =         (ws + 202637312);
    bcat   = (float*)(ws + 203685888);
  }

  float*    wcat = (float*)   Wsl1;
  _Float16* WB1  = (_Float16*)Wsl1;
  _Float16* WB2  = (_Float16*)Wsl2;

  // ---- fp32 edge layer (layers 1,2: fully bit-exact) ----
  auto edge_layer_f32 = [&](const float* src, int F, int H1,
                            const float* w1, const float* b1,
                            const float* w2, const float* b2, float* dst) {
    knn_kernel<<<B_, N_, 0, stream>>>(src, F, idx);
    prep_uvw<<<(F * H1 + 255) / 256, 256, 0, stream>>>(w1, b1, F, H1, wcat, bcat);
    int W2 = 2 * H1;
    dim3 gUV((W2 + 63) / 64, crows / 128);
    for (int cb = 0; cb < B_; cb += chunk_b) {
      size_t base = (size_t)cb * N_;
      gemm_f32<false, false, true><<<gUV, 256, 0, stream>>>(src + base * F, wcat, bcat, UV, crows, W2, F);
      edge_stage2<<<crows / 16, 256, 0, stream>>>(UV, idx + base * 4, w2, b2, dst + base * 192, H1);
    }
  };

  // ---- fp16x3 edge layer (layer 4: output feeds no KNN) ----
  auto edge_layer_f16 = [&](const float* src, int F, int H1,
                            const float* w1, const float* b1,
                            const float* w2, const float* b2, float* dst) {
    int Fpad = (F + 31) & ~31;
    int KpadW2 = (H1 + 31) & ~31;
    int NN = 2 * H1;
    knn_kernel<<<B_, N_, 0, stream>>>(src, F, idx);
    prep_wcatT<<<(NN * Fpad + 255) / 256, 256, 0, stream>>>(w1, b1, F, H1, Fpad, WB1, bcat);
    prep_wT<<<(192 * KpadW2 + 255) / 256, 256, 0, stream>>>(w2, H1, 192, KpadW2, WB2);
    dim3 gUV((NN + 127) / 128, crows / 128);
    for (int cb = 0; cb < B_; cb += chunk_b) {
      size_t base = (size_t)cb * N_;
      gemm3h<false, false, true, false, false><<<gUV, 256, 0, stream>>>(
          src + base * F, src + base * F, nullptr, nullptr, F, WB1, bcat, nullptr, nullptr, UV, crows, NN, F, Fpad);
      edge_stage2_m<<<crows / 16, 256, 0, stream>>>(
          UV, idx + base * 4, WB2, b2, dst + base * 192, H1, KpadW2);
    }
  };

  // ---- hybrid c-layer: fp32 UV (exact) + fp16x3 stage2 + exact fp32 cols 0-2 ----
  auto edge_layer_c = [&](const float* src, float* dst) {
    const float* w1 = P[9]; const float* b1 = P[10];
    const float* w2 = P[11]; const float* b2 = P[12];
    int F = 192, H1 = 252, W2 = 504, KpadW2 = 256;
    knn_kernel<<<B_, N_, 0, stream>>>(src, F, idx);
    prep_uvw<<<(F * H1 + 255) / 256, 256, 0, stream>>>(w1, b1, F, H1, wcat, bcat);
    prep_wT<<<(192 * KpadW2 + 255) / 256, 256, 0, stream>>>(w2, H1, 192, KpadW2, WB2);
    dim3 gUV((W2 + 63) / 64, crows / 128);
    for (int cb = 0; cb < B_; cb += chunk_b) {
      size_t base = (size_t)cb * N_;
      gemm_f32<false, false, true><<<gUV, 256, 0, stream>>>(src + base * F, wcat, bcat, UV, crows, W2, F);
      edge_stage2_m<<<crows / 16, 256, 0, stream>>>(UV, idx + base * 4, WB2, b2, dst + base * 192, H1, KpadW2);
      edge_exact3<<<crows / 64, 256, 0, stream>>>(UV, idx + base * 4, w2, b2, dst + base * 192, H1);
    }
  };

  // a = edge(x) -> A ; b = edge(a) -> Bb      [fp32 exact: feed KNN 2,3 via full GEMMs]
  edge_layer_f32(x,  4,   96,  P[1], P[2], P[3], P[4], A);
  edge_layer_f32(A,  192, 252, P[5], P[6], P[7], P[8], Bb);

  if (fused) {
    // c = edge(b) -> Cb ; d = edge(c) -> Db  (a,b stay live; UV region still in use)
    edge_layer_c(Bb, Cb);
    edge_layer_f16(Cb, 192, 252, P[13], P[14], P[15], P[16], Db);
    // Fused nn1 (K=768, one chain) + nn2, M-chunked at 32768 rows.
    // h1c shares the (now dead) UV region. nn2-chunk writes only A-rows its own
    // nn1-chunk already consumed; later nn1-chunks read higher rows only.
    prep_wT<<<(252 * 768 + 255) / 256, 256, 0, stream>>>(P[17] + 4 * 252, 768, 252, 768, WB1);
    prep_wT<<<(192 * 256 + 255) / 256, 256, 0, stream>>>(P[19], 252, 192, 256, WB2);
    dim3 g(2, 256);
    for (int mc = 0; mc < 2; ++mc) {
      size_t roff = (size_t)mc * 32768;
      gemm3h<false, false, true, true, true><<<g, 256, 0, stream>>>(
          A + roff * 192, Bb + roff * 192, Cb + roff * 192, Db + roff * 192, 0,
          WB1, P[18], x + roff * 4, P[17], h1, 32768, 252, 768, 768);
      gemm3h<true, false, true, false, false><<<g, 256, 0, stream>>>(
          h1, h1, nullptr, nullptr, 252, WB2, P[20], nullptr, nullptr,
          A + roff * 192, 32768, 192, 252, 256);
    }
  } else {
    // h1 = [x,a,b] @ nn1w[0:388] + nn1b
    prep_wT<<<(252 * 384 + 255) / 256, 256, 0, stream>>>(P[17] + 4 * 252, 384, 252, 384, WB1);
    dim3 g(2, BN / 128);
    gemm3h<false, false, true, true, false><<<g, 256, 0, stream>>>(
        A, Bb, nullptr, nullptr, 192, WB1, P[18], x, P[17], h1, BN, 252, 384, 384);
    // c = edge(b) -> A (overwrites a) ; d = edge(c) -> Bb
    edge_layer_c(Bb, Cb);
    edge_layer_f16(Cb, 192, 252, P[13], P[14], P[15], P[16], Db);
    // h1 += [c,d] @ nn1w[388:772]
    prep_wT<<<(252 * 384 + 255) / 256, 256, 0, stream>>>(P[17] + (size_t)388 * 252, 384, 252, 384, WB1);
    gemm3h<false, true, false, false, false><<<g, 256, 0, stream>>>(
        Cb, Db, nullptr, nullptr, 192, WB1, nullptr, nullptr, nullptr, h1, BN, 252, 384, 384);
    // nn2: h2 = leaky(h1) @ nn2w + nn2b -> A
    prep_wT<<<(192 * 256 + 255) / 256, 256, 0, stream>>>(P[19], 252, 192, 256, WB2);
    gemm3h<true, false, true, false, false><<<g, 256, 0, stream>>>(
        h1, h1, nullptr, nullptr, 252, WB2, P[20], nullptr, nullptr, A, BN, 192, 252, 256);
  }

  pool_kernel<<<B_, 192, 0, stream>>>(A, pooled);
  head_kernel<<<B_, 128, 0, stream>>>(pooled, P[21], P[22], P[23], P[24], (float*)d_out);
}

// Round 17
// 1795.331 us; speedup vs baseline: 1.1236x; 1.0392x over previous
//
#include <hip/hip_runtime.h>
#include <cstdint>
#include <cstddef>

#define LK(x) ((x) > 0.f ? (x) : 0.01f * (x))

typedef _Float16 f16x8 __attribute__((ext_vector_type(8)));
typedef _Float16 f16x4 __attribute__((ext_vector_type(4)));
typedef float f32x4 __attribute__((ext_vector_type(4)));

constexpr int B_ = 256;
constexpr int N_ = 256;
constexpr int BN = B_ * N_;

// fp16 2-way split (for fp16x3 path)
__device__ inline void dec2(float v, _Float16& h, _Float16& l) {
  _Float16 hh = (_Float16)v;
  h = hh;
  l = (_Float16)(v - (float)hh);
}

// ---------------- KNN: one block per batch, one thread per point ----------------
__global__ void knn_kernel(const float* __restrict__ feat, int F, int* __restrict__ idxout) {
  __shared__ float px[N_], py[N_], pz[N_];
  int b = blockIdx.x, t = threadIdx.x;
  const float* row = feat + ((size_t)b * N_ + t) * F;
  px[t] = row[0]; py[t] = row[1]; pz[t] = row[2];
  __syncthreads();
  float x = px[t], y = py[t], z = pz[t];
  float bd0 = INFINITY, bd1 = INFINITY, bd2 = INFINITY, bd3 = INFINITY;
  int bi0 = 0, bi1 = 0, bi2 = 0, bi3 = 0;
  for (int j = 0; j < N_; ++j) {
    #pragma clang fp contract(off)
    float dx = x - px[j], dy = y - py[j], dz = z - pz[j];
    float d = (dx * dx + dy * dy) + dz * dz;
    if (j == t) continue;
    if (d < bd3) {
      if (d < bd2) {
        bd3 = bd2; bi3 = bi2;
        if (d < bd1) {
          bd2 = bd1; bi2 = bi1;
          if (d < bd0) { bd1 = bd0; bi1 = bi0; bd0 = d; bi0 = j; }
          else         { bd1 = d; bi1 = j; }
        } else         { bd2 = d; bi2 = j; }
      } else           { bd3 = d; bi3 = j; }
    }
  }
  int* o = idxout + ((size_t)b * N_ + t) * 4;
  o[0] = bi0; o[1] = bi1; o[2] = bi2; o[3] = bi3;
}

// ============================ fp32 path (bit-exact chain) ============================

// wcat = [w1_top - w1_bot | w1_bot] (F x 2H1), bcat = [b1 | 0]
__global__ void prep_uvw(const float* __restrict__ w1, const float* __restrict__ b1,
                         int F, int H1, float* __restrict__ wcat, float* __restrict__ bcat) {
  int t = blockIdx.x * 256 + threadIdx.x;
  int FH = F * H1;
  if (t < FH) {
    int k = t / H1, c = t - k * H1;
    float top = w1[(size_t)k * H1 + c];
    float bot = w1[(size_t)(F + k) * H1 + c];
    wcat[(size_t)k * 2 * H1 + c]      = top - bot;
    wcat[(size_t)k * 2 * H1 + H1 + c] = bot;
  }
  if (t < H1) { bcat[t] = b1[t]; bcat[H1 + t] = 0.f; }
}

// fp32 GEMM: 128x64 tile, BK=16, 256 thr, 8x4 micro.
// 1-DEEP REGISTER PREFETCH (R13-measured WIN: kept verbatim).
template<bool ACT_A, bool ACCUM, bool HAS_BIAS>
__global__ __launch_bounds__(256) void gemm_f32(
    const float* __restrict__ A, const float* __restrict__ W,
    const float* __restrict__ bias, float* __restrict__ C,
    int M, int N, int K) {
  __shared__ float sA[16][132];
  __shared__ float sW[16][68];
  int tid = threadIdx.x;
  int m0 = blockIdx.y * 128;
  int n0 = blockIdx.x * 64;
  int kkA = tid & 15, mA = tid >> 4;
  int nW = tid & 63, kW = tid >> 6;
  int ty = tid >> 4, tx = tid & 15;
  float acc[8][4] = {};
  float pa[8], pw[4];

#define G_LD(K0)                                                  \
  { int kg_ = (K0) + kkA;                                         \
    _Pragma("unroll")                                             \
    for (int i = 0; i < 8; ++i) {                                 \
      int m = mA + i * 16;                                        \
      float v = 0.f;                                              \
      if (kg_ < K) {                                              \
        v = A[(size_t)(m0 + m) * K + kg_];                        \
        if (ACT_A) v = LK(v);                                     \
      }                                                           \
      pa[i] = v;                                                  \
    }                                                             \
    _Pragma("unroll")                                             \
    for (int q = 0; q < 4; ++q) {                                 \
      int kk = kW + q * 4;                                        \
      int kgw = (K0) + kk, n = n0 + nW;                           \
      float v = 0.f;                                              \
      if (kgw < K && n < N) v = W[(size_t)kgw * N + n];           \
      pw[q] = v;                                                  \
    } }

  G_LD(0)

  for (int k0 = 0; k0 < K; k0 += 16) {
    __syncthreads();           // previous compute finished reading LDS
    #pragma unroll
    for (int i = 0; i < 8; ++i) sA[kkA][mA + i * 16] = pa[i];
    #pragma unroll
    for (int q = 0; q < 4; ++q) sW[kW + q * 4][nW] = pw[q];
    if (k0 + 16 < K) { G_LD(k0 + 16) }
    __syncthreads();
    #pragma unroll
    for (int kk = 0; kk < 16; ++kk) {
      float4 a0 = *(const float4*)&sA[kk][ty * 8];
      float4 a1 = *(const float4*)&sA[kk][ty * 8 + 4];
      float4 w  = *(const float4*)&sW[kk][tx * 4];
      float av[8] = {a0.x, a0.y, a0.z, a0.w, a1.x, a1.y, a1.z, a1.w};
      float wv[4] = {w.x, w.y, w.z, w.w};
      #pragma unroll
      for (int i = 0; i < 8; ++i)
        #pragma unroll
        for (int j = 0; j < 4; ++j)
          acc[i][j] += av[i] * wv[j];
    }
  }
#undef G_LD
  int n = n0 + tx * 4;
  float bv[4] = {0.f, 0.f, 0.f, 0.f};
  if (HAS_BIAS) {
    #pragma unroll
    for (int j = 0; j < 4; ++j) if (n + j < N) bv[j] = bias[n + j];
  }
  #pragma unroll
  for (int i = 0; i < 8; ++i) {
    size_t m = (size_t)(m0 + ty * 8 + i);
    if (n + 3 < N) {
      float4 o;
      o.x = acc[i][0] + bv[0]; o.y = acc[i][1] + bv[1];
      o.z = acc[i][2] + bv[2]; o.w = acc[i][3] + bv[3];
      float4* cp = (float4*)(C + m * N + n);
      if (ACCUM) { float4 c = *cp; o.x += c.x; o.y += c.y; o.z += c.z; o.w += c.w; }
      *cp = o;
    } else {
      #pragma unroll
      for (int j = 0; j < 4; ++j) {
        if (n + j < N) {
          float v = acc[i][j] + bv[j];
          size_t off = m * N + n + j;
          if (ACCUM) v += C[off];
          C[off] = v;
        }
      }
    }
  }
}

// fp32 fused edge stage 2, K-tiled (R12-measured 16-pt version, VGPR 52) — layers 1,2
__global__ __launch_bounds__(256) void edge_stage2(
    const float* __restrict__ UV, const int* __restrict__ idx,
    const float* __restrict__ w2, const float* __restrict__ b2,
    float* __restrict__ out, int H1) {
  __shared__ float sH[16][68];
  __shared__ float sW[16][196];
  __shared__ int sJ[64];
  int tid = threadIdx.x;
  int g0 = blockIdx.x * 16;
  int bbase = (g0 >> 8) << 8;
  if (tid < 64) sJ[tid] = bbase + idx[(size_t)g0 * 4 + tid];
  int W2 = H1 * 2;
  int r = tid >> 2, seg = tid & 3;
  int gp_r = g0 + (r >> 2);
  int ty = tid >> 4, tx = tid & 15;
  int gp = g0 + ty;
  float acc[4][12] = {};
  int nKt = (H1 + 15) >> 4;
  for (int kt = 0; kt < nKt; ++kt) {
    int k0 = kt << 4;
    __syncthreads();
    {
      int c = k0 + (seg << 2);
      const float* up = UV + (size_t)gp_r * W2 + c;
      const float* vp = UV + (size_t)sJ[r] * W2 + H1 + c;
      float u[4], v[4];
      if (c + 3 < H1) {
        float4 uu = *(const float4*)up; float4 vv = *(const float4*)vp;
        u[0] = uu.x; u[1] = uu.y; u[2] = uu.z; u[3] = uu.w;
        v[0] = vv.x; v[1] = vv.y; v[2] = vv.z; v[3] = vv.w;
      } else {
        #pragma unroll
        for (int j = 0; j < 4; ++j) {
          u[j] = (c + j < H1) ? up[j] : 0.f;
          v[j] = (c + j < H1) ? vp[j] : 0.f;
        }
      }
      #pragma unroll
      for (int j = 0; j < 4; ++j) {
        float t = u[j] + v[j];
        sH[(seg << 2) + j][r] = (c + j < H1) ? LK(t) : 0.f;
      }
    }
    #pragma unroll
    for (int p = 0; p < 3; ++p) {
      int q = tid + (p << 8);
      int kk = q / 48;
      int c4 = q - kk * 48;
      int k = k0 + kk;
      float4 wv = {0.f, 0.f, 0.f, 0.f};
      if (k < H1) wv = *(const float4*)(w2 + (size_t)k * 192 + (c4 << 2));
      *(float4*)&sW[kk][c4 << 2] = wv;
    }
    __syncthreads();
    #pragma unroll
    for (int kk = 0; kk < 16; ++kk) {
      float4 a = *(const float4*)&sH[kk][ty << 2];
      float av[4] = {a.x, a.y, a.z, a.w};
      #pragma unroll
      for (int ct = 0; ct < 3; ++ct) {
        float4 w = *(const float4*)&sW[kk][ct * 64 + (tx << 2)];
        float wv[4] = {w.x, w.y, w.z, w.w};
        #pragma unroll
        for (int i = 0; i < 4; ++i)
          #pragma unroll
          for (int j = 0; j < 4; ++j)
            acc[i][ct * 4 + j] += av[i] * wv[j];
      }
    }
  }
  #pragma unroll
  for (int ct = 0; ct < 3; ++ct) {
    float o[4];
    #pragma unroll
    for (int j = 0; j < 4; ++j) {
      int col = ct * 64 + (tx << 2) + j;
      float bvv = b2[col];
      float s = 0.f;
      #pragma unroll
      for (int i = 0; i < 4; ++i) {
        float t = acc[i][ct * 4 + j] + bvv;
        s += LK(t);
      }
      o[j] = s;
    }
    float4 ov = {o[0], o[1], o[2], o[3]};
    *(float4*)(out + (size_t)gp * 192 + ct * 64 + (tx << 2)) = ov;
  }
}

// exact fp32 replica of stage2 for cols 0..2 ONLY (the KNN-feeding columns).
__global__ __launch_bounds__(256) void edge_exact3(
    const float* __restrict__ UV, const int* __restrict__ idx,
    const float* __restrict__ w2, const float* __restrict__ b2,
    float* __restrict__ out, int H1) {
  __shared__ float sw[252 * 4];
  int tid = threadIdx.x;
  for (int k = tid; k < H1; k += 256) {
    sw[k * 4 + 0] = w2[(size_t)k * 192 + 0];
    sw[k * 4 + 1] = w2[(size_t)k * 192 + 1];
    sw[k * 4 + 2] = w2[(size_t)k * 192 + 2];
    sw[k * 4 + 3] = 0.f;
  }
  __syncthreads();
  int p = blockIdx.x * 64 + (tid >> 2);   // chunk-local point
  int e = tid & 3;
  int bbase = (p >> 8) << 8;
  int j = bbase + idx[(size_t)p * 4 + e];
  int W2 = 2 * H1;
  const float* up = UV + (size_t)p * W2;
  const float* vp = UV + (size_t)j * W2 + H1;
  float a0 = 0.f, a1 = 0.f, a2 = 0.f;
  int k = 0;
  for (; k + 3 < H1; k += 4) {
    float4 u = *(const float4*)(up + k);
    float4 v = *(const float4*)(vp + k);
    float h0 = LK(u.x + v.x), h1 = LK(u.y + v.y);
    float h2 = LK(u.z + v.z), h3 = LK(u.w + v.w);
    float4 w0 = *(const float4*)&sw[(k + 0) * 4];
    float4 w1 = *(const float4*)&sw[(k + 1) * 4];
    float4 w2v = *(const float4*)&sw[(k + 2) * 4];
    float4 w3 = *(const float4*)&sw[(k + 3) * 4];
    a0 = __builtin_fmaf(h0, w0.x, a0); a1 = __builtin_fmaf(h0, w0.y, a1); a2 = __builtin_fmaf(h0, w0.z, a2);
    a0 = __builtin_fmaf(h1, w1.x, a0); a1 = __builtin_fmaf(h1, w1.y, a1); a2 = __builtin_fmaf(h1, w1.z, a2);
    a0 = __builtin_fmaf(h2, w2v.x, a0); a1 = __builtin_fmaf(h2, w2v.y, a1); a2 = __builtin_fmaf(h2, w2v.z, a2);
    a0 = __builtin_fmaf(h3, w3.x, a0); a1 = __builtin_fmaf(h3, w3.y, a1); a2 = __builtin_fmaf(h3, w3.z, a2);
  }
  for (; k < H1; ++k) {
    float h = LK(up[k] + vp[k]);
    a0 = __builtin_fmaf(h, sw[k * 4 + 0], a0);
    a1 = __builtin_fmaf(h, sw[k * 4 + 1], a1);
    a2 = __builtin_fmaf(h, sw[k * 4 + 2], a2);
  }
  float acc3[3] = {a0, a1, a2};
  #pragma unroll
  for (int c = 0; c < 3; ++c) {
    float t = acc3[c] + b2[c];
    float pc = LK(t);
    float q1 = __shfl_down(pc, 1);
    float q2 = __shfl_down(pc, 2);
    float q3 = __shfl_down(pc, 3);
    if (e == 0) {
      float s = ((pc + q1) + q2) + q3;   // e-ascending order, matches edge_stage2 epilogue
      out[(size_t)p * 192 + c] = s;
    }
  }
}

// ====================== fp16x3 MFMA path (noise-tolerant GEMMs) ======================

// Wp[n][k-octets]: [8 hi | 8 lo]; [wdiff | wbot] transposed. bcat = [b1|0]
__global__ void prep_wcatT(const float* __restrict__ w1, const float* __restrict__ b1,
                           int F, int H1, int Fpad, _Float16* __restrict__ Wp,
                           float* __restrict__ bcat) {
  int t = blockIdx.x * 256 + threadIdx.x;
  int NN = 2 * H1;
  if (t < NN * Fpad) {
    int n = t / Fpad, k = t - n * Fpad;
    float v = 0.f;
    if (k < F) {
      if (n < H1) v = w1[(size_t)k * H1 + n] - w1[(size_t)(F + k) * H1 + n];
      else        v = w1[(size_t)(F + k) * H1 + (n - H1)];
    }
    _Float16 h, l; dec2(v, h, l);
    size_t base = (size_t)n * 2 * Fpad + (size_t)(k >> 3) * 16 + (k & 7);
    Wp[base] = h; Wp[base + 8] = l;
  }
  if (t < NN) bcat[t] = (t < H1) ? b1[t] : 0.f;
}

__global__ void prep_wT(const float* __restrict__ W, int K, int N, int Kpad,
                        _Float16* __restrict__ Wp) {
  int t = blockIdx.x * 256 + threadIdx.x;
  if (t >= N * Kpad) return;
  int n = t / Kpad, k = t - n * Kpad;
  float v = (k < K) ? W[(size_t)k * N + n] : 0.f;
  _Float16 h, l; dec2(v, h, l);
  size_t base = (size_t)n * 2 * Kpad + (size_t)(k >> 3) * 16 + (k & 7);
  Wp[base] = h; Wp[base + 8] = l;
}

// fp16x3 MFMA GEMM. Block 128x128, 4 waves (2x2), K-step 32.
// PIPELINED (1-deep reg prefetch) + LDS-TRANSPOSE EPILOGUE (measured R7).
// CAT4: A is the concatenation [A0|A1|A2|A3], each 192 cols (fused nn1, K=768).
template<bool ACT_A, bool ACCUM, bool HAS_BIAS, bool XB, bool CAT4>
__global__ __launch_bounds__(256) void gemm3h(
    const float* __restrict__ A0, const float* __restrict__ A1,
    const float* __restrict__ A2, const float* __restrict__ A3, int w0,
    const _Float16* __restrict__ Wp, const float* __restrict__ bias,
    const float* __restrict__ X, const float* __restrict__ Wx,
    float* __restrict__ C, int M, int N, int K, int Kpad) {
  __shared__ _Float16 sAB[2 * 128 * 72];   // sA | sB ; reused as float sT[128][72]
  _Float16* sA = sAB;
  _Float16* sB = sAB + 128 * 72;
  float* sT = (float*)sAB;
  int tid = threadIdx.x;
  int m0 = blockIdx.y * 128, n0 = blockIdx.x * 128;
  int lane = tid & 63, wid = tid >> 6;
  int wy = wid >> 1, wx = wid & 1;
  int lm = lane & 15, lq = lane >> 4;
  int rA = tid >> 1, qA = (tid & 1) * 4;
  f32x4 acc[4][4];
  #pragma unroll
  for (int i = 0; i < 4; ++i)
    #pragma unroll
    for (int j = 0; j < 4; ++j) acc[i][j] = 0.f;

  float4 pa0, pa1, pa2, pa3, pb0, pb1, pb2, pb3;

#define LOADA_ONE(KL, DST)                                          \
  { int kl_ = (KL); float4 v_ = {0.f, 0.f, 0.f, 0.f};               \
    if (kl_ + 3 < wA) v_ = *(const float4*)(arow + kl_);            \
    else {                                                          \
      if (kl_ + 0 < wA) v_.x = arow[kl_ + 0];                       \
      if (kl_ + 1 < wA) v_.y = arow[kl_ + 1];                       \
      if (kl_ + 2 < wA) v_.z = arow[kl_ + 2]; }                     \
    DST = v_; }

#define LOAD_AB(K0)                                                 \
  { int k0_ = (K0);                                                 \
    const float* Ap; int kb, wA;                                    \
    if (CAT4) {                                                     \
      int s_ = k0_ / 192;                                           \
      Ap = (s_ == 0) ? A0 : (s_ == 1) ? A1 : (s_ == 2) ? A2 : A3;   \
      kb = k0_ - s_ * 192; wA = 192;                                \
    } else if (k0_ < w0) { Ap = A0; kb = k0_;      wA = w0; }       \
    else                 { Ap = A1; kb = k0_ - w0; wA = K - w0; }   \
    const float* arow = Ap + (size_t)(m0 + rA) * wA;                \
    LOADA_ONE(kb + (qA + 0) * 4, pa0)                               \
    LOADA_ONE(kb + (qA + 1) * 4, pa1)                               \
    LOADA_ONE(kb + (qA + 2) * 4, pa2)                               \
    LOADA_ONE(kb + (qA + 3) * 4, pa3)                               \
    int n_ = n0 + rA;                                               \
    const _Float16* src = Wp + (size_t)n_ * 2 * Kpad + (size_t)k0_ * 2; \
    float4 z_ = {0.f, 0.f, 0.f, 0.f};                               \
    if (n_ < N) {                                                   \
      pb0 = *(const float4*)(src + (qA + 0) * 8);                   \
      pb1 = *(const float4*)(src + (qA + 1) * 8);                   \
      pb2 = *(const float4*)(src + (qA + 2) * 8);                   \
      pb3 = *(const float4*)(src + (qA + 3) * 8);                   \
    } else { pb0 = z_; pb1 = z_; pb2 = z_; pb3 = z_; } }

#define ST_A(V, Q)                                                  \
  { float4 t_ = (V);                                                \
    if (ACT_A) { t_.x = LK(t_.x); t_.y = LK(t_.y);                  \
                 t_.z = LK(t_.z); t_.w = LK(t_.w); }                \
    _Float16 h0,h1,h2,h3,l0,l1,l2,l3;                               \
    dec2(t_.x,h0,l0); dec2(t_.y,h1,l1);                             \
    dec2(t_.z,h2,l2); dec2(t_.w,h3,l3);                             \
    int off_ = rA * 72 + ((Q) >> 1) * 16 + ((Q) & 1) * 4;           \
    f16x4 th; th[0]=h0; th[1]=h1; th[2]=h2; th[3]=h3;               \
    f16x4 tl; tl[0]=l0; tl[1]=l1; tl[2]=l2; tl[3]=l3;               \
    *(f16x4*)&sA[off_]     = th;                                    \
    *(f16x4*)&sA[off_ + 8] = tl; }

  LOAD_AB(0)

  for (int k0 = 0; k0 < Kpad; k0 += 32) {
    __syncthreads();
    ST_A(pa0, qA + 0)
    ST_A(pa1, qA + 1)
    ST_A(pa2, qA + 2)
    ST_A(pa3, qA + 3)
    *(float4*)&sB[rA * 72 + (qA + 0) * 8] = pb0;
    *(float4*)&sB[rA * 72 + (qA + 1) * 8] = pb1;
    *(float4*)&sB[rA * 72 + (qA + 2) * 8] = pb2;
    *(float4*)&sB[rA * 72 + (qA + 3) * 8] = pb3;
    if (k0 + 32 < Kpad) { LOAD_AB(k0 + 32) }
    __syncthreads();
    f16x8 af[4][2], bf[4][2];
    #pragma unroll
    for (int mt = 0; mt < 4; ++mt) {
      int row = wy * 64 + mt * 16 + lm;
      af[mt][0] = *(const f16x8*)&sA[row * 72 + lq * 16];
      af[mt][1] = *(const f16x8*)&sA[row * 72 + lq * 16 + 8];
    }
    #pragma unroll
    for (int nt = 0; nt < 4; ++nt) {
      int row = wx * 64 + nt * 16 + lm;
      bf[nt][0] = *(const f16x8*)&sB[row * 72 + lq * 16];
      bf[nt][1] = *(const f16x8*)&sB[row * 72 + lq * 16 + 8];
    }
    #pragma unroll
    for (int mt = 0; mt < 4; ++mt)
      #pragma unroll
      for (int nt = 0; nt < 4; ++nt) {
        acc[mt][nt] = __builtin_amdgcn_mfma_f32_16x16x32_f16(af[mt][0], bf[nt][0], acc[mt][nt], 0, 0, 0);
        acc[mt][nt] = __builtin_amdgcn_mfma_f32_16x16x32_f16(af[mt][0], bf[nt][1], acc[mt][nt], 0, 0, 0);
        acc[mt][nt] = __builtin_amdgcn_mfma_f32_16x16x32_f16(af[mt][1], bf[nt][0], acc[mt][nt], 0, 0, 0);
      }
  }
#undef LOADA_ONE
#undef LOAD_AB
#undef ST_A

  // ---- staged, coalesced epilogue: two wx-halves through LDS ----
  int rbase = tid >> 4;          // 0..15
  int c4 = (tid & 15) << 2;      // 0..60
  #pragma unroll
  for (int half = 0; half < 2; ++half) {
    __syncthreads();
    if (wx == half) {
      #pragma unroll
      for (int mt = 0; mt < 4; ++mt)
        #pragma unroll
        for (int nt = 0; nt < 4; ++nt)
          #pragma unroll
          for (int r = 0; r < 4; ++r)
            sT[(wy * 64 + mt * 16 + lq * 4 + r) * 72 + nt * 16 + lm] = acc[mt][nt][r];
    }
    __syncthreads();
    int n = n0 + half * 64 + c4;
    float bv[4] = {0.f, 0.f, 0.f, 0.f};
    if (HAS_BIAS || XB) {
      #pragma unroll
      for (int j = 0; j < 4; ++j) if (n + j < N) bv[j] = bias[n + j];
    }
    float wxv0[4], wxv1[4], wxv2[4], wxv3[4];
    if (XB) {
      #pragma unroll
      for (int j = 0; j < 4; ++j) {
        wxv0[j] = (n + j < N) ? Wx[n + j] : 0.f;
        wxv1[j] = (n + j < N) ? Wx[N + n + j] : 0.f;
        wxv2[j] = (n + j < N) ? Wx[2 * N + n + j] : 0.f;
        wxv3[j] = (n + j < N) ? Wx[3 * N + n + j] : 0.f;
      }
    }
    #pragma unroll
    for (int it = 0; it < 8; ++it) {
      int row = it * 16 + rbase;
      size_t m = (size_t)m0 + row;
      float4 t = *(const float4*)&sT[row * 72 + c4];
      float o[4] = {t.x, t.y, t.z, t.w};
      if (XB) {
        float4 xv = *(const float4*)(X + m * 4);
        #pragma unroll
        for (int j = 0; j < 4; ++j)
          o[j] = o[j] + bv[j] + (xv.x * wxv0[j] + xv.y * wxv1[j] + xv.z * wxv2[j] + xv.w * wxv3[j]);
      } else {
        #pragma unroll
        for (int j = 0; j < 4; ++j) o[j] += bv[j];
      }
      if (n + 3 < N) {
        float4* cp = (float4*)(C + m * N + n);
        if (ACCUM) { float4 c = *cp; o[0] += c.x; o[1] += c.y; o[2] += c.z; o[3] += c.w; }
        float4 ov = {o[0], o[1], o[2], o[3]};
        *cp = ov;
      } else {
        #pragma unroll
        for (int j = 0; j < 4; ++j) {
          if (n + j < N) {
            float v = o[j];
            size_t off = m * N + n + j;
            if (ACCUM) v += C[off];
            C[off] = v;
          }
        }
      }
    }
  }
}

// fp16x3 fused edge stage 2 (layers 3 cols + layer 4)
__global__ __launch_bounds__(256) void edge_stage2_m(
    const float* __restrict__ UV, const int* __restrict__ idx,
    const _Float16* __restrict__ Wp, const float* __restrict__ b2,
    float* __restrict__ out, int H1, int Kpad) {
  __shared__ _Float16 sH[64 * 72];
  __shared__ _Float16 sW[192 * 72];
  __shared__ int sJ[64];
  int tid = threadIdx.x;
  int g0 = blockIdx.x * 16;
  int bbase = (g0 >> 8) << 8;
  if (tid < 64) sJ[tid] = bbase + idx[(size_t)g0 * 4 + tid];
  int W2 = 2 * H1;
  int lane = tid & 63, w = tid >> 6;
  int lm = lane & 15, lq = lane >> 4;
  int rS = tid >> 2, qS = tid & 3;
  f32x4 acc[4][3];
  #pragma unroll
  for (int i = 0; i < 4; ++i)
    #pragma unroll
    for (int j = 0; j < 3; ++j) acc[i][j] = 0.f;

  for (int k0 = 0; k0 < Kpad; k0 += 32) {
    __syncthreads();
    {
      int gp_r = g0 + (rS >> 2);
      int jr = sJ[rS];
      const float* up = UV + (size_t)gp_r * W2;
      const float* vp = UV + (size_t)jr * W2 + H1;
      #pragma unroll
      for (int hf = 0; hf < 2; ++hf) {
        int k = k0 + qS * 8 + hf * 4;
        float4 u = {0.f,0.f,0.f,0.f}, v = {0.f,0.f,0.f,0.f};
        if (k + 3 < H1) { u = *(const float4*)(up + k); v = *(const float4*)(vp + k); }
        else {
          if (k + 0 < H1) { u.x = up[k+0]; v.x = vp[k+0]; }
          if (k + 1 < H1) { u.y = up[k+1]; v.y = vp[k+1]; }
          if (k + 2 < H1) { u.z = up[k+2]; v.z = vp[k+2]; }
        }
        float e0 = LK(u.x + v.x), e1 = LK(u.y + v.y), e2 = LK(u.z + v.z), e3 = LK(u.w + v.w);
        _Float16 h0,h1,h2,h3,l0,l1,l2,l3;
        dec2(e0,h0,l0); dec2(e1,h1,l1); dec2(e2,h2,l2); dec2(e3,h3,l3);
        int off = rS * 72 + qS * 16 + hf * 4;
        f16x4 th; th[0]=h0; th[1]=h1; th[2]=h2; th[3]=h3;
        f16x4 tl; tl[0]=l0; tl[1]=l1; tl[2]=l2; tl[3]=l3;
        *(f16x4*)&sH[off]     = th;
        *(f16x4*)&sH[off + 8] = tl;
      }
    }
    {
      const _Float16* src = Wp + (size_t)k0 * 2;
      #pragma unroll
      for (int p = 0; p < 6; ++p) {
        int e = tid + p * 256;
        int n = e >> 3, u = e & 7;
        *(float4*)&sW[n * 72 + u * 8] =
            *(const float4*)(src + (size_t)n * 2 * Kpad + u * 8);
      }
    }
    __syncthreads();
    f16x8 af[4][2], bf[3][2];
    #pragma unroll
    for (int mt = 0; mt < 4; ++mt) {
      int row = mt * 16 + lm;
      af[mt][0] = *(const f16x8*)&sH[row * 72 + lq * 16];
      af[mt][1] = *(const f16x8*)&sH[row * 72 + lq * 16 + 8];
    }
    #pragma unroll
    for (int t3 = 0; t3 < 3; ++t3) {
      int row = (w * 3 + t3) * 16 + lm;
      bf[t3][0] = *(const f16x8*)&sW[row * 72 + lq * 16];
      bf[t3][1] = *(const f16x8*)&sW[row * 72 + lq * 16 + 8];
    }
    #pragma unroll
    for (int mt = 0; mt < 4; ++mt)
      #pragma unroll
      for (int t3 = 0; t3 < 3; ++t3) {
        acc[mt][t3] = __builtin_amdgcn_mfma_f32_16x16x32_f16(af[mt][0], bf[t3][0], acc[mt][t3], 0, 0, 0);
        acc[mt][t3] = __builtin_amdgcn_mfma_f32_16x16x32_f16(af[mt][0], bf[t3][1], acc[mt][t3], 0, 0, 0);
        acc[mt][t3] = __builtin_amdgcn_mfma_f32_16x16x32_f16(af[mt][1], bf[t3][0], acc[mt][t3], 0, 0, 0);
      }
  }
  #pragma unroll
  for (int mt = 0; mt < 4; ++mt) {
    int gp = g0 + mt * 4 + lq;
    #pragma unroll
    for (int t3 = 0; t3 < 3; ++t3) {
      int col = (w * 3 + t3) * 16 + lm;
      float bv = b2[col];
      float s = 0.f;
      #pragma unroll
      for (int r = 0; r < 4; ++r) s += LK(acc[mt][t3][r] + bv);
      out[(size_t)gp * 192 + col] = s;
    }
  }
}

// ---------------- pooling ----------------
__global__ void pool_kernel(const float* __restrict__ h, float* __restrict__ pooled) {
  int b = blockIdx.x, ch = threadIdx.x;  // 192 threads
  const float* p = h + (size_t)b * N_ * 192 + ch;
  float mx = -INFINITY, mn = INFINITY, sm = 0.f;
  for (int n = 0; n < N_; ++n) {
    float v = p[(size_t)n * 192];
    mx = fmaxf(mx, v); mn = fminf(mn, v); sm += v;
  }
  float* o = pooled + (size_t)b * 768;
  o[ch]       = LK(mx);
  o[192 + ch] = LK(mn);
  o[384 + ch] = LK(sm);
  o[576 + ch] = LK(sm * (1.f / 256.f));
}

// ---------------- head ----------------
__global__ void head_kernel(const float* __restrict__ pooled,
                            const float* __restrict__ w3, const float* __restrict__ b3,
                            const float* __restrict__ w4, const float* __restrict__ b4,
                            float* __restrict__ out) {
  __shared__ float sp[768];
  __shared__ float st[96];
  int b = blockIdx.x, t = threadIdx.x;   // 128 threads
  for (int c = t; c < 768; c += 128) sp[c] = pooled[(size_t)b * 768 + c];
  __syncthreads();
  if (t < 96) {
    float s = b3[t];
    for (int r = 0; r < 768; ++r) s += sp[r] * w3[(size_t)r * 96 + t];
    s = LK(s);
    st[t] = s * w4[t];
  }
  __syncthreads();
  if (t == 0) {
    float s = b4[0];
    for (int i = 0; i < 96; ++i) s += st[i];
    out[b] = s;
  }
}

extern "C" void kernel_launch(void* const* d_in, const int* in_sizes, int n_in,
                              void* d_out, int out_size, void* d_ws, size_t ws_size,
                              hipStream_t stream) {
  (void)in_sizes; (void)n_in; (void)out_size;
  const float* x = (const float*)d_in[0];
  const float* P[25];
  for (int i = 0; i < 25; ++i) P[i] = (const float*)d_in[i];

  // Workspace tiers:
  //  T2' (>=254.8 MB): fused nn1 + CHUNK_B=96 (UV=49.5 MB; 1536-block grids -> 6 blocks/CU)
  //  T1  (>=238.3 MB): fused nn1 + CHUNK_B=64 (measured R12/R14/R16 path)
  //  T0: R7 fallback layout, CHUNK_B=64
  constexpr size_t SZ_IDX = 1048576, SZ_FEAT = 50331648;
  constexpr size_t SZ_R1 = 33030144;           // UV(64ch) == h1c
  constexpr size_t SZ_R2 = 49545216;           // UV(96ch)
  constexpr size_t SZ_POOL = 786432, SZ_W = 1048576;
  constexpr size_t FUSED_WS1 = SZ_IDX + 4 * SZ_FEAT + SZ_R1 + SZ_POOL + 2 * SZ_W + 4096;
  constexpr size_t FUSED_WS2 = SZ_IDX + 4 * SZ_FEAT + SZ_R2 + SZ_POOL + 2 * SZ_W + 4096;
  const bool fused = (ws_size >= FUSED_WS1);
  const int chunk_b = (ws_size >= FUSED_WS2) ? 96 : 64;

  char* ws = (char*)d_ws;
  int*   idx; float *A, *Bb, *Cb, *Db, *h1, *UV, *pooled; char *Wsl1, *Wsl2; float* bcat;
  if (fused) {
    size_t szR = (chunk_b == 96) ? SZ_R2 : SZ_R1;
    size_t o = 0;
    idx    = (int*)  (ws + o); o += SZ_IDX;
    A      = (float*)(ws + o); o += SZ_FEAT;
    Bb     = (float*)(ws + o); o += SZ_FEAT;
    Cb     = (float*)(ws + o); o += SZ_FEAT;
    Db     = (float*)(ws + o); o += SZ_FEAT;
    UV     = (float*)(ws + o); h1 = UV; o += szR;   // time-shared: UV dies before h1c born
    pooled = (float*)(ws + o); o += SZ_POOL;
    Wsl1   =         (ws + o); o += SZ_W;
    Wsl2   =         (ws + o); o += SZ_W;
    bcat   = (float*)(ws + o);
  } else {
    // exact measured-R7 layout (peak ~203.7 MB); chunk_b is 64 here by construction
    idx    = (int*)  (ws + 0);
    A      = (float*)(ws + 1048576);
    Bb     = (float*)(ws + 51380224);
    Cb     = A;  Db = Bb;                    // aliases (c overwrites a, d overwrites b)
    h1     = (float*)(ws + 101711872);
    UV     = (float*)(ws + 167772160);
    pooled = (float*)(ws + 200802304);
    Wsl1   =         (ws + 201588736);
    Wsl2   =         (ws + 202637312);
    bcat   = (float*)(ws + 203685888);
  }

  float*    wcat = (float*)   Wsl1;
  _Float16* WB1  = (_Float16*)Wsl1;
  _Float16* WB2  = (_Float16*)Wsl2;

  // ---- fp32 edge layer (layers 1,2: fully bit-exact) ----
  auto edge_layer_f32 = [&](const float* src, int F, int H1,
                            const float* w1, const float* b1,
                            const float* w2, const float* b2, float* dst) {
    knn_kernel<<<B_, N_, 0, stream>>>(src, F, idx);
    prep_uvw<<<(F * H1 + 255) / 256, 256, 0, stream>>>(w1, b1, F, H1, wcat, bcat);
    int W2 = 2 * H1;
    for (int cb = 0; cb < B_; cb += chunk_b) {
      int cbn = (B_ - cb < chunk_b) ? (B_ - cb) : chunk_b;
      int rows = cbn * N_;
      size_t base = (size_t)cb * N_;
      dim3 gUV((W2 + 63) / 64, rows / 128);
      gemm_f32<false, false, true><<<gUV, 256, 0, stream>>>(src + base * F, wcat, bcat, UV, rows, W2, F);
      edge_stage2<<<rows / 16, 256, 0, stream>>>(UV, idx + base * 4, w2, b2, dst + base * 192, H1);
    }
  };

  // ---- fp16x3 edge layer (layer 4: output feeds no KNN) ----
  auto edge_layer_f16 = [&](const float* src, int F, int H1,
                            const float* w1, const float* b1,
                            const float* w2, const float* b2, float* dst) {
    int Fpad = (F + 31) & ~31;
    int KpadW2 = (H1 + 31) & ~31;
    int NN = 2 * H1;
    knn_kernel<<<B_, N_, 0, stream>>>(src, F, idx);
    prep_wcatT<<<(NN * Fpad + 255) / 256, 256, 0, stream>>>(w1, b1, F, H1, Fpad, WB1, bcat);
    prep_wT<<<(192 * KpadW2 + 255) / 256, 256, 0, stream>>>(w2, H1, 192, KpadW2, WB2);
    for (int cb = 0; cb < B_; cb += chunk_b) {
      int cbn = (B_ - cb < chunk_b) ? (B_ - cb) : chunk_b;
      int rows = cbn * N_;
      size_t base = (size_t)cb * N_;
      dim3 gUV((NN + 127) / 128, rows / 128);
      gemm3h<false, false, true, false, false><<<gUV, 256, 0, stream>>>(
          src + base * F, src + base * F, nullptr, nullptr, F, WB1, bcat, nullptr, nullptr, UV, rows, NN, F, Fpad);
      edge_stage2_m<<<rows / 16, 256, 0, stream>>>(
          UV, idx + base * 4, WB2, b2, dst + base * 192, H1, KpadW2);
    }
  };

  // ---- hybrid c-layer: fp32 UV (exact) + fp16x3 stage2 + exact fp32 cols 0-2 ----
  auto edge_layer_c = [&](const float* src, float* dst) {
    const float* w1 = P[9]; const float* b1 = P[10];
    const float* w2 = P[11]; const float* b2 = P[12];
    int F = 192, H1 = 252, W2 = 504, KpadW2 = 256;
    knn_kernel<<<B_, N_, 0, stream>>>(src, F, idx);
    prep_uvw<<<(F * H1 + 255) / 256, 256, 0, stream>>>(w1, b1, F, H1, wcat, bcat);
    prep_wT<<<(192 * KpadW2 + 255) / 256, 256, 0, stream>>>(w2, H1, 192, KpadW2, WB2);
    for (int cb = 0; cb < B_; cb += chunk_b) {
      int cbn = (B_ - cb < chunk_b) ? (B_ - cb) : chunk_b;
      int rows = cbn * N_;
      size_t base = (size_t)cb * N_;
      dim3 gUV((W2 + 63) / 64, rows / 128);
      gemm_f32<false, false, true><<<gUV, 256, 0, stream>>>(src + base * F, wcat, bcat, UV, rows, W2, F);
      edge_stage2_m<<<rows / 16, 256, 0, stream>>>(UV, idx + base * 4, WB2, b2, dst + base * 192, H1, KpadW2);
      edge_exact3<<<rows / 64, 256, 0, stream>>>(UV, idx + base * 4, w2, b2, dst + base * 192, H1);
    }
  };

  // a = edge(x) -> A ; b = edge(a) -> Bb      [fp32 exact: feed KNN 2,3 via full GEMMs]
  edge_layer_f32(x,  4,   96,  P[1], P[2], P[3], P[4], A);
  edge_layer_f32(A,  192, 252, P[5], P[6], P[7], P[8], Bb);

  if (fused) {
    // c = edge(b) -> Cb ; d = edge(c) -> Db  (a,b stay live; UV region still in use)
    edge_layer_c(Bb, Cb);
    edge_layer_f16(Cb, 192, 252, P[13], P[14], P[15], P[16], Db);
    // Fused nn1 (K=768, one chain) + nn2, M-chunked at 32768 rows.
    // h1c shares the (now dead) UV region. nn2-chunk writes only A-rows its own
    // nn1-chunk already consumed; later nn1-chunks read higher rows only.
    prep_wT<<<(252 * 768 + 255) / 256, 256, 0, stream>>>(P[17] + 4 * 252, 768, 252, 768, WB1);
    prep_wT<<<(192 * 256 + 255) / 256, 256, 0, stream>>>(P[19], 252, 192, 256, WB2);
    dim3 g(2, 256);
    for (int mc = 0; mc < 2; ++mc) {
      size_t roff = (size_t)mc * 32768;
      gemm3h<false, false, true, true, true><<<g, 256, 0, stream>>>(
          A + roff * 192, Bb + roff * 192, Cb + roff * 192, Db + roff * 192, 0,
          WB1, P[18], x + roff * 4, P[17], h1, 32768, 252, 768, 768);
      gemm3h<true, false, true, false, false><<<g, 256, 0, stream>>>(
          h1, h1, nullptr, nullptr, 252, WB2, P[20], nullptr, nullptr,
          A + roff * 192, 32768, 192, 252, 256);
    }
  } else {
    // h1 = [x,a,b] @ nn1w[0:388] + nn1b
    prep_wT<<<(252 * 384 + 255) / 256, 256, 0, stream>>>(P[17] + 4 * 252, 384, 252, 384, WB1);
    dim3 g(2, BN / 128);
    gemm3h<false, false, true, true, false><<<g, 256, 0, stream>>>(
        A, Bb, nullptr, nullptr, 192, WB1, P[18], x, P[17], h1, BN, 252, 384, 384);
    // c = edge(b) -> A (overwrites a) ; d = edge(c) -> Bb
    edge_layer_c(Bb, Cb);
    edge_layer_f16(Cb, 192, 252, P[13], P[14], P[15], P[16], Db);
    // h1 += [c,d] @ nn1w[388:772]
    prep_wT<<<(252 * 384 + 255) / 256, 256, 0, stream>>>(P[17] + (size_t)388 * 252, 384, 252, 384, WB1);
    gemm3h<false, true, false, false, false><<<g, 256, 0, stream>>>(
        Cb, Db, nullptr, nullptr, 192, WB1, nullptr, nullptr, nullptr, h1, BN, 252, 384, 384);
    // nn2: h2 = leaky(h1) @ nn2w + nn2b -> A
    prep_wT<<<(192 * 256 + 255) / 256, 256, 0, stream>>>(P[19], 252, 192, 256, WB2);
    gemm3h<true, false, true, false, false><<<g, 256, 0, stream>>>(
        h1, h1, nullptr, nullptr, 252, WB2, P[20], nullptr, nullptr, A, BN, 192, 252, 256);
  }

  pool_kernel<<<B_, 192, 0, stream>>>(A, pooled);
  head_kernel<<<B_, 128, 0, stream>>>(pooled, P[21], P[22], P[23], P[24], (float*)d_out);
}